// Round 8
// baseline (465.244 us; speedup 1.0000x reference)
//
#include <hip/hip_runtime.h>
#include <math.h>
#include <stdint.h>

namespace {

constexpr int Bn  = 8;
constexpr int Nn  = 500;
constexpr int Qn  = 25;
constexpr int ENC = 512;
constexpr int DIN = 300;
constexpr int NCn = 70;
constexpr int NETn = 3;

typedef __attribute__((ext_vector_type(8))) short bf16x8_t;
typedef __attribute__((ext_vector_type(4))) float f32x4_t;

__device__ __forceinline__ unsigned short f2bf(float f) {
    unsigned int u = __builtin_bit_cast(unsigned int, f);
    u += 0x7fffu + ((u >> 16) & 1u);   // RNE
    return (unsigned short)(u >> 16);
}
__device__ __forceinline__ float bf2f(unsigned short h) {
    unsigned int u = ((unsigned int)h) << 16;
    return __builtin_bit_cast(float, u);
}
__device__ __forceinline__ float sigmoidf_(float x) { return 1.0f / (1.0f + expf(-x)); }

// ---------------------------------------------------------------------------
// Asum[b][i][j] = sum_e adj[b,e,i,j], fp32, j padded 500->512 with zeros.
__global__ __launch_bounds__(128) void sum_adj_pad_k(const float* __restrict__ adj,
                                                     float* __restrict__ Asum) {
    int bi = blockIdx.x;
    int b = bi / Nn, i = bi - b * Nn;
    int j = threadIdx.x * 4;
    float4 s = make_float4(0.f, 0.f, 0.f, 0.f);
    if (j < Nn) {
#pragma unroll
        for (int e = 0; e < NETn; ++e) {
            const float* p = adj + (((size_t)(b * NETn + e) * Nn) + i) * Nn + j;
            float4 v = *(const float4*)p;
            s.x += v.x; s.y += v.y; s.z += v.z; s.w += v.w;
        }
    }
    *(float4*)(Asum + ((size_t)bi) * 512 + j) = s;
}

// ---------------------------------------------------------------------------
// Transpose + convert: in f32 [K][N] -> out bf16 [N][Kpad], zero-padded k>=K.
__global__ __launch_bounds__(256) void tcvt_k(const float* __restrict__ in,
                                              unsigned short* __restrict__ out,
                                              int K, int N, int Kpad) {
    __shared__ float tile[32][33];
    int tx = threadIdx.x & 31, ty = threadIdx.x >> 5;
    int n0 = blockIdx.x * 32, k0 = blockIdx.y * 32;
#pragma unroll
    for (int r = 0; r < 4; ++r) {
        int k = k0 + ty * 4 + r;
        int n = n0 + tx;
        tile[ty * 4 + r][tx] = (k < K && n < N) ? in[(size_t)k * N + n] : 0.0f;
    }
    __syncthreads();
#pragma unroll
    for (int r = 0; r < 4; ++r) {
        int n = n0 + ty * 4 + r;
        int k = k0 + tx;
        if (n < N && k < Kpad) out[(size_t)n * Kpad + k] = f2bf(tile[tx][ty * 4 + r]);
    }
}

// ---------------------------------------------------------------------------
// MFMA core (R4/R7-proven structure): 64x64 tile, BK=32, 4 waves (2x2 of
// 32x32), double-buffered LDS, one barrier per 32-k step.
// AMODE 0: A fp32 row-major (optional A2 concat for k>=ksplit); boundary
//          k-chunks clamp loads at Klim.
// AMODE 1: A bf16 row-major (Abf), direct 16B loads.
// Bt: bf16 B^T row-major [n][k]. LDS 16B lines XOR-swizzled (conflict-free).
template <int AMODE>
__device__ __forceinline__ void mfma_core(
    const float* __restrict__ A, const float* __restrict__ A2,
    const unsigned short* __restrict__ Abf,
    int lda, int ksplit, int Klim,
    const unsigned short* __restrict__ Bt, int ldb,
    int m0, int n0, int K, int Mlim,
    unsigned short* As, unsigned short* Bts, f32x4_t acc[2][2]) {
    const int t = threadIdx.x;
    const int lane = t & 63;
    const int w = t >> 6;
    const int sm = t >> 2;                 // staging row 0..63
    const int sp = t & 3;                  // physical 16B line within row
    const int sq = sp ^ ((sm >> 1) & 3);   // logical k-chunk staged
    const int arow = m0 + sm;
    const bool rowok = arow < Mlim;
    const int wm = (w & 1) * 32, wn = (w >> 1) * 32;
    const int quad = lane >> 4, cidx = lane & 15;
    const int am0 = wm + cidx, am1 = wm + 16 + cidx;
    const int an0 = wn + cidx, an1 = wn + 16 + cidx;
    const int apo0 = am0 * 32 + (quad ^ ((am0 >> 1) & 3)) * 8;
    const int apo1 = am1 * 32 + (quad ^ ((am1 >> 1) & 3)) * 8;
    const int bpo0 = an0 * 32 + (quad ^ ((an0 >> 1) & 3)) * 8;
    const int bpo1 = an1 * 32 + (quad ^ ((an1 >> 1) & 3)) * 8;

    bf16x8_t ast, bst;
    auto stage = [&](int k0) {
        int kg = k0 + sq * 8;
        if (AMODE == 1) {
            bf16x8_t r = {0, 0, 0, 0, 0, 0, 0, 0};
            if (rowok) r = *(const bf16x8_t*)(Abf + (size_t)arow * lda + kg);
            ast = r;
        } else {
            float4 f0 = make_float4(0.f, 0.f, 0.f, 0.f);
            float4 f1 = make_float4(0.f, 0.f, 0.f, 0.f);
            if (rowok) {
                const float* src = (A2 != nullptr && kg >= ksplit)
                                       ? A2 + (size_t)arow * lda + (kg - ksplit)
                                       : A + (size_t)arow * lda + kg;
                if (kg + 8 <= Klim) {
                    f0 = *(const float4*)src;
                    f1 = *(const float4*)(src + 4);
                } else if (kg + 4 <= Klim) {
                    f0 = *(const float4*)src;
                }
            }
            ast[0] = (short)f2bf(f0.x); ast[1] = (short)f2bf(f0.y);
            ast[2] = (short)f2bf(f0.z); ast[3] = (short)f2bf(f0.w);
            ast[4] = (short)f2bf(f1.x); ast[5] = (short)f2bf(f1.y);
            ast[6] = (short)f2bf(f1.z); ast[7] = (short)f2bf(f1.w);
        }
        bst = *(const bf16x8_t*)(Bt + (size_t)(n0 + sm) * ldb + kg);
    };

    const int ktot = K >> 5;
    stage(0);
    *(bf16x8_t*)(As + t * 8) = ast;
    *(bf16x8_t*)(Bts + t * 8) = bst;
    for (int kt = 0; kt < ktot; ++kt) {
        __syncthreads();
        const int cur = (kt & 1) * 2048;
        const bool more = (kt + 1) < ktot;
        if (more) stage((kt + 1) << 5);
        bf16x8_t a0 = *(const bf16x8_t*)(As + cur + apo0);
        bf16x8_t a1 = *(const bf16x8_t*)(As + cur + apo1);
        bf16x8_t b0 = *(const bf16x8_t*)(Bts + cur + bpo0);
        bf16x8_t b1 = *(const bf16x8_t*)(Bts + cur + bpo1);
        acc[0][0] = __builtin_amdgcn_mfma_f32_16x16x32_bf16(a0, b0, acc[0][0], 0, 0, 0);
        acc[0][1] = __builtin_amdgcn_mfma_f32_16x16x32_bf16(a0, b1, acc[0][1], 0, 0, 0);
        acc[1][0] = __builtin_amdgcn_mfma_f32_16x16x32_bf16(a1, b0, acc[1][0], 0, 0, 0);
        acc[1][1] = __builtin_amdgcn_mfma_f32_16x16x32_bf16(a1, b1, acc[1][1], 0, 0, 0);
        if (more) {
            const int nxt = ((kt + 1) & 1) * 2048;
            *(bf16x8_t*)(As + nxt + t * 8) = ast;
            *(bf16x8_t*)(Bts + nxt + t * 8) = bst;
        }
    }
}

#define EPI_SETUP                                         \
    int t = threadIdx.x, lane = t & 63, w = t >> 6;       \
    int wm = (w & 1) * 32, wn = (w >> 1) * 32;            \
    int quad = lane >> 4, cidx = lane & 15;               \
    (void)wm; (void)wn; (void)quad; (void)cidx;

// ---------------------------------------------------------------------------
__global__ __launch_bounds__(256) void gemm_nc_k(const float* __restrict__ ng,
                                                 const unsigned short* __restrict__ WnT,
                                                 const float* __restrict__ bn,
                                                 const int* __restrict__ lens,
                                                 float* __restrict__ nc,
                                                 float* __restrict__ lh0) {
    __shared__ __align__(16) unsigned short As[4096], Bts[4096];
    f32x4_t z = {0.f, 0.f, 0.f, 0.f};
    f32x4_t acc[2][2] = {{z, z}, {z, z}};
    int m0 = blockIdx.x * 64, n0 = blockIdx.y * 64;
    mfma_core<0>(ng, nullptr, nullptr, DIN, 1 << 30, DIN, WnT, 320, m0, n0, 320,
                 Bn * Nn, As, Bts, acc);
    EPI_SETUP
#pragma unroll
    for (int nj = 0; nj < 2; ++nj) {
        int col = n0 + wn + nj * 16 + cidx;
        float bias = bn[col];
#pragma unroll
        for (int mi = 0; mi < 2; ++mi) {
#pragma unroll
            for (int r = 0; r < 4; ++r) {
                int row = m0 + wm + mi * 16 + quad * 4 + r;
                if (row < Bn * Nn) {
                    float tv = tanhf(acc[mi][nj][r] + bias);
                    int b = row / Nn, i = row - b * Nn;
                    float rm = (i < lens[b]) ? 1.0f : 0.0f;
                    nc[(size_t)row * ENC + col] = tv;
                    lh0[(size_t)row * ENC + col] = tv * rm;
                }
            }
        }
    }
}

// ---------------------------------------------------------------------------
__global__ __launch_bounds__(256) void gemm_qc_k(const float* __restrict__ qg,
                                                 const unsigned short* __restrict__ WqT,
                                                 const float* __restrict__ bq,
                                                 float* __restrict__ qc) {
    __shared__ __align__(16) unsigned short As[4096], Bts[4096];
    f32x4_t z = {0.f, 0.f, 0.f, 0.f};
    f32x4_t acc[2][2] = {{z, z}, {z, z}};
    int m0 = blockIdx.x * 64, n0 = blockIdx.y * 64;
    mfma_core<0>(qg, nullptr, nullptr, DIN, 1 << 30, DIN, WqT, 320, m0, n0, 320,
                 Bn * Qn, As, Bts, acc);
    EPI_SETUP
#pragma unroll
    for (int nj = 0; nj < 2; ++nj) {
        int col = n0 + wn + nj * 16 + cidx;
        float bias = bq[col];
#pragma unroll
        for (int mi = 0; mi < 2; ++mi) {
#pragma unroll
            for (int r = 0; r < 4; ++r) {
                int row = m0 + wm + mi * 16 + quad * 4 + r;
                if (row < Bn * Qn) qc[(size_t)row * ENC + col] = acc[mi][nj][r] + bias;
            }
        }
    }
}

// ---------------------------------------------------------------------------
__global__ __launch_bounds__(256) void gemm_hm_k(const float* __restrict__ lh,
                                                 const unsigned short* __restrict__ WhT,
                                                 const float* __restrict__ bh,
                                                 const int* __restrict__ lens,
                                                 unsigned short* __restrict__ hmT) {
    __shared__ __align__(16) unsigned short As[4096], Bts[4096];
    f32x4_t z = {0.f, 0.f, 0.f, 0.f};
    f32x4_t acc[2][2] = {{z, z}, {z, z}};
    int m0 = blockIdx.x * 64, n0 = blockIdx.y * 64;
    mfma_core<0>(lh, nullptr, nullptr, ENC, 1 << 30, ENC, WhT, ENC, m0, n0, ENC,
                 Bn * Nn, As, Bts, acc);
    EPI_SETUP
#pragma unroll
    for (int nj = 0; nj < 2; ++nj) {
        int col = n0 + wn + nj * 16 + cidx;
        float bias = bh[col];
#pragma unroll
        for (int mi = 0; mi < 2; ++mi) {
#pragma unroll
            for (int r = 0; r < 4; ++r) {
                int row = m0 + wm + mi * 16 + quad * 4 + r;
                if (row < Bn * Nn) {
                    int b = row / Nn, i = row - b * Nn;
                    float rm = (i < lens[b]) ? 1.0f : 0.0f;
                    float v = (acc[mi][nj][r] + bias) * rm;
                    hmT[((size_t)b * ENC + col) * 512 + i] = f2bf(v);
                }
            }
        }
    }
}

// ---------------------------------------------------------------------------
// upd = Asum[b] @ hm[b] + hm[b]   (A fp32 padded [500][512], batched via z)
__global__ __launch_bounds__(256) void gemm_upd_k(const float* __restrict__ Asum,
                                                  const unsigned short* __restrict__ hmT,
                                                  float* __restrict__ upd) {
    __shared__ __align__(16) unsigned short As[4096], Bts[4096];
    f32x4_t z = {0.f, 0.f, 0.f, 0.f};
    f32x4_t acc[2][2] = {{z, z}, {z, z}};
    int b = blockIdx.z;
    const float* A = Asum + (size_t)b * Nn * 512;
    const unsigned short* BtH = hmT + (size_t)b * ENC * 512;
    int m0 = blockIdx.x * 64, n0 = blockIdx.y * 64;
    mfma_core<0>(A, nullptr, nullptr, 512, 1 << 30, 512, BtH, 512, m0, n0, 512,
                 Nn, As, Bts, acc);
    EPI_SETUP
#pragma unroll
    for (int nj = 0; nj < 2; ++nj) {
        int col = n0 + wn + nj * 16 + cidx;
#pragma unroll
        for (int mi = 0; mi < 2; ++mi) {
#pragma unroll
            for (int r = 0; r < 4; ++r) {
                int i = m0 + wm + mi * 16 + quad * 4 + r;
                if (i < Nn) {
                    float hv = bf2f(hmT[((size_t)b * ENC + col) * 512 + i]);
                    upd[((size_t)(b * Nn + i)) * ENC + col] = acc[mi][nj][r] + hv;
                }
            }
        }
    }
}

// ---------------------------------------------------------------------------
__global__ __launch_bounds__(256) void gemm_att_k(const float* __restrict__ upd,
                                                  const float* __restrict__ lh,
                                                  const unsigned short* __restrict__ WcT,
                                                  const float* __restrict__ bc,
                                                  const int* __restrict__ lens,
                                                  float* __restrict__ lh_out) {
    __shared__ __align__(16) unsigned short As[4096], Bts[4096];
    f32x4_t z = {0.f, 0.f, 0.f, 0.f};
    f32x4_t acc[2][2] = {{z, z}, {z, z}};
    int m0 = blockIdx.x * 64, n0 = blockIdx.y * 64;
    mfma_core<0>(upd, lh, nullptr, ENC, ENC, 1 << 30, WcT, 2 * ENC, m0, n0, 2 * ENC,
                 Bn * Nn, As, Bts, acc);
    EPI_SETUP
#pragma unroll
    for (int nj = 0; nj < 2; ++nj) {
        int col = n0 + wn + nj * 16 + cidx;
        float bias = bc[col];
#pragma unroll
        for (int mi = 0; mi < 2; ++mi) {
#pragma unroll
            for (int r = 0; r < 4; ++r) {
                int row = m0 + wm + mi * 16 + quad * 4 + r;
                if (row < Bn * Nn) {
                    int b = row / Nn, i = row - b * Nn;
                    float rm = (i < lens[b]) ? 1.0f : 0.0f;
                    float a = sigmoidf_(acc[mi][nj][r] + bias) * rm;
                    size_t off = (size_t)row * ENC + col;
                    lh_out[off] = a * tanhf(upd[off]) + (1.0f - a) * lh[off];
                }
            }
        }
    }
}

// ---------------------------------------------------------------------------
// Materialize g = [nc | n2q | nc*n2q | nc*q2n] as bf16 [4000][2048].
// grid 4000, block 256: wave = segment, lane covers 8 cols (16 B store).
__global__ __launch_bounds__(256) void gbf_k(const float* __restrict__ nc,
                                             const float* __restrict__ n2q,
                                             const float* __restrict__ q2n,
                                             unsigned short* __restrict__ gbf) {
    int row = blockIdx.x;
    int b = row / Nn;
    int t = threadIdx.x;
    int seg = t >> 6;          // 0..3
    int d = (t & 63) * 8;
    size_t off = (size_t)row * ENC + d;
    float4 a0, a1;
    if (seg == 0) {
        a0 = *(const float4*)(nc + off); a1 = *(const float4*)(nc + off + 4);
    } else if (seg == 1) {
        a0 = *(const float4*)(n2q + off); a1 = *(const float4*)(n2q + off + 4);
    } else if (seg == 2) {
        float4 x0 = *(const float4*)(nc + off), x1 = *(const float4*)(nc + off + 4);
        float4 y0 = *(const float4*)(n2q + off), y1 = *(const float4*)(n2q + off + 4);
        a0 = make_float4(x0.x * y0.x, x0.y * y0.y, x0.z * y0.z, x0.w * y0.w);
        a1 = make_float4(x1.x * y1.x, x1.y * y1.y, x1.z * y1.z, x1.w * y1.w);
    } else {
        float4 x0 = *(const float4*)(nc + off), x1 = *(const float4*)(nc + off + 4);
        const float* qp = q2n + (size_t)b * ENC + d;
        float4 y0 = *(const float4*)qp, y1 = *(const float4*)(qp + 4);
        a0 = make_float4(x0.x * y0.x, x0.y * y0.y, x0.z * y0.z, x0.w * y0.w);
        a1 = make_float4(x1.x * y1.x, x1.y * y1.y, x1.z * y1.z, x1.w * y1.w);
    }
    bf16x8_t r;
    r[0] = (short)f2bf(a0.x); r[1] = (short)f2bf(a0.y);
    r[2] = (short)f2bf(a0.z); r[3] = (short)f2bf(a0.w);
    r[4] = (short)f2bf(a1.x); r[5] = (short)f2bf(a1.y);
    r[6] = (short)f2bf(a1.z); r[7] = (short)f2bf(a1.w);
    *(bf16x8_t*)(gbf + (size_t)row * 2048 + seg * 512 + d) = r;
}

// ---------------------------------------------------------------------------
// g @ W1 split-K partials via MFMA; z = K-slice in [0,4) (512 wide).
__global__ __launch_bounds__(256) void gemm_final_k(const unsigned short* __restrict__ gbf,
                                                    const unsigned short* __restrict__ W1T,
                                                    float* __restrict__ part) {
    __shared__ __align__(16) unsigned short As[4096], Bts[4096];
    f32x4_t z4 = {0.f, 0.f, 0.f, 0.f};
    f32x4_t acc[2][2] = {{z4, z4}, {z4, z4}};
    int zz = blockIdx.z;
    int m0 = blockIdx.x * 64, n0 = blockIdx.y * 64;
    mfma_core<1>(nullptr, nullptr, gbf + zz * 512, 2048, 1 << 30, 1 << 30,
                 W1T + zz * 512, 2048, m0, n0, 512, Bn * Nn, As, Bts, acc);
    EPI_SETUP
    constexpr int M = Bn * Nn;
#pragma unroll
    for (int nj = 0; nj < 2; ++nj) {
        int col = n0 + wn + nj * 16 + cidx;   // < 128
#pragma unroll
        for (int mi = 0; mi < 2; ++mi) {
#pragma unroll
            for (int r = 0; r < 4; ++r) {
                int row = m0 + wm + mi * 16 + quad * 4 + r;
                if (row < M) part[((size_t)zz * M + row) * 128 + col] = acc[mi][nj][r];
            }
        }
    }
}

// ---------------------------------------------------------------------------
// Fused sim -> softmax(q) -> nodes2query + rowmax.  One wave per n-row.
__global__ __launch_bounds__(256) void sim_fused_k(const float* __restrict__ lh,
                                                   const float* __restrict__ qc,
                                                   const float* __restrict__ wa,
                                                   float* __restrict__ n2q,
                                                   float* __restrict__ rowmax) {
    __shared__ float qcs[Qn * ENC];   // 51.2 KB
    __shared__ float qdot[32];
    int b = blockIdx.x;
    int t = threadIdx.x;
    const float* qcb = qc + (size_t)b * Qn * ENC;
    for (int i = t * 4; i < Qn * ENC; i += 1024) *(float4*)&qcs[i] = *(const float4*)&qcb[i];
    __syncthreads();
    {
        int q = t >> 3, j = t & 7;
        if (q < Qn) {
            float s = 0.f;
            for (int k = 0; k < 64; ++k) {
                int d = j + 8 * k;
                s += qcs[q * ENC + d] * wa[ENC + d];
            }
            s += __shfl_xor(s, 1, 64);
            s += __shfl_xor(s, 2, 64);
            s += __shfl_xor(s, 4, 64);
            if (j == 0) qdot[q] = s;
        }
    }
    __syncthreads();

    int wv = t >> 6, lane = t & 63;
    int n = blockIdx.y * 4 + wv;
    int d0 = lane * 8;
    const float* lrow = lh + ((size_t)b * Nn + n) * ENC;
    float4 la = *(const float4*)(lrow + d0);
    float4 lb = *(const float4*)(lrow + d0 + 4);
    float lv[8] = {la.x, la.y, la.z, la.w, lb.x, lb.y, lb.z, lb.w};
    float ndp = 0.f;
    float lvs[8];
#pragma unroll
    for (int j = 0; j < 8; ++j) {
        ndp += lv[j] * wa[d0 + j];
        lvs[j] = lv[j] * wa[2 * ENC + d0 + j];
    }
#pragma unroll
    for (int off = 32; off; off >>= 1) ndp += __shfl_xor(ndp, off, 64);

    float s_[Qn];
#pragma unroll
    for (int q = 0; q < Qn; ++q) {
        const float* qrow = qcs + q * ENC + d0;
        float4 qa = *(const float4*)qrow;
        float4 qb = *(const float4*)(qrow + 4);
        s_[q] = lvs[0] * qa.x + lvs[1] * qa.y + lvs[2] * qa.z + lvs[3] * qa.w +
                lvs[4] * qb.x + lvs[5] * qb.y + lvs[6] * qb.z + lvs[7] * qb.w;
    }
#pragma unroll
    for (int q = 0; q < Qn; ++q) {
#pragma unroll
        for (int off = 32; off; off >>= 1) s_[q] += __shfl_xor(s_[q], off, 64);
    }
    float mx = -INFINITY;
#pragma unroll
    for (int q = 0; q < Qn; ++q) {
        s_[q] += ndp + qdot[q];
        mx = fmaxf(mx, s_[q]);
    }
    float sum = 0.f;
#pragma unroll
    for (int q = 0; q < Qn; ++q) { s_[q] = expf(s_[q] - mx); sum += s_[q]; }
    float inv = 1.0f / sum;
    float o[8] = {};
#pragma unroll
    for (int q = 0; q < Qn; ++q) {
        const float* qrow = qcs + q * ENC + d0;
        float4 qa = *(const float4*)qrow;
        float4 qb = *(const float4*)(qrow + 4);
        float p = s_[q] * inv;
        o[0] += p * qa.x; o[1] += p * qa.y; o[2] += p * qa.z; o[3] += p * qa.w;
        o[4] += p * qb.x; o[5] += p * qb.y; o[6] += p * qb.z; o[7] += p * qb.w;
    }
    float* orow = n2q + ((size_t)b * Nn + n) * ENC + d0;
    *(float4*)orow = make_float4(o[0], o[1], o[2], o[3]);
    *(float4*)(orow + 4) = make_float4(o[4], o[5], o[6], o[7]);
    if (lane == 0) rowmax[b * Nn + n] = mx;
}

// ---------------------------------------------------------------------------
__global__ __launch_bounds__(512) void bvec_k(const float* __restrict__ rowmax,
                                              float* __restrict__ bvec) {
    __shared__ float red[8];
    int b = blockIdx.x, t = threadIdx.x;
    float v = (t < Nn) ? rowmax[b * Nn + t] : -INFINITY;
    float m = v;
    for (int off = 32; off; off >>= 1) m = fmaxf(m, __shfl_xor(m, off, 64));
    if ((t & 63) == 0) red[t >> 6] = m;
    __syncthreads();
    float bm = red[0];
    for (int i = 1; i < 8; ++i) bm = fmaxf(bm, red[i]);
    float e = (t < Nn) ? expf(v - bm) : 0.0f;
    float ssum = e;
    for (int off = 32; off; off >>= 1) ssum += __shfl_xor(ssum, off, 64);
    __syncthreads();
    if ((t & 63) == 0) red[t >> 6] = ssum;
    __syncthreads();
    float tot = 0.f;
    for (int i = 0; i < 8; ++i) tot += red[i];
    if (t < Nn) bvec[b * Nn + t] = e / tot;
}

// ---------------------------------------------------------------------------
__global__ __launch_bounds__(256) void q2n_k(const float* __restrict__ bvec,
                                             const float* __restrict__ nc,
                                             float* __restrict__ q2n) {
    int b = blockIdx.x;
    int d = blockIdx.y * 256 + threadIdx.x;
    const float* ncb = nc + (size_t)b * Nn * ENC;
    float acc = 0.f;
    for (int n = 0; n < Nn; ++n) acc = fmaf(bvec[b * Nn + n], ncb[(size_t)n * ENC + d], acc);
    q2n[b * ENC + d] = acc;
}

// ---------------------------------------------------------------------------
// raw[row] = b2 + sum_h tanh(sum_z part[z][row][h] + b1[h]) * W2[h]
__global__ __launch_bounds__(256) void final_reduce_k(const float* __restrict__ part,
                                                      const float* __restrict__ b1p,
                                                      const float* __restrict__ W2p,
                                                      const float* __restrict__ b2p,
                                                      float* __restrict__ raw) {
    constexpr int M = Bn * Nn;
    int wave = threadIdx.x >> 6, lane = threadIdx.x & 63;
    int row = blockIdx.x * 4 + wave;
    if (row >= M) return;
    float v0 = 0.f, v1 = 0.f;
#pragma unroll
    for (int s = 0; s < 4; ++s) {
        const float* pr = part + ((size_t)s * M + row) * 128;
        v0 += pr[lane];
        v1 += pr[lane + 64];
    }
    float p = tanhf(v0 + b1p[lane]) * W2p[lane] + tanhf(v1 + b1p[lane + 64]) * W2p[lane + 64];
    for (int off = 32; off; off >>= 1) p += __shfl_xor(p, off, 64);
    if (lane == 0) raw[row] = p + b2p[0];
}

// ---------------------------------------------------------------------------
__global__ __launch_bounds__(256) void predmax_k(const int* __restrict__ mask,
                                                 const float* __restrict__ raw,
                                                 float* __restrict__ out) {
    int idx = blockIdx.x * 4 + (threadIdx.x >> 6);
    int lane = threadIdx.x & 63;
    if (idx >= Bn * NCn) return;
    int b = idx / NCn, c = idx - b * NCn;
    const int* mrow = mask + ((size_t)b * NCn + c) * Nn;
    const float* rrow = raw + (size_t)b * Nn;
    float mx = -INFINITY;
    for (int n = lane; n < Nn; n += 64) {
        float v = mrow[n] ? rrow[n] : 0.0f;
        if (v == 0.0f) v = -1.0e6f;
        mx = fmaxf(mx, v);
    }
    for (int off = 32; off; off >>= 1) mx = fmaxf(mx, __shfl_xor(mx, off, 64));
    if (lane == 0) out[idx] = mx;
}

}  // namespace

extern "C" void kernel_launch(void* const* d_in, const int* in_sizes, int n_in,
                              void* d_out, int out_size, void* d_ws, size_t ws_size,
                              hipStream_t stream) {
    const float* nodes_glove  = (const float*)d_in[0];
    const float* query_glove  = (const float*)d_in[1];
    const float* adj          = (const float*)d_in[2];
    const int*   nodes_length = (const int*)d_in[3];
    const int*   maskp        = (const int*)d_in[4];
    const float* Wn = (const float*)d_in[5];
    const float* bn = (const float*)d_in[6];
    const float* Wq = (const float*)d_in[7];
    const float* bq = (const float*)d_in[8];
    const float* Wh = (const float*)d_in[9];
    const float* bh = (const float*)d_in[10];
    const float* Wc = (const float*)d_in[11];
    const float* bc = (const float*)d_in[12];
    const float* wa = (const float*)d_in[13];
    const float* W1 = (const float*)d_in[14];
    const float* b1 = (const float*)d_in[15];
    const float* W2 = (const float*)d_in[16];
    const float* b2 = (const float*)d_in[17];
    float* out = (float*)d_out;

    // ws budget: total usage must not exceed the R4/R7-proven high-water mark
    // (~11.98M floats) — R5/R6 crashes were ws overflow. All new buffers alias.
    float* ws = (float*)d_ws;
    size_t off = 0;
    auto alloc = [&](size_t n) { float* p = ws + off; off += n; return p; };
    constexpr size_t ME = (size_t)Bn * Nn * ENC;   // 2,048,000
    float* nc   = alloc(ME);
    float* lh0  = alloc(ME);   // lh0+upd adjacent: reused as gbf [4000][2048] bf16
    float* upd  = alloc(ME);
    float* lh1  = alloc(ME);
    float* Asum = alloc(ME);   // fp32 [8][500][512]; then n2q; then final part buf
    float* qc   = alloc((size_t)Bn * Qn * ENC);
    float* rowmax = alloc(Bn * Nn);
    float* bvec   = alloc(Bn * Nn);
    float* q2n    = alloc(Bn * ENC);
    float* raw    = alloc(Bn * Nn);
    unsigned short* hmT = (unsigned short*)alloc((size_t)Bn * ENC * 512 / 2);
    unsigned short* WnT = (unsigned short*)alloc((size_t)ENC * 320 / 2);
    unsigned short* WqT = (unsigned short*)alloc((size_t)ENC * 320 / 2);
    unsigned short* WhT = (unsigned short*)alloc((size_t)ENC * ENC / 2);
    unsigned short* WcT = (unsigned short*)alloc((size_t)ENC * 2 * ENC / 2);
    alloc(16384);  // tail pad
    float* n2q  = Asum;                         // phase 2
    float* part = Asum;                         // phase 3 (after gbf consumed n2q)
    unsigned short* gbf = (unsigned short*)lh0; // spans lh0+upd (8.19M shorts)
    unsigned short* W1T = WnT;                  // spans WnT+WqT (327,680 shorts >= 262,144)

    constexpr int M = Bn * Nn;  // 4000

    sum_adj_pad_k<<<dim3(Bn * Nn), 128, 0, stream>>>(adj, Asum);
    tcvt_k<<<dim3(16, 10), 256, 0, stream>>>(Wn, WnT, DIN, ENC, 320);
    tcvt_k<<<dim3(16, 10), 256, 0, stream>>>(Wq, WqT, DIN, ENC, 320);
    tcvt_k<<<dim3(16, 16), 256, 0, stream>>>(Wh, WhT, ENC, ENC, ENC);
    tcvt_k<<<dim3(16, 32), 256, 0, stream>>>(Wc, WcT, 2 * ENC, ENC, 2 * ENC);

    gemm_nc_k<<<dim3((M + 63) / 64, 8), 256, 0, stream>>>(nodes_glove, WnT, bn,
                                                          nodes_length, nc, lh0);
    gemm_qc_k<<<dim3((Bn * Qn + 63) / 64, 8), 256, 0, stream>>>(query_glove, WqT, bq, qc);
    // WnT/WqT dead from here; W1T (aliasing them) safe to build now.
    tcvt_k<<<dim3(4, 64), 256, 0, stream>>>(W1, W1T, 2048, 128, 2048);

    // 3 hops; cur starts at lh0 so after 3 swaps cur==lh1, freeing lh0+upd.
    float* cur = lh0;
    float* nxt = lh1;
    for (int h = 0; h < 3; ++h) {
        gemm_hm_k<<<dim3((M + 63) / 64, 8), 256, 0, stream>>>(cur, WhT, bh,
                                                              nodes_length, hmT);
        gemm_upd_k<<<dim3(8, 8, Bn), 256, 0, stream>>>(Asum, hmT, upd);
        gemm_att_k<<<dim3((M + 63) / 64, 8), 256, 0, stream>>>(upd, cur, WcT, bc,
                                                               nodes_length, nxt);
        float* tmp = cur; cur = nxt; nxt = tmp;
    }
    // cur == lh1 == final last_hop; lh0, upd, Asum now free.

    sim_fused_k<<<dim3(Bn, 125), 256, 0, stream>>>(cur, qc, wa, n2q, rowmax);
    bvec_k<<<dim3(Bn), 512, 0, stream>>>(rowmax, bvec);
    q2n_k<<<dim3(Bn, ENC / 256), 256, 0, stream>>>(bvec, nc, q2n);
    gbf_k<<<dim3(M), 256, 0, stream>>>(nc, n2q, q2n, gbf);       // consumes n2q
    gemm_final_k<<<dim3((M + 63) / 64, 2, 4), 256, 0, stream>>>(gbf, W1T, part);
    final_reduce_k<<<dim3((M + 3) / 4), 256, 0, stream>>>(part, b1, W2, b2, raw);
    predmax_k<<<dim3((Bn * NCn + 3) / 4), 256, 0, stream>>>(maskp, raw, out);
}

// Round 10
// 454.827 us; speedup vs baseline: 1.0229x; 1.0229x over previous
//
#include <hip/hip_runtime.h>
#include <hip/hip_bf16.h>
#include <math.h>
#include <stdint.h>

namespace {

constexpr int Bn  = 8;
constexpr int Nn  = 500;
constexpr int Qn  = 25;
constexpr int ENC = 512;
constexpr int DIN = 300;
constexpr int NCn = 70;
constexpr int NETn = 3;

typedef __attribute__((ext_vector_type(8))) short bf16x8_t;
typedef __attribute__((ext_vector_type(4))) float f32x4_t;

// Hardware bf16 conversion (gfx950 v_cvt_pk_bf16_f32), RNE — numerically
// identical to the previous manual round-to-nearest-even.
__device__ __forceinline__ unsigned short f2bf(float f) {
    union { __hip_bfloat16 b; unsigned short u; } r;
    r.b = __float2bfloat16(f);
    return r.u;
}
__device__ __forceinline__ bf16x8_t cvt8(float4 f0, float4 f1) {
    union { bf16x8_t v; __hip_bfloat162 b[4]; } r;
    r.b[0] = __float22bfloat162_rn(make_float2(f0.x, f0.y));
    r.b[1] = __float22bfloat162_rn(make_float2(f0.z, f0.w));
    r.b[2] = __float22bfloat162_rn(make_float2(f1.x, f1.y));
    r.b[3] = __float22bfloat162_rn(make_float2(f1.z, f1.w));
    return r.v;
}
__device__ __forceinline__ float bf2f(unsigned short h) {
    unsigned int u = ((unsigned int)h) << 16;
    return __builtin_bit_cast(float, u);
}
__device__ __forceinline__ float sigmoidf_(float x) { return 1.0f / (1.0f + expf(-x)); }

// ---------------------------------------------------------------------------
// Asum[b][i][j] = sum_e adj[b,e,i,j], fp32, j padded 500->512 with zeros.
__global__ __launch_bounds__(128) void sum_adj_pad_k(const float* __restrict__ adj,
                                                     float* __restrict__ Asum) {
    int bi = blockIdx.x;
    int b = bi / Nn, i = bi - b * Nn;
    int j = threadIdx.x * 4;
    float4 s = make_float4(0.f, 0.f, 0.f, 0.f);
    if (j < Nn) {
#pragma unroll
        for (int e = 0; e < NETn; ++e) {
            const float* p = adj + (((size_t)(b * NETn + e) * Nn) + i) * Nn + j;
            float4 v = *(const float4*)p;
            s.x += v.x; s.y += v.y; s.z += v.z; s.w += v.w;
        }
    }
    *(float4*)(Asum + ((size_t)bi) * 512 + j) = s;
}

// ---------------------------------------------------------------------------
// Transpose + convert: in f32 [K][N] -> out bf16 [N][Kpad], zero-padded k>=K.
__global__ __launch_bounds__(256) void tcvt_k(const float* __restrict__ in,
                                              unsigned short* __restrict__ out,
                                              int K, int N, int Kpad) {
    __shared__ float tile[32][33];
    int tx = threadIdx.x & 31, ty = threadIdx.x >> 5;
    int n0 = blockIdx.x * 32, k0 = blockIdx.y * 32;
#pragma unroll
    for (int r = 0; r < 4; ++r) {
        int k = k0 + ty * 4 + r;
        int n = n0 + tx;
        tile[ty * 4 + r][tx] = (k < K && n < N) ? in[(size_t)k * N + n] : 0.0f;
    }
    __syncthreads();
#pragma unroll
    for (int r = 0; r < 4; ++r) {
        int n = n0 + ty * 4 + r;
        int k = k0 + tx;
        if (n < N && k < Kpad) out[(size_t)n * Kpad + k] = f2bf(tile[tx][ty * 4 + r]);
    }
}

// ---------------------------------------------------------------------------
// MFMA core (R4/R7/R8-proven structure): 64x64 tile, BK=32, 4 waves (2x2 of
// 32x32), double-buffered LDS, one barrier per 32-k step.
// AMODE 0: A fp32 row-major (optional A2 concat for k>=ksplit); boundary
//          k-chunks clamp loads at Klim.
// AMODE 1: A bf16 row-major (Abf), direct 16B loads.
// Bt: bf16 B^T row-major [n][k]. LDS 16B lines XOR-swizzled (conflict-free).
template <int AMODE>
__device__ __forceinline__ void mfma_core(
    const float* __restrict__ A, const float* __restrict__ A2,
    const unsigned short* __restrict__ Abf,
    int lda, int ksplit, int Klim,
    const unsigned short* __restrict__ Bt, int ldb,
    int m0, int n0, int K, int Mlim,
    unsigned short* As, unsigned short* Bts, f32x4_t acc[2][2]) {
    const int t = threadIdx.x;
    const int lane = t & 63;
    const int w = t >> 6;
    const int sm = t >> 2;                 // staging row 0..63
    const int sp = t & 3;                  // physical 16B line within row
    const int sq = sp ^ ((sm >> 1) & 3);   // logical k-chunk staged
    const int arow = m0 + sm;
    const bool rowok = arow < Mlim;
    const int wm = (w & 1) * 32, wn = (w >> 1) * 32;
    const int quad = lane >> 4, cidx = lane & 15;
    const int am0 = wm + cidx, am1 = wm + 16 + cidx;
    const int an0 = wn + cidx, an1 = wn + 16 + cidx;
    const int apo0 = am0 * 32 + (quad ^ ((am0 >> 1) & 3)) * 8;
    const int apo1 = am1 * 32 + (quad ^ ((am1 >> 1) & 3)) * 8;
    const int bpo0 = an0 * 32 + (quad ^ ((an0 >> 1) & 3)) * 8;
    const int bpo1 = an1 * 32 + (quad ^ ((an1 >> 1) & 3)) * 8;

    bf16x8_t ast, bst;
    auto stage = [&](int k0) {
        int kg = k0 + sq * 8;
        if (AMODE == 1) {
            bf16x8_t r = {0, 0, 0, 0, 0, 0, 0, 0};
            if (rowok) r = *(const bf16x8_t*)(Abf + (size_t)arow * lda + kg);
            ast = r;
        } else {
            float4 f0 = make_float4(0.f, 0.f, 0.f, 0.f);
            float4 f1 = make_float4(0.f, 0.f, 0.f, 0.f);
            if (rowok) {
                const float* src = (A2 != nullptr && kg >= ksplit)
                                       ? A2 + (size_t)arow * lda + (kg - ksplit)
                                       : A + (size_t)arow * lda + kg;
                if (kg + 8 <= Klim) {
                    f0 = *(const float4*)src;
                    f1 = *(const float4*)(src + 4);
                } else if (kg + 4 <= Klim) {
                    f0 = *(const float4*)src;
                }
            }
            ast = cvt8(f0, f1);
        }
        bst = *(const bf16x8_t*)(Bt + (size_t)(n0 + sm) * ldb + kg);
    };

    const int ktot = K >> 5;
    stage(0);
    *(bf16x8_t*)(As + t * 8) = ast;
    *(bf16x8_t*)(Bts + t * 8) = bst;
    for (int kt = 0; kt < ktot; ++kt) {
        __syncthreads();
        const int cur = (kt & 1) * 2048;
        const bool more = (kt + 1) < ktot;
        if (more) stage((kt + 1) << 5);
        bf16x8_t a0 = *(const bf16x8_t*)(As + cur + apo0);
        bf16x8_t a1 = *(const bf16x8_t*)(As + cur + apo1);
        bf16x8_t b0 = *(const bf16x8_t*)(Bts + cur + bpo0);
        bf16x8_t b1 = *(const bf16x8_t*)(Bts + cur + bpo1);
        acc[0][0] = __builtin_amdgcn_mfma_f32_16x16x32_bf16(a0, b0, acc[0][0], 0, 0, 0);
        acc[0][1] = __builtin_amdgcn_mfma_f32_16x16x32_bf16(a0, b1, acc[0][1], 0, 0, 0);
        acc[1][0] = __builtin_amdgcn_mfma_f32_16x16x32_bf16(a1, b0, acc[1][0], 0, 0, 0);
        acc[1][1] = __builtin_amdgcn_mfma_f32_16x16x32_bf16(a1, b1, acc[1][1], 0, 0, 0);
        if (more) {
            const int nxt = ((kt + 1) & 1) * 2048;
            *(bf16x8_t*)(As + nxt + t * 8) = ast;
            *(bf16x8_t*)(Bts + nxt + t * 8) = bst;
        }
    }
}

#define EPI_SETUP                                         \
    int t = threadIdx.x, lane = t & 63, w = t >> 6;       \
    int wm = (w & 1) * 32, wn = (w >> 1) * 32;            \
    int quad = lane >> 4, cidx = lane & 15;               \
    (void)wm; (void)wn; (void)quad; (void)cidx;

// ---------------------------------------------------------------------------
__global__ __launch_bounds__(256) void gemm_nc_k(const float* __restrict__ ng,
                                                 const unsigned short* __restrict__ WnT,
                                                 const float* __restrict__ bn,
                                                 const int* __restrict__ lens,
                                                 float* __restrict__ nc,
                                                 float* __restrict__ lh0) {
    __shared__ __align__(16) unsigned short As[4096], Bts[4096];
    f32x4_t z = {0.f, 0.f, 0.f, 0.f};
    f32x4_t acc[2][2] = {{z, z}, {z, z}};
    int m0 = blockIdx.x * 64, n0 = blockIdx.y * 64;
    mfma_core<0>(ng, nullptr, nullptr, DIN, 1 << 30, DIN, WnT, 320, m0, n0, 320,
                 Bn * Nn, As, Bts, acc);
    EPI_SETUP
#pragma unroll
    for (int nj = 0; nj < 2; ++nj) {
        int col = n0 + wn + nj * 16 + cidx;
        float bias = bn[col];
#pragma unroll
        for (int mi = 0; mi < 2; ++mi) {
#pragma unroll
            for (int r = 0; r < 4; ++r) {
                int row = m0 + wm + mi * 16 + quad * 4 + r;
                if (row < Bn * Nn) {
                    float tv = tanhf(acc[mi][nj][r] + bias);
                    int b = row / Nn, i = row - b * Nn;
                    float rm = (i < lens[b]) ? 1.0f : 0.0f;
                    nc[(size_t)row * ENC + col] = tv;
                    lh0[(size_t)row * ENC + col] = tv * rm;
                }
            }
        }
    }
}

// ---------------------------------------------------------------------------
__global__ __launch_bounds__(256) void gemm_qc_k(const float* __restrict__ qg,
                                                 const unsigned short* __restrict__ WqT,
                                                 const float* __restrict__ bq,
                                                 float* __restrict__ qc) {
    __shared__ __align__(16) unsigned short As[4096], Bts[4096];
    f32x4_t z = {0.f, 0.f, 0.f, 0.f};
    f32x4_t acc[2][2] = {{z, z}, {z, z}};
    int m0 = blockIdx.x * 64, n0 = blockIdx.y * 64;
    mfma_core<0>(qg, nullptr, nullptr, DIN, 1 << 30, DIN, WqT, 320, m0, n0, 320,
                 Bn * Qn, As, Bts, acc);
    EPI_SETUP
#pragma unroll
    for (int nj = 0; nj < 2; ++nj) {
        int col = n0 + wn + nj * 16 + cidx;
        float bias = bq[col];
#pragma unroll
        for (int mi = 0; mi < 2; ++mi) {
#pragma unroll
            for (int r = 0; r < 4; ++r) {
                int row = m0 + wm + mi * 16 + quad * 4 + r;
                if (row < Bn * Qn) qc[(size_t)row * ENC + col] = acc[mi][nj][r] + bias;
            }
        }
    }
}

// ---------------------------------------------------------------------------
__global__ __launch_bounds__(256) void gemm_hm_k(const float* __restrict__ lh,
                                                 const unsigned short* __restrict__ WhT,
                                                 const float* __restrict__ bh,
                                                 const int* __restrict__ lens,
                                                 unsigned short* __restrict__ hmT) {
    __shared__ __align__(16) unsigned short As[4096], Bts[4096];
    f32x4_t z = {0.f, 0.f, 0.f, 0.f};
    f32x4_t acc[2][2] = {{z, z}, {z, z}};
    int m0 = blockIdx.x * 64, n0 = blockIdx.y * 64;
    mfma_core<0>(lh, nullptr, nullptr, ENC, 1 << 30, ENC, WhT, ENC, m0, n0, ENC,
                 Bn * Nn, As, Bts, acc);
    EPI_SETUP
#pragma unroll
    for (int nj = 0; nj < 2; ++nj) {
        int col = n0 + wn + nj * 16 + cidx;
        float bias = bh[col];
#pragma unroll
        for (int mi = 0; mi < 2; ++mi) {
#pragma unroll
            for (int r = 0; r < 4; ++r) {
                int row = m0 + wm + mi * 16 + quad * 4 + r;
                if (row < Bn * Nn) {
                    int b = row / Nn, i = row - b * Nn;
                    float rm = (i < lens[b]) ? 1.0f : 0.0f;
                    float v = (acc[mi][nj][r] + bias) * rm;
                    hmT[((size_t)b * ENC + col) * 512 + i] = f2bf(v);
                }
            }
        }
    }
}

// ---------------------------------------------------------------------------
// upd = Asum[b] @ hm[b] + hm[b]   (A fp32 padded [500][512], batched via z)
__global__ __launch_bounds__(256) void gemm_upd_k(const float* __restrict__ Asum,
                                                  const unsigned short* __restrict__ hmT,
                                                  float* __restrict__ upd) {
    __shared__ __align__(16) unsigned short As[4096], Bts[4096];
    f32x4_t z = {0.f, 0.f, 0.f, 0.f};
    f32x4_t acc[2][2] = {{z, z}, {z, z}};
    int b = blockIdx.z;
    const float* A = Asum + (size_t)b * Nn * 512;
    const unsigned short* BtH = hmT + (size_t)b * ENC * 512;
    int m0 = blockIdx.x * 64, n0 = blockIdx.y * 64;
    mfma_core<0>(A, nullptr, nullptr, 512, 1 << 30, 512, BtH, 512, m0, n0, 512,
                 Nn, As, Bts, acc);
    EPI_SETUP
#pragma unroll
    for (int nj = 0; nj < 2; ++nj) {
        int col = n0 + wn + nj * 16 + cidx;
#pragma unroll
        for (int mi = 0; mi < 2; ++mi) {
#pragma unroll
            for (int r = 0; r < 4; ++r) {
                int i = m0 + wm + mi * 16 + quad * 4 + r;
                if (i < Nn) {
                    float hv = bf2f(hmT[((size_t)b * ENC + col) * 512 + i]);
                    upd[((size_t)(b * Nn + i)) * ENC + col] = acc[mi][nj][r] + hv;
                }
            }
        }
    }
}

// ---------------------------------------------------------------------------
__global__ __launch_bounds__(256) void gemm_att_k(const float* __restrict__ upd,
                                                  const float* __restrict__ lh,
                                                  const unsigned short* __restrict__ WcT,
                                                  const float* __restrict__ bc,
                                                  const int* __restrict__ lens,
                                                  float* __restrict__ lh_out) {
    __shared__ __align__(16) unsigned short As[4096], Bts[4096];
    f32x4_t z = {0.f, 0.f, 0.f, 0.f};
    f32x4_t acc[2][2] = {{z, z}, {z, z}};
    int m0 = blockIdx.x * 64, n0 = blockIdx.y * 64;
    mfma_core<0>(upd, lh, nullptr, ENC, ENC, 1 << 30, WcT, 2 * ENC, m0, n0, 2 * ENC,
                 Bn * Nn, As, Bts, acc);
    EPI_SETUP
#pragma unroll
    for (int nj = 0; nj < 2; ++nj) {
        int col = n0 + wn + nj * 16 + cidx;
        float bias = bc[col];
#pragma unroll
        for (int mi = 0; mi < 2; ++mi) {
#pragma unroll
            for (int r = 0; r < 4; ++r) {
                int row = m0 + wm + mi * 16 + quad * 4 + r;
                if (row < Bn * Nn) {
                    int b = row / Nn, i = row - b * Nn;
                    float rm = (i < lens[b]) ? 1.0f : 0.0f;
                    float a = sigmoidf_(acc[mi][nj][r] + bias) * rm;
                    size_t off = (size_t)row * ENC + col;
                    lh_out[off] = a * tanhf(upd[off]) + (1.0f - a) * lh[off];
                }
            }
        }
    }
}

// ---------------------------------------------------------------------------
// Materialize g = [nc | n2q | nc*n2q | nc*q2n] as bf16 [4000][2048].
__global__ __launch_bounds__(256) void gbf_k(const float* __restrict__ nc,
                                             const float* __restrict__ n2q,
                                             const float* __restrict__ q2n,
                                             unsigned short* __restrict__ gbf) {
    int row = blockIdx.x;
    int b = row / Nn;
    int t = threadIdx.x;
    int seg = t >> 6;          // 0..3
    int d = (t & 63) * 8;
    size_t off = (size_t)row * ENC + d;
    float4 a0, a1;
    if (seg == 0) {
        a0 = *(const float4*)(nc + off); a1 = *(const float4*)(nc + off + 4);
    } else if (seg == 1) {
        a0 = *(const float4*)(n2q + off); a1 = *(const float4*)(n2q + off + 4);
    } else if (seg == 2) {
        float4 x0 = *(const float4*)(nc + off), x1 = *(const float4*)(nc + off + 4);
        float4 y0 = *(const float4*)(n2q + off), y1 = *(const float4*)(n2q + off + 4);
        a0 = make_float4(x0.x * y0.x, x0.y * y0.y, x0.z * y0.z, x0.w * y0.w);
        a1 = make_float4(x1.x * y1.x, x1.y * y1.y, x1.z * y1.z, x1.w * y1.w);
    } else {
        float4 x0 = *(const float4*)(nc + off), x1 = *(const float4*)(nc + off + 4);
        const float* qp = q2n + (size_t)b * ENC + d;
        float4 y0 = *(const float4*)qp, y1 = *(const float4*)(qp + 4);
        a0 = make_float4(x0.x * y0.x, x0.y * y0.y, x0.z * y0.z, x0.w * y0.w);
        a1 = make_float4(x1.x * y1.x, x1.y * y1.y, x1.z * y1.z, x1.w * y1.w);
    }
    *(bf16x8_t*)(gbf + (size_t)row * 2048 + seg * 512 + d) = cvt8(a0, a1);
}

// ---------------------------------------------------------------------------
// g @ W1 split-K partials via MFMA; z = K-slice in [0,4) (512 wide).
__global__ __launch_bounds__(256) void gemm_final_k(const unsigned short* __restrict__ gbf,
                                                    const unsigned short* __restrict__ W1T,
                                                    float* __restrict__ part) {
    __shared__ __align__(16) unsigned short As[4096], Bts[4096];
    f32x4_t z4 = {0.f, 0.f, 0.f, 0.f};
    f32x4_t acc[2][2] = {{z4, z4}, {z4, z4}};
    int zz = blockIdx.z;
    int m0 = blockIdx.x * 64, n0 = blockIdx.y * 64;
    mfma_core<1>(nullptr, nullptr, gbf + zz * 512, 2048, 1 << 30, 1 << 30,
                 W1T + zz * 512, 2048, m0, n0, 512, Bn * Nn, As, Bts, acc);
    EPI_SETUP
    constexpr int M = Bn * Nn;
#pragma unroll
    for (int nj = 0; nj < 2; ++nj) {
        int col = n0 + wn + nj * 16 + cidx;   // < 128
#pragma unroll
        for (int mi = 0; mi < 2; ++mi) {
#pragma unroll
            for (int r = 0; r < 4; ++r) {
                int row = m0 + wm + mi * 16 + quad * 4 + r;
                if (row < M) part[((size_t)zz * M + row) * 128 + col] = acc[mi][nj][r];
            }
        }
    }
}

// ---------------------------------------------------------------------------
// Fused sim -> softmax(q) -> nodes2query + rowmax.  One wave per n-row.
// Lane owns d in {4L..4L+3} u {256+4L..256+4L+3}: consecutive lanes read
// consecutive 16B -> conflict-free ds_read_b128 (fixes R4's 16-way conflict).
__global__ __launch_bounds__(256) void sim_fused_k(const float* __restrict__ lh,
                                                   const float* __restrict__ qc,
                                                   const float* __restrict__ wa,
                                                   float* __restrict__ n2q,
                                                   float* __restrict__ rowmax) {
    __shared__ float qcs[Qn * ENC];   // 51.2 KB
    __shared__ float qdot[32];
    int b = blockIdx.x;
    int t = threadIdx.x;
    const float* qcb = qc + (size_t)b * Qn * ENC;
    for (int i = t * 4; i < Qn * ENC; i += 1024) *(float4*)&qcs[i] = *(const float4*)&qcb[i];
    __syncthreads();
    {
        int q = t >> 3, j = t & 7;
        if (q < Qn) {
            float s = 0.f;
            for (int k = 0; k < 64; ++k) {
                int d = j + 8 * k;
                s += qcs[q * ENC + d] * wa[ENC + d];
            }
            s += __shfl_xor(s, 1, 64);
            s += __shfl_xor(s, 2, 64);
            s += __shfl_xor(s, 4, 64);
            if (j == 0) qdot[q] = s;
        }
    }
    __syncthreads();

    int wv = t >> 6, lane = t & 63;
    int n = blockIdx.y * 4 + wv;
    int dA = lane * 4;          // first owned 16B chunk
    int dB = 256 + lane * 4;    // second owned 16B chunk
    const float* lrow = lh + ((size_t)b * Nn + n) * ENC;
    float4 la = *(const float4*)(lrow + dA);
    float4 lb = *(const float4*)(lrow + dB);
    float lv[8] = {la.x, la.y, la.z, la.w, lb.x, lb.y, lb.z, lb.w};
    float ndp = 0.f;
    float lvs[8];
#pragma unroll
    for (int j = 0; j < 4; ++j) {
        ndp += lv[j] * wa[dA + j];
        lvs[j] = lv[j] * wa[2 * ENC + dA + j];
        ndp += lv[4 + j] * wa[dB + j];
        lvs[4 + j] = lv[4 + j] * wa[2 * ENC + dB + j];
    }
#pragma unroll
    for (int off = 32; off; off >>= 1) ndp += __shfl_xor(ndp, off, 64);

    float s_[Qn];
#pragma unroll
    for (int q = 0; q < Qn; ++q) {
        float4 qa = *(const float4*)(qcs + q * ENC + dA);
        float4 qb = *(const float4*)(qcs + q * ENC + dB);
        s_[q] = lvs[0] * qa.x + lvs[1] * qa.y + lvs[2] * qa.z + lvs[3] * qa.w +
                lvs[4] * qb.x + lvs[5] * qb.y + lvs[6] * qb.z + lvs[7] * qb.w;
    }
#pragma unroll
    for (int q = 0; q < Qn; ++q) {
#pragma unroll
        for (int off = 32; off; off >>= 1) s_[q] += __shfl_xor(s_[q], off, 64);
    }
    float mx = -INFINITY;
#pragma unroll
    for (int q = 0; q < Qn; ++q) {
        s_[q] += ndp + qdot[q];
        mx = fmaxf(mx, s_[q]);
    }
    float sum = 0.f;
#pragma unroll
    for (int q = 0; q < Qn; ++q) { s_[q] = expf(s_[q] - mx); sum += s_[q]; }
    float inv = 1.0f / sum;
    float o[8] = {};
#pragma unroll
    for (int q = 0; q < Qn; ++q) {
        float4 qa = *(const float4*)(qcs + q * ENC + dA);
        float4 qb = *(const float4*)(qcs + q * ENC + dB);
        float p = s_[q] * inv;
        o[0] += p * qa.x; o[1] += p * qa.y; o[2] += p * qa.z; o[3] += p * qa.w;
        o[4] += p * qb.x; o[5] += p * qb.y; o[6] += p * qb.z; o[7] += p * qb.w;
    }
    float* orow = n2q + ((size_t)b * Nn + n) * ENC;
    *(float4*)(orow + dA) = make_float4(o[0], o[1], o[2], o[3]);
    *(float4*)(orow + dB) = make_float4(o[4], o[5], o[6], o[7]);
    if (lane == 0) rowmax[b * Nn + n] = mx;
}

// ---------------------------------------------------------------------------
__global__ __launch_bounds__(512) void bvec_k(const float* __restrict__ rowmax,
                                              float* __restrict__ bvec) {
    __shared__ float red[8];
    int b = blockIdx.x, t = threadIdx.x;
    float v = (t < Nn) ? rowmax[b * Nn + t] : -INFINITY;
    float m = v;
    for (int off = 32; off; off >>= 1) m = fmaxf(m, __shfl_xor(m, off, 64));
    if ((t & 63) == 0) red[t >> 6] = m;
    __syncthreads();
    float bm = red[0];
    for (int i = 1; i < 8; ++i) bm = fmaxf(bm, red[i]);
    float e = (t < Nn) ? expf(v - bm) : 0.0f;
    float ssum = e;
    for (int off = 32; off; off >>= 1) ssum += __shfl_xor(ssum, off, 64);
    __syncthreads();
    if ((t & 63) == 0) red[t >> 6] = ssum;
    __syncthreads();
    float tot = 0.f;
    for (int i = 0; i < 8; ++i) tot += red[i];
    if (t < Nn) bvec[b * Nn + t] = e / tot;
}

// ---------------------------------------------------------------------------
__global__ __launch_bounds__(256) void q2n_k(const float* __restrict__ bvec,
                                             const float* __restrict__ nc,
                                             float* __restrict__ q2n) {
    int b = blockIdx.x;
    int d = blockIdx.y * 256 + threadIdx.x;
    const float* ncb = nc + (size_t)b * Nn * ENC;
    float acc = 0.f;
    for (int n = 0; n < Nn; ++n) acc = fmaf(bvec[b * Nn + n], ncb[(size_t)n * ENC + d], acc);
    q2n[b * ENC + d] = acc;
}

// ---------------------------------------------------------------------------
// raw[row] = b2 + sum_h tanh(sum_z part[z][row][h] + b1[h]) * W2[h]
__global__ __launch_bounds__(256) void final_reduce_k(const float* __restrict__ part,
                                                      const float* __restrict__ b1p,
                                                      const float* __restrict__ W2p,
                                                      const float* __restrict__ b2p,
                                                      float* __restrict__ raw) {
    constexpr int M = Bn * Nn;
    int wave = threadIdx.x >> 6, lane = threadIdx.x & 63;
    int row = blockIdx.x * 4 + wave;
    if (row >= M) return;
    float v0 = 0.f, v1 = 0.f;
#pragma unroll
    for (int s = 0; s < 4; ++s) {
        const float* pr = part + ((size_t)s * M + row) * 128;
        v0 += pr[lane];
        v1 += pr[lane + 64];
    }
    float p = tanhf(v0 + b1p[lane]) * W2p[lane] + tanhf(v1 + b1p[lane + 64]) * W2p[lane + 64];
    for (int off = 32; off; off >>= 1) p += __shfl_xor(p, off, 64);
    if (lane == 0) raw[row] = p + b2p[0];
}

// ---------------------------------------------------------------------------
__global__ __launch_bounds__(256) void predmax_k(const int* __restrict__ mask,
                                                 const float* __restrict__ raw,
                                                 float* __restrict__ out) {
    int idx = blockIdx.x * 4 + (threadIdx.x >> 6);
    int lane = threadIdx.x & 63;
    if (idx >= Bn * NCn) return;
    int b = idx / NCn, c = idx - b * NCn;
    const int* mrow = mask + ((size_t)b * NCn + c) * Nn;
    const float* rrow = raw + (size_t)b * Nn;
    float mx = -INFINITY;
    for (int n = lane; n < Nn; n += 64) {
        float v = mrow[n] ? rrow[n] : 0.0f;
        if (v == 0.0f) v = -1.0e6f;
        mx = fmaxf(mx, v);
    }
    for (int off = 32; off; off >>= 1) mx = fmaxf(mx, __shfl_xor(mx, off, 64));
    if (lane == 0) out[idx] = mx;
}

}  // namespace

extern "C" void kernel_launch(void* const* d_in, const int* in_sizes, int n_in,
                              void* d_out, int out_size, void* d_ws, size_t ws_size,
                              hipStream_t stream) {
    const float* nodes_glove  = (const float*)d_in[0];
    const float* query_glove  = (const float*)d_in[1];
    const float* adj          = (const float*)d_in[2];
    const int*   nodes_length = (const int*)d_in[3];
    const int*   maskp        = (const int*)d_in[4];
    const float* Wn = (const float*)d_in[5];
    const float* bn = (const float*)d_in[6];
    const float* Wq = (const float*)d_in[7];
    const float* bq = (const float*)d_in[8];
    const float* Wh = (const float*)d_in[9];
    const float* bh = (const float*)d_in[10];
    const float* Wc = (const float*)d_in[11];
    const float* bc = (const float*)d_in[12];
    const float* wa = (const float*)d_in[13];
    const float* W1 = (const float*)d_in[14];
    const float* b1 = (const float*)d_in[15];
    const float* W2 = (const float*)d_in[16];
    const float* b2 = (const float*)d_in[17];
    float* out = (float*)d_out;

    float* ws = (float*)d_ws;
    size_t off = 0;
    auto alloc = [&](size_t n) { float* p = ws + off; off += n; return p; };
    constexpr size_t ME = (size_t)Bn * Nn * ENC;   // 2,048,000
    float* nc   = alloc(ME);
    float* lh0  = alloc(ME);   // lh0+upd adjacent: reused as gbf [4000][2048] bf16
    float* upd  = alloc(ME);
    float* lh1  = alloc(ME);
    float* Asum = alloc(ME);   // fp32 [8][500][512]; then n2q; then final part buf
    float* qc   = alloc((size_t)Bn * Qn * ENC);
    float* rowmax = alloc(Bn * Nn);
    float* bvec   = alloc(Bn * Nn);
    float* q2n    = alloc(Bn * ENC);
    float* raw    = alloc(Bn * Nn);
    unsigned short* hmT = (unsigned short*)alloc((size_t)Bn * ENC * 512 / 2);
    unsigned short* WnT = (unsigned short*)alloc((size_t)ENC * 320 / 2);
    unsigned short* WqT = (unsigned short*)alloc((size_t)ENC * 320 / 2);
    unsigned short* WhT = (unsigned short*)alloc((size_t)ENC * ENC / 2);
    unsigned short* WcT = (unsigned short*)alloc((size_t)ENC * 2 * ENC / 2);
    alloc(16384);  // tail pad
    float* n2q  = Asum;                         // phase 2
    float* part = Asum;                         // phase 3 (after gbf consumed n2q)
    unsigned short* gbf = (unsigned short*)lh0; // spans lh0+upd (8.19M shorts)
    unsigned short* W1T = WnT;                  // spans WnT+WqT (327,680 >= 262,144)

    constexpr int M = Bn * Nn;  // 4000

    sum_adj_pad_k<<<dim3(Bn * Nn), 128, 0, stream>>>(adj, Asum);
    tcvt_k<<<dim3(16, 10), 256, 0, stream>>>(Wn, WnT, DIN, ENC, 320);
    tcvt_k<<<dim3(16, 10), 256, 0, stream>>>(Wq, WqT, DIN, ENC, 320);
    tcvt_k<<<dim3(16, 16), 256, 0, stream>>>(Wh, WhT, ENC, ENC, ENC);
    tcvt_k<<<dim3(16, 32), 256, 0, stream>>>(Wc, WcT, 2 * ENC, ENC, 2 * ENC);

    gemm_nc_k<<<dim3((M + 63) / 64, 8), 256, 0, stream>>>(nodes_glove, WnT, bn,
                                                          nodes_length, nc, lh0);
    gemm_qc_k<<<dim3((Bn * Qn + 63) / 64, 8), 256, 0, stream>>>(query_glove, WqT, bq, qc);
    // WnT/WqT dead from here; W1T (aliasing them) safe to build now.
    tcvt_k<<<dim3(4, 64), 256, 0, stream>>>(W1, W1T, 2048, 128, 2048);

    // 3 hops; cur starts at lh0 so after 3 swaps cur==lh1, freeing lh0+upd.
    float* cur = lh0;
    float* nxt = lh1;
    for (int h = 0; h < 3; ++h) {
        gemm_hm_k<<<dim3((M + 63) / 64, 8), 256, 0, stream>>>(cur, WhT, bh,
                                                              nodes_length, hmT);
        gemm_upd_k<<<dim3(8, 8, Bn), 256, 0, stream>>>(Asum, hmT, upd);
        gemm_att_k<<<dim3((M + 63) / 64, 8), 256, 0, stream>>>(upd, cur, WcT, bc,
                                                               nodes_length, nxt);
        float* tmp = cur; cur = nxt; nxt = tmp;
    }
    // cur == lh1 == final last_hop; lh0, upd, Asum now free.

    sim_fused_k<<<dim3(Bn, 125), 256, 0, stream>>>(cur, qc, wa, n2q, rowmax);
    bvec_k<<<dim3(Bn), 512, 0, stream>>>(rowmax, bvec);
    q2n_k<<<dim3(Bn, ENC / 256), 256, 0, stream>>>(bvec, nc, q2n);
    gbf_k<<<dim3(M), 256, 0, stream>>>(nc, n2q, q2n, gbf);       // consumes n2q
    gemm_final_k<<<dim3((M + 63) / 64, 2, 4), 256, 0, stream>>>(gbf, W1T, part);
    final_reduce_k<<<dim3((M + 3) / 4), 256, 0, stream>>>(part, b1, W2, b2, raw);
    predmax_k<<<dim3((Bn * NCn + 3) / 4), 256, 0, stream>>>(maskp, raw, out);
}

// Round 11
// 441.305 us; speedup vs baseline: 1.0542x; 1.0306x over previous
//
#include <hip/hip_runtime.h>
#include <hip/hip_bf16.h>
#include <math.h>
#include <stdint.h>

namespace {

constexpr int Bn  = 8;
constexpr int Nn  = 500;
constexpr int Qn  = 25;
constexpr int ENC = 512;
constexpr int DIN = 300;
constexpr int NCn = 70;
constexpr int NETn = 3;

typedef __attribute__((ext_vector_type(8))) short bf16x8_t;
typedef __attribute__((ext_vector_type(4))) float f32x4_t;

__device__ __forceinline__ unsigned short f2bf(float f) {
    union { __hip_bfloat16 b; unsigned short u; } r;
    r.b = __float2bfloat16(f);
    return r.u;
}
__device__ __forceinline__ bf16x8_t cvt8(float4 f0, float4 f1) {
    union { bf16x8_t v; __hip_bfloat162 b[4]; } r;
    r.b[0] = __float22bfloat162_rn(make_float2(f0.x, f0.y));
    r.b[1] = __float22bfloat162_rn(make_float2(f0.z, f0.w));
    r.b[2] = __float22bfloat162_rn(make_float2(f1.x, f1.y));
    r.b[3] = __float22bfloat162_rn(make_float2(f1.z, f1.w));
    return r.v;
}
__device__ __forceinline__ float sigmoidf_(float x) { return 1.0f / (1.0f + expf(-x)); }

// ---------------------------------------------------------------------------
// Asum[b][i][j] = sum_e adj[b,e,i,j], fp32, j padded 500->512 with zeros.
__global__ __launch_bounds__(128) void sum_adj_pad_k(const float* __restrict__ adj,
                                                     float* __restrict__ Asum) {
    int bi = blockIdx.x;
    int b = bi / Nn, i = bi - b * Nn;
    int j = threadIdx.x * 4;
    float4 s = make_float4(0.f, 0.f, 0.f, 0.f);
    if (j < Nn) {
#pragma unroll
        for (int e = 0; e < NETn; ++e) {
            const float* p = adj + (((size_t)(b * NETn + e) * Nn) + i) * Nn + j;
            float4 v = *(const float4*)p;
            s.x += v.x; s.y += v.y; s.z += v.z; s.w += v.w;
        }
    }
    *(float4*)(Asum + ((size_t)bi) * 512 + j) = s;
}

// ---------------------------------------------------------------------------
// Transpose + convert: in f32 [K][N] -> out bf16 [N][Kpad], zero-padded k>=K.
__global__ __launch_bounds__(256) void tcvt_k(const float* __restrict__ in,
                                              unsigned short* __restrict__ out,
                                              int K, int N, int Kpad) {
    __shared__ float tile[32][33];
    int tx = threadIdx.x & 31, ty = threadIdx.x >> 5;
    int n0 = blockIdx.x * 32, k0 = blockIdx.y * 32;
#pragma unroll
    for (int r = 0; r < 4; ++r) {
        int k = k0 + ty * 4 + r;
        int n = n0 + tx;
        tile[ty * 4 + r][tx] = (k < K && n < N) ? in[(size_t)k * N + n] : 0.0f;
    }
    __syncthreads();
#pragma unroll
    for (int r = 0; r < 4; ++r) {
        int n = n0 + ty * 4 + r;
        int k = k0 + tx;
        if (n < N && k < Kpad) out[(size_t)n * Kpad + k] = f2bf(tile[tx][ty * 4 + r]);
    }
}

// ---------------------------------------------------------------------------
// MFMA core (R4/R7/R8-proven structure): 64x64 tile, BK=32, 4 waves (2x2 of
// 32x32), double-buffered LDS, one barrier per 32-k step.
// AMODE 0: A fp32 row-major (optional A2 concat for k>=ksplit); boundary
//          k-chunks clamp loads at Klim.
// AMODE 1: A bf16 row-major (Abf), direct 16B loads.
// Bt: bf16 B^T row-major [n][k]. LDS 16B lines XOR-swizzled (conflict-free).
template <int AMODE>
__device__ __forceinline__ void mfma_core(
    const float* __restrict__ A, const float* __restrict__ A2,
    const unsigned short* __restrict__ Abf,
    int lda, int ksplit, int Klim,
    const unsigned short* __restrict__ Bt, int ldb,
    int m0, int n0, int K, int Mlim,
    unsigned short* As, unsigned short* Bts, f32x4_t acc[2][2]) {
    const int t = threadIdx.x;
    const int lane = t & 63;
    const int w = t >> 6;
    const int sm = t >> 2;                 // staging row 0..63
    const int sp = t & 3;                  // physical 16B line within row
    const int sq = sp ^ ((sm >> 1) & 3);   // logical k-chunk staged
    const int arow = m0 + sm;
    const bool rowok = arow < Mlim;
    const int wm = (w & 1) * 32, wn = (w >> 1) * 32;
    const int quad = lane >> 4, cidx = lane & 15;
    const int am0 = wm + cidx, am1 = wm + 16 + cidx;
    const int an0 = wn + cidx, an1 = wn + 16 + cidx;
    const int apo0 = am0 * 32 + (quad ^ ((am0 >> 1) & 3)) * 8;
    const int apo1 = am1 * 32 + (quad ^ ((am1 >> 1) & 3)) * 8;
    const int bpo0 = an0 * 32 + (quad ^ ((an0 >> 1) & 3)) * 8;
    const int bpo1 = an1 * 32 + (quad ^ ((an1 >> 1) & 3)) * 8;

    bf16x8_t ast, bst;
    auto stage = [&](int k0) {
        int kg = k0 + sq * 8;
        if (AMODE == 1) {
            bf16x8_t r = {0, 0, 0, 0, 0, 0, 0, 0};
            if (rowok) r = *(const bf16x8_t*)(Abf + (size_t)arow * lda + kg);
            ast = r;
        } else {
            float4 f0 = make_float4(0.f, 0.f, 0.f, 0.f);
            float4 f1 = make_float4(0.f, 0.f, 0.f, 0.f);
            if (rowok) {
                const float* src = (A2 != nullptr && kg >= ksplit)
                                       ? A2 + (size_t)arow * lda + (kg - ksplit)
                                       : A + (size_t)arow * lda + kg;
                if (kg + 8 <= Klim) {
                    f0 = *(const float4*)src;
                    f1 = *(const float4*)(src + 4);
                } else if (kg + 4 <= Klim) {
                    f0 = *(const float4*)src;
                }
            }
            ast = cvt8(f0, f1);
        }
        bst = *(const bf16x8_t*)(Bt + (size_t)(n0 + sm) * ldb + kg);
    };

    const int ktot = K >> 5;
    stage(0);
    *(bf16x8_t*)(As + t * 8) = ast;
    *(bf16x8_t*)(Bts + t * 8) = bst;
    for (int kt = 0; kt < ktot; ++kt) {
        __syncthreads();
        const int cur = (kt & 1) * 2048;
        const bool more = (kt + 1) < ktot;
        if (more) stage((kt + 1) << 5);
        bf16x8_t a0 = *(const bf16x8_t*)(As + cur + apo0);
        bf16x8_t a1 = *(const bf16x8_t*)(As + cur + apo1);
        bf16x8_t b0 = *(const bf16x8_t*)(Bts + cur + bpo0);
        bf16x8_t b1 = *(const bf16x8_t*)(Bts + cur + bpo1);
        acc[0][0] = __builtin_amdgcn_mfma_f32_16x16x32_bf16(a0, b0, acc[0][0], 0, 0, 0);
        acc[0][1] = __builtin_amdgcn_mfma_f32_16x16x32_bf16(a0, b1, acc[0][1], 0, 0, 0);
        acc[1][0] = __builtin_amdgcn_mfma_f32_16x16x32_bf16(a1, b0, acc[1][0], 0, 0, 0);
        acc[1][1] = __builtin_amdgcn_mfma_f32_16x16x32_bf16(a1, b1, acc[1][1], 0, 0, 0);
        if (more) {
            const int nxt = ((kt + 1) & 1) * 2048;
            *(bf16x8_t*)(As + nxt + t * 8) = ast;
            *(bf16x8_t*)(Bts + nxt + t * 8) = bst;
        }
    }
}

#define EPI_SETUP                                         \
    int t = threadIdx.x, lane = t & 63, w = t >> 6;       \
    int wm = (w & 1) * 32, wn = (w >> 1) * 32;            \
    int quad = lane >> 4, cidx = lane & 15;               \
    (void)wm; (void)wn; (void)quad; (void)cidx;

// ---------------------------------------------------------------------------
__global__ __launch_bounds__(256) void gemm_nc_k(const float* __restrict__ ng,
                                                 const unsigned short* __restrict__ WnT,
                                                 const float* __restrict__ bn,
                                                 const int* __restrict__ lens,
                                                 float* __restrict__ nc,
                                                 float* __restrict__ lh0) {
    __shared__ __align__(16) unsigned short As[4096], Bts[4096];
    f32x4_t z = {0.f, 0.f, 0.f, 0.f};
    f32x4_t acc[2][2] = {{z, z}, {z, z}};
    int m0 = blockIdx.x * 64, n0 = blockIdx.y * 64;
    mfma_core<0>(ng, nullptr, nullptr, DIN, 1 << 30, DIN, WnT, 320, m0, n0, 320,
                 Bn * Nn, As, Bts, acc);
    EPI_SETUP
#pragma unroll
    for (int nj = 0; nj < 2; ++nj) {
        int col = n0 + wn + nj * 16 + cidx;
        float bias = bn[col];
#pragma unroll
        for (int mi = 0; mi < 2; ++mi) {
#pragma unroll
            for (int r = 0; r < 4; ++r) {
                int row = m0 + wm + mi * 16 + quad * 4 + r;
                if (row < Bn * Nn) {
                    float tv = tanhf(acc[mi][nj][r] + bias);
                    int b = row / Nn, i = row - b * Nn;
                    float rm = (i < lens[b]) ? 1.0f : 0.0f;
                    nc[(size_t)row * ENC + col] = tv;
                    lh0[(size_t)row * ENC + col] = tv * rm;
                }
            }
        }
    }
}

// ---------------------------------------------------------------------------
__global__ __launch_bounds__(256) void gemm_qc_k(const float* __restrict__ qg,
                                                 const unsigned short* __restrict__ WqT,
                                                 const float* __restrict__ bq,
                                                 float* __restrict__ qc) {
    __shared__ __align__(16) unsigned short As[4096], Bts[4096];
    f32x4_t z = {0.f, 0.f, 0.f, 0.f};
    f32x4_t acc[2][2] = {{z, z}, {z, z}};
    int m0 = blockIdx.x * 64, n0 = blockIdx.y * 64;
    mfma_core<0>(qg, nullptr, nullptr, DIN, 1 << 30, DIN, WqT, 320, m0, n0, 320,
                 Bn * Qn, As, Bts, acc);
    EPI_SETUP
#pragma unroll
    for (int nj = 0; nj < 2; ++nj) {
        int col = n0 + wn + nj * 16 + cidx;
        float bias = bq[col];
#pragma unroll
        for (int mi = 0; mi < 2; ++mi) {
#pragma unroll
            for (int r = 0; r < 4; ++r) {
                int row = m0 + wm + mi * 16 + quad * 4 + r;
                if (row < Bn * Qn) qc[(size_t)row * ENC + col] = acc[mi][nj][r] + bias;
            }
        }
    }
}

// ---------------------------------------------------------------------------
// hm = (lh @ Wh + bh) * rowmask, row-major fp32 (consumed by sparse upd).
__global__ __launch_bounds__(256) void gemm_hm_k(const float* __restrict__ lh,
                                                 const unsigned short* __restrict__ WhT,
                                                 const float* __restrict__ bh,
                                                 const int* __restrict__ lens,
                                                 float* __restrict__ hm) {
    __shared__ __align__(16) unsigned short As[4096], Bts[4096];
    f32x4_t z = {0.f, 0.f, 0.f, 0.f};
    f32x4_t acc[2][2] = {{z, z}, {z, z}};
    int m0 = blockIdx.x * 64, n0 = blockIdx.y * 64;
    mfma_core<0>(lh, nullptr, nullptr, ENC, 1 << 30, ENC, WhT, ENC, m0, n0, ENC,
                 Bn * Nn, As, Bts, acc);
    EPI_SETUP
#pragma unroll
    for (int nj = 0; nj < 2; ++nj) {
        int col = n0 + wn + nj * 16 + cidx;
        float bias = bh[col];
#pragma unroll
        for (int mi = 0; mi < 2; ++mi) {
#pragma unroll
            for (int r = 0; r < 4; ++r) {
                int row = m0 + wm + mi * 16 + quad * 4 + r;
                if (row < Bn * Nn) {
                    int b = row / Nn, i = row - b * Nn;
                    float rm = (i < lens[b]) ? 1.0f : 0.0f;
                    hm[(size_t)row * ENC + col] = (acc[mi][nj][r] + bias) * rm;
                }
            }
        }
    }
}

// ---------------------------------------------------------------------------
// Sparse aggregation: upd[b,i,:] = hm[b,i,:] + sum_j Asum[b,i,j]*hm[b,j,:].
// adj density ~2% -> ~30 nonzeros/row. One wave per row; ballot mask walk
// (wave-uniform, no divergence), 2 rows per iteration for load ILP.
// grid 1000, block 256 (4 waves).
__global__ __launch_bounds__(256) void upd_sparse_k(const float* __restrict__ Asum,
                                                    const float* __restrict__ hm,
                                                    float* __restrict__ upd) {
    int wv = threadIdx.x >> 6, lane = threadIdx.x & 63;
    int row = blockIdx.x * 4 + wv;            // 0..3999
    int b = row / Nn, i = row - b * Nn;
    const float* arow = Asum + (size_t)row * 512;
    const float* hmb = hm + (size_t)b * Nn * ENC;
    int d0 = lane * 8;

    const float* hrow = hmb + (size_t)i * ENC + d0;
    float4 h0 = *(const float4*)hrow;
    float4 h1 = *(const float4*)(hrow + 4);
    float acc[8] = {h0.x, h0.y, h0.z, h0.w, h1.x, h1.y, h1.z, h1.w};

#pragma unroll
    for (int c = 0; c < 8; ++c) {
        int j = c * 64 + lane;
        float val = (j < Nn) ? arow[j] : 0.0f;
        unsigned long long mask = __ballot(val != 0.0f);
        while (mask) {
            int b0 = __ffsll((unsigned long long)mask) - 1;
            unsigned long long m2 = mask & (mask - 1);
            int b1 = -1;
            if (m2) { b1 = __ffsll((unsigned long long)m2) - 1; m2 &= m2 - 1; }
            mask = m2;
            float v0 = __shfl(val, b0, 64);
            const float* p0 = hmb + (size_t)(c * 64 + b0) * ENC + d0;
            float4 x0 = *(const float4*)p0;
            float4 x1 = *(const float4*)(p0 + 4);
            float v1 = 0.0f;
            float4 y0 = make_float4(0.f, 0.f, 0.f, 0.f);
            float4 y1 = make_float4(0.f, 0.f, 0.f, 0.f);
            if (b1 >= 0) {
                v1 = __shfl(val, b1, 64);
                const float* p1 = hmb + (size_t)(c * 64 + b1) * ENC + d0;
                y0 = *(const float4*)p1;
                y1 = *(const float4*)(p1 + 4);
            }
            acc[0] += v0 * x0.x + v1 * y0.x;
            acc[1] += v0 * x0.y + v1 * y0.y;
            acc[2] += v0 * x0.z + v1 * y0.z;
            acc[3] += v0 * x0.w + v1 * y0.w;
            acc[4] += v0 * x1.x + v1 * y1.x;
            acc[5] += v0 * x1.y + v1 * y1.y;
            acc[6] += v0 * x1.z + v1 * y1.z;
            acc[7] += v0 * x1.w + v1 * y1.w;
        }
    }
    float* urow = upd + (size_t)row * ENC + d0;
    *(float4*)urow = make_float4(acc[0], acc[1], acc[2], acc[3]);
    *(float4*)(urow + 4) = make_float4(acc[4], acc[5], acc[6], acc[7]);
}

// ---------------------------------------------------------------------------
__global__ __launch_bounds__(256) void gemm_att_k(const float* __restrict__ upd,
                                                  const float* __restrict__ lh,
                                                  const unsigned short* __restrict__ WcT,
                                                  const float* __restrict__ bc,
                                                  const int* __restrict__ lens,
                                                  float* __restrict__ lh_out) {
    __shared__ __align__(16) unsigned short As[4096], Bts[4096];
    f32x4_t z = {0.f, 0.f, 0.f, 0.f};
    f32x4_t acc[2][2] = {{z, z}, {z, z}};
    int m0 = blockIdx.x * 64, n0 = blockIdx.y * 64;
    mfma_core<0>(upd, lh, nullptr, ENC, ENC, 1 << 30, WcT, 2 * ENC, m0, n0, 2 * ENC,
                 Bn * Nn, As, Bts, acc);
    EPI_SETUP
#pragma unroll
    for (int nj = 0; nj < 2; ++nj) {
        int col = n0 + wn + nj * 16 + cidx;
        float bias = bc[col];
#pragma unroll
        for (int mi = 0; mi < 2; ++mi) {
#pragma unroll
            for (int r = 0; r < 4; ++r) {
                int row = m0 + wm + mi * 16 + quad * 4 + r;
                if (row < Bn * Nn) {
                    int b = row / Nn, i = row - b * Nn;
                    float rm = (i < lens[b]) ? 1.0f : 0.0f;
                    float a = sigmoidf_(acc[mi][nj][r] + bias) * rm;
                    size_t off = (size_t)row * ENC + col;
                    lh_out[off] = a * tanhf(upd[off]) + (1.0f - a) * lh[off];
                }
            }
        }
    }
}

// ---------------------------------------------------------------------------
// Materialize g = [nc | n2q | nc*n2q | nc*q2n] as bf16 [4000][2048].
__global__ __launch_bounds__(256) void gbf_k(const float* __restrict__ nc,
                                             const float* __restrict__ n2q,
                                             const float* __restrict__ q2n,
                                             unsigned short* __restrict__ gbf) {
    int row = blockIdx.x;
    int b = row / Nn;
    int t = threadIdx.x;
    int seg = t >> 6;          // 0..3
    int d = (t & 63) * 8;
    size_t off = (size_t)row * ENC + d;
    float4 a0, a1;
    if (seg == 0) {
        a0 = *(const float4*)(nc + off); a1 = *(const float4*)(nc + off + 4);
    } else if (seg == 1) {
        a0 = *(const float4*)(n2q + off); a1 = *(const float4*)(n2q + off + 4);
    } else if (seg == 2) {
        float4 x0 = *(const float4*)(nc + off), x1 = *(const float4*)(nc + off + 4);
        float4 y0 = *(const float4*)(n2q + off), y1 = *(const float4*)(n2q + off + 4);
        a0 = make_float4(x0.x * y0.x, x0.y * y0.y, x0.z * y0.z, x0.w * y0.w);
        a1 = make_float4(x1.x * y1.x, x1.y * y1.y, x1.z * y1.z, x1.w * y1.w);
    } else {
        float4 x0 = *(const float4*)(nc + off), x1 = *(const float4*)(nc + off + 4);
        const float* qp = q2n + (size_t)b * ENC + d;
        float4 y0 = *(const float4*)qp, y1 = *(const float4*)(qp + 4);
        a0 = make_float4(x0.x * y0.x, x0.y * y0.y, x0.z * y0.z, x0.w * y0.w);
        a1 = make_float4(x1.x * y1.x, x1.y * y1.y, x1.z * y1.z, x1.w * y1.w);
    }
    *(bf16x8_t*)(gbf + (size_t)row * 2048 + seg * 512 + d) = cvt8(a0, a1);
}

// ---------------------------------------------------------------------------
// g @ W1 split-K partials via MFMA; z = K-slice in [0,4) (512 wide).
__global__ __launch_bounds__(256) void gemm_final_k(const unsigned short* __restrict__ gbf,
                                                    const unsigned short* __restrict__ W1T,
                                                    float* __restrict__ part) {
    __shared__ __align__(16) unsigned short As[4096], Bts[4096];
    f32x4_t z4 = {0.f, 0.f, 0.f, 0.f};
    f32x4_t acc[2][2] = {{z4, z4}, {z4, z4}};
    int zz = blockIdx.z;
    int m0 = blockIdx.x * 64, n0 = blockIdx.y * 64;
    mfma_core<1>(nullptr, nullptr, gbf + zz * 512, 2048, 1 << 30, 1 << 30,
                 W1T + zz * 512, 2048, m0, n0, 512, Bn * Nn, As, Bts, acc);
    EPI_SETUP
    constexpr int M = Bn * Nn;
#pragma unroll
    for (int nj = 0; nj < 2; ++nj) {
        int col = n0 + wn + nj * 16 + cidx;   // < 128
#pragma unroll
        for (int mi = 0; mi < 2; ++mi) {
#pragma unroll
            for (int r = 0; r < 4; ++r) {
                int row = m0 + wm + mi * 16 + quad * 4 + r;
                if (row < M) part[((size_t)zz * M + row) * 128 + col] = acc[mi][nj][r];
            }
        }
    }
}

// ---------------------------------------------------------------------------
// Fused sim -> softmax(q) -> nodes2query + rowmax.  One wave per n-row.
__global__ __launch_bounds__(256) void sim_fused_k(const float* __restrict__ lh,
                                                   const float* __restrict__ qc,
                                                   const float* __restrict__ wa,
                                                   float* __restrict__ n2q,
                                                   float* __restrict__ rowmax) {
    __shared__ float qcs[Qn * ENC];   // 51.2 KB
    __shared__ float qdot[32];
    int b = blockIdx.x;
    int t = threadIdx.x;
    const float* qcb = qc + (size_t)b * Qn * ENC;
    for (int i = t * 4; i < Qn * ENC; i += 1024) *(float4*)&qcs[i] = *(const float4*)&qcb[i];
    __syncthreads();
    {
        int q = t >> 3, j = t & 7;
        if (q < Qn) {
            float s = 0.f;
            for (int k = 0; k < 64; ++k) {
                int d = j + 8 * k;
                s += qcs[q * ENC + d] * wa[ENC + d];
            }
            s += __shfl_xor(s, 1, 64);
            s += __shfl_xor(s, 2, 64);
            s += __shfl_xor(s, 4, 64);
            if (j == 0) qdot[q] = s;
        }
    }
    __syncthreads();

    int wv = t >> 6, lane = t & 63;
    int n = blockIdx.y * 4 + wv;
    int dA = lane * 4;
    int dB = 256 + lane * 4;
    const float* lrow = lh + ((size_t)b * Nn + n) * ENC;
    float4 la = *(const float4*)(lrow + dA);
    float4 lb = *(const float4*)(lrow + dB);
    float lv[8] = {la.x, la.y, la.z, la.w, lb.x, lb.y, lb.z, lb.w};
    float ndp = 0.f;
    float lvs[8];
#pragma unroll
    for (int j = 0; j < 4; ++j) {
        ndp += lv[j] * wa[dA + j];
        lvs[j] = lv[j] * wa[2 * ENC + dA + j];
        ndp += lv[4 + j] * wa[dB + j];
        lvs[4 + j] = lv[4 + j] * wa[2 * ENC + dB + j];
    }
#pragma unroll
    for (int off = 32; off; off >>= 1) ndp += __shfl_xor(ndp, off, 64);

    float s_[Qn];
#pragma unroll
    for (int q = 0; q < Qn; ++q) {
        float4 qa = *(const float4*)(qcs + q * ENC + dA);
        float4 qb = *(const float4*)(qcs + q * ENC + dB);
        s_[q] = lvs[0] * qa.x + lvs[1] * qa.y + lvs[2] * qa.z + lvs[3] * qa.w +
                lvs[4] * qb.x + lvs[5] * qb.y + lvs[6] * qb.z + lvs[7] * qb.w;
    }
#pragma unroll
    for (int q = 0; q < Qn; ++q) {
#pragma unroll
        for (int off = 32; off; off >>= 1) s_[q] += __shfl_xor(s_[q], off, 64);
    }
    float mx = -INFINITY;
#pragma unroll
    for (int q = 0; q < Qn; ++q) {
        s_[q] += ndp + qdot[q];
        mx = fmaxf(mx, s_[q]);
    }
    float sum = 0.f;
#pragma unroll
    for (int q = 0; q < Qn; ++q) { s_[q] = expf(s_[q] - mx); sum += s_[q]; }
    float inv = 1.0f / sum;
    float o[8] = {};
#pragma unroll
    for (int q = 0; q < Qn; ++q) {
        float4 qa = *(const float4*)(qcs + q * ENC + dA);
        float4 qb = *(const float4*)(qcs + q * ENC + dB);
        float p = s_[q] * inv;
        o[0] += p * qa.x; o[1] += p * qa.y; o[2] += p * qa.z; o[3] += p * qa.w;
        o[4] += p * qb.x; o[5] += p * qb.y; o[6] += p * qb.z; o[7] += p * qb.w;
    }
    float* orow = n2q + ((size_t)b * Nn + n) * ENC;
    *(float4*)(orow + dA) = make_float4(o[0], o[1], o[2], o[3]);
    *(float4*)(orow + dB) = make_float4(o[4], o[5], o[6], o[7]);
    if (lane == 0) rowmax[b * Nn + n] = mx;
}

// ---------------------------------------------------------------------------
__global__ __launch_bounds__(512) void bvec_k(const float* __restrict__ rowmax,
                                              float* __restrict__ bvec) {
    __shared__ float red[8];
    int b = blockIdx.x, t = threadIdx.x;
    float v = (t < Nn) ? rowmax[b * Nn + t] : -INFINITY;
    float m = v;
    for (int off = 32; off; off >>= 1) m = fmaxf(m, __shfl_xor(m, off, 64));
    if ((t & 63) == 0) red[t >> 6] = m;
    __syncthreads();
    float bm = red[0];
    for (int i = 1; i < 8; ++i) bm = fmaxf(bm, red[i]);
    float e = (t < Nn) ? expf(v - bm) : 0.0f;
    float ssum = e;
    for (int off = 32; off; off >>= 1) ssum += __shfl_xor(ssum, off, 64);
    __syncthreads();
    if ((t & 63) == 0) red[t >> 6] = ssum;
    __syncthreads();
    float tot = 0.f;
    for (int i = 0; i < 8; ++i) tot += red[i];
    if (t < Nn) bvec[b * Nn + t] = e / tot;
}

// ---------------------------------------------------------------------------
__global__ __launch_bounds__(256) void q2n_k(const float* __restrict__ bvec,
                                             const float* __restrict__ nc,
                                             float* __restrict__ q2n) {
    int b = blockIdx.x;
    int d = blockIdx.y * 256 + threadIdx.x;
    const float* ncb = nc + (size_t)b * Nn * ENC;
    float acc = 0.f;
    for (int n = 0; n < Nn; ++n) acc = fmaf(bvec[b * Nn + n], ncb[(size_t)n * ENC + d], acc);
    q2n[b * ENC + d] = acc;
}

// ---------------------------------------------------------------------------
// raw[row] = b2 + sum_h tanh(sum_z part[z][row][h] + b1[h]) * W2[h]
__global__ __launch_bounds__(256) void final_reduce_k(const float* __restrict__ part,
                                                      const float* __restrict__ b1p,
                                                      const float* __restrict__ W2p,
                                                      const float* __restrict__ b2p,
                                                      float* __restrict__ raw) {
    constexpr int M = Bn * Nn;
    int wave = threadIdx.x >> 6, lane = threadIdx.x & 63;
    int row = blockIdx.x * 4 + wave;
    if (row >= M) return;
    float v0 = 0.f, v1 = 0.f;
#pragma unroll
    for (int s = 0; s < 4; ++s) {
        const float* pr = part + ((size_t)s * M + row) * 128;
        v0 += pr[lane];
        v1 += pr[lane + 64];
    }
    float p = tanhf(v0 + b1p[lane]) * W2p[lane] + tanhf(v1 + b1p[lane + 64]) * W2p[lane + 64];
    for (int off = 32; off; off >>= 1) p += __shfl_xor(p, off, 64);
    if (lane == 0) raw[row] = p + b2p[0];
}

// ---------------------------------------------------------------------------
__global__ __launch_bounds__(256) void predmax_k(const int* __restrict__ mask,
                                                 const float* __restrict__ raw,
                                                 float* __restrict__ out) {
    int idx = blockIdx.x * 4 + (threadIdx.x >> 6);
    int lane = threadIdx.x & 63;
    if (idx >= Bn * NCn) return;
    int b = idx / NCn, c = idx - b * NCn;
    const int* mrow = mask + ((size_t)b * NCn + c) * Nn;
    const float* rrow = raw + (size_t)b * Nn;
    float mx = -INFINITY;
    for (int n = lane; n < Nn; n += 64) {
        float v = mrow[n] ? rrow[n] : 0.0f;
        if (v == 0.0f) v = -1.0e6f;
        mx = fmaxf(mx, v);
    }
    for (int off = 32; off; off >>= 1) mx = fmaxf(mx, __shfl_xor(mx, off, 64));
    if (lane == 0) out[idx] = mx;
}

}  // namespace

extern "C" void kernel_launch(void* const* d_in, const int* in_sizes, int n_in,
                              void* d_out, int out_size, void* d_ws, size_t ws_size,
                              hipStream_t stream) {
    const float* nodes_glove  = (const float*)d_in[0];
    const float* query_glove  = (const float*)d_in[1];
    const float* adj          = (const float*)d_in[2];
    const int*   nodes_length = (const int*)d_in[3];
    const int*   maskp        = (const int*)d_in[4];
    const float* Wn = (const float*)d_in[5];
    const float* bn = (const float*)d_in[6];
    const float* Wq = (const float*)d_in[7];
    const float* bq = (const float*)d_in[8];
    const float* Wh = (const float*)d_in[9];
    const float* bh = (const float*)d_in[10];
    const float* Wc = (const float*)d_in[11];
    const float* bc = (const float*)d_in[12];
    const float* wa = (const float*)d_in[13];
    const float* W1 = (const float*)d_in[14];
    const float* b1 = (const float*)d_in[15];
    const float* W2 = (const float*)d_in[16];
    const float* b2 = (const float*)d_in[17];
    float* out = (float*)d_out;

    float* ws = (float*)d_ws;
    size_t off = 0;
    auto alloc = [&](size_t n) { float* p = ws + off; off += n; return p; };
    constexpr size_t ME = (size_t)Bn * Nn * ENC;   // 2,048,000
    float* nc   = alloc(ME);
    float* lh0  = alloc(ME);   // lh0+upd adjacent: reused as gbf [4000][2048] bf16
    float* upd  = alloc(ME);
    float* lh1  = alloc(ME);
    float* Asum = alloc(ME);   // fp32 [8][500][512]; then n2q; then final part buf
    float* hm   = alloc(ME);   // row-major fp32 hm (sparse-upd consumer)
    float* qc   = alloc((size_t)Bn * Qn * ENC);
    float* rowmax = alloc(Bn * Nn);
    float* bvec   = alloc(Bn * Nn);
    float* q2n    = alloc(Bn * ENC);
    float* raw    = alloc(Bn * Nn);
    unsigned short* WnT = (unsigned short*)alloc((size_t)ENC * 320 / 2);
    unsigned short* WqT = (unsigned short*)alloc((size_t)ENC * 320 / 2);
    unsigned short* WhT = (unsigned short*)alloc((size_t)ENC * ENC / 2);
    unsigned short* WcT = (unsigned short*)alloc((size_t)ENC * 2 * ENC / 2);
    alloc(16384);  // tail pad
    float* n2q  = Asum;                         // phase 2
    float* part = Asum;                         // phase 3 (after gbf consumed n2q)
    unsigned short* gbf = (unsigned short*)lh0; // spans lh0+upd (8.19M shorts)
    unsigned short* W1T = WnT;                  // spans WnT+WqT (327,680 >= 262,144)

    constexpr int M = Bn * Nn;  // 4000

    sum_adj_pad_k<<<dim3(Bn * Nn), 128, 0, stream>>>(adj, Asum);
    tcvt_k<<<dim3(16, 10), 256, 0, stream>>>(Wn, WnT, DIN, ENC, 320);
    tcvt_k<<<dim3(16, 10), 256, 0, stream>>>(Wq, WqT, DIN, ENC, 320);
    tcvt_k<<<dim3(16, 16), 256, 0, stream>>>(Wh, WhT, ENC, ENC, ENC);
    tcvt_k<<<dim3(16, 32), 256, 0, stream>>>(Wc, WcT, 2 * ENC, ENC, 2 * ENC);

    gemm_nc_k<<<dim3((M + 63) / 64, 8), 256, 0, stream>>>(nodes_glove, WnT, bn,
                                                          nodes_length, nc, lh0);
    gemm_qc_k<<<dim3((Bn * Qn + 63) / 64, 8), 256, 0, stream>>>(query_glove, WqT, bq, qc);
    // WnT/WqT dead from here; W1T (aliasing them) safe to build now.
    tcvt_k<<<dim3(4, 64), 256, 0, stream>>>(W1, W1T, 2048, 128, 2048);

    // 3 hops; cur starts at lh0 so after 3 swaps cur==lh1, freeing lh0+upd.
    float* cur = lh0;
    float* nxt = lh1;
    for (int h = 0; h < 3; ++h) {
        gemm_hm_k<<<dim3((M + 63) / 64, 8), 256, 0, stream>>>(cur, WhT, bh,
                                                              nodes_length, hm);
        upd_sparse_k<<<dim3(M / 4), 256, 0, stream>>>(Asum, hm, upd);
        gemm_att_k<<<dim3((M + 63) / 64, 8), 256, 0, stream>>>(upd, cur, WcT, bc,
                                                               nodes_length, nxt);
        float* tmp = cur; cur = nxt; nxt = tmp;
    }
    // cur == lh1 == final last_hop; lh0, upd, Asum now free.

    sim_fused_k<<<dim3(Bn, 125), 256, 0, stream>>>(cur, qc, wa, n2q, rowmax);
    bvec_k<<<dim3(Bn), 512, 0, stream>>>(rowmax, bvec);
    q2n_k<<<dim3(Bn, ENC / 256), 256, 0, stream>>>(bvec, nc, q2n);
    gbf_k<<<dim3(M), 256, 0, stream>>>(nc, n2q, q2n, gbf);       // consumes n2q
    gemm_final_k<<<dim3((M + 63) / 64, 2, 4), 256, 0, stream>>>(gbf, W1T, part);
    final_reduce_k<<<dim3((M + 3) / 4), 256, 0, stream>>>(part, b1, W2, b2, raw);
    predmax_k<<<dim3((Bn * NCn + 3) / 4), 256, 0, stream>>>(maskp, raw, out);
}

// Round 12
// 375.683 us; speedup vs baseline: 1.2384x; 1.1747x over previous
//
#include <hip/hip_runtime.h>
#include <hip/hip_bf16.h>
#include <math.h>
#include <stdint.h>

namespace {

constexpr int Bn  = 8;
constexpr int Nn  = 500;
constexpr int Qn  = 25;
constexpr int ENC = 512;
constexpr int DIN = 300;
constexpr int NCn = 70;
constexpr int NETn = 3;

typedef __attribute__((ext_vector_type(8))) short bf16x8_t;
typedef __attribute__((ext_vector_type(4))) float f32x4_t;

__device__ __forceinline__ unsigned short f2bf(float f) {
    union { __hip_bfloat16 b; unsigned short u; } r;
    r.b = __float2bfloat16(f);
    return r.u;
}
__device__ __forceinline__ bf16x8_t cvt8(float4 f0, float4 f1) {
    union { bf16x8_t v; __hip_bfloat162 b[4]; } r;
    r.b[0] = __float22bfloat162_rn(make_float2(f0.x, f0.y));
    r.b[1] = __float22bfloat162_rn(make_float2(f0.z, f0.w));
    r.b[2] = __float22bfloat162_rn(make_float2(f1.x, f1.y));
    r.b[3] = __float22bfloat162_rn(make_float2(f1.z, f1.w));
    return r.v;
}
__device__ __forceinline__ float bf2f(unsigned short h) {
    unsigned int u = ((unsigned int)h) << 16;
    return __builtin_bit_cast(float, u);
}
__device__ __forceinline__ float sigmoidf_(float x) { return 1.0f / (1.0f + expf(-x)); }

// ---------------------------------------------------------------------------
// Asum[b][i][j] = sum_e adj[b,e,i,j], fp32, j padded 500->512 with zeros.
__global__ __launch_bounds__(128) void sum_adj_pad_k(const float* __restrict__ adj,
                                                     float* __restrict__ Asum) {
    int bi = blockIdx.x;
    int b = bi / Nn, i = bi - b * Nn;
    int j = threadIdx.x * 4;
    float4 s = make_float4(0.f, 0.f, 0.f, 0.f);
    if (j < Nn) {
#pragma unroll
        for (int e = 0; e < NETn; ++e) {
            const float* p = adj + (((size_t)(b * NETn + e) * Nn) + i) * Nn + j;
            float4 v = *(const float4*)p;
            s.x += v.x; s.y += v.y; s.z += v.z; s.w += v.w;
        }
    }
    *(float4*)(Asum + ((size_t)bi) * 512 + j) = s;
}

// ---------------------------------------------------------------------------
// All 5 weight transposes in one launch. z selects matrix; idle blocks exit.
// in f32 [K][N] -> out bf16 [N][Kpad], zero-padded k>=K.
__global__ __launch_bounds__(256) void tcvt_all_k(
    const float* __restrict__ Wn, const float* __restrict__ Wq,
    const float* __restrict__ Wh, const float* __restrict__ Wc,
    const float* __restrict__ W1,
    unsigned short* __restrict__ WnT, unsigned short* __restrict__ WqT,
    unsigned short* __restrict__ WhT, unsigned short* __restrict__ WcT,
    unsigned short* __restrict__ W1T) {
    __shared__ float tile[32][33];
    int sel = blockIdx.z;
    const float* in; unsigned short* out; int K, N, Kpad;
    if (sel == 0)      { in = Wn; out = WnT; K = DIN;  N = ENC; Kpad = 320;  }
    else if (sel == 1) { in = Wq; out = WqT; K = DIN;  N = ENC; Kpad = 320;  }
    else if (sel == 2) { in = Wh; out = WhT; K = ENC;  N = ENC; Kpad = 512;  }
    else if (sel == 3) { in = Wc; out = WcT; K = 1024; N = ENC; Kpad = 1024; }
    else               { in = W1; out = W1T; K = 2048; N = 128; Kpad = 2048; }
    int n0 = blockIdx.x * 32, k0 = blockIdx.y * 32;
    if (n0 >= N || k0 >= Kpad) return;
    int tx = threadIdx.x & 31, ty = threadIdx.x >> 5;
#pragma unroll
    for (int r = 0; r < 4; ++r) {
        int k = k0 + ty * 4 + r;
        int n = n0 + tx;
        tile[ty * 4 + r][tx] = (k < K && n < N) ? in[(size_t)k * N + n] : 0.0f;
    }
    __syncthreads();
#pragma unroll
    for (int r = 0; r < 4; ++r) {
        int n = n0 + ty * 4 + r;
        int k = k0 + tx;
        if (n < N && k < Kpad) out[(size_t)n * Kpad + k] = f2bf(tile[tx][ty * 4 + r]);
    }
}

// ---------------------------------------------------------------------------
// MFMA core: 64x64 tile, BK=32, 4 waves (2x2 of 32x32), double-buffered LDS.
// AMODE 0: A fp32 row-major (A2 concat for k>=ksplit); k-chunks clamp at Klim.
// AMODE 1: A bf16 row-major (Abf; optional Abf2 concat for k>=ksplit).
// Bt: bf16 B^T row-major [n][k]. LDS 16B lines XOR-swizzled (conflict-free).
template <int AMODE>
__device__ __forceinline__ void mfma_core(
    const float* __restrict__ A, const float* __restrict__ A2,
    const unsigned short* __restrict__ Abf, const unsigned short* __restrict__ Abf2,
    int lda, int ksplit, int Klim,
    const unsigned short* __restrict__ Bt, int ldb,
    int m0, int n0, int K, int Mlim,
    unsigned short* As, unsigned short* Bts, f32x4_t acc[2][2]) {
    const int t = threadIdx.x;
    const int lane = t & 63;
    const int w = t >> 6;
    const int sm = t >> 2;                 // staging row 0..63
    const int sp = t & 3;                  // physical 16B line within row
    const int sq = sp ^ ((sm >> 1) & 3);   // logical k-chunk staged
    const int arow = m0 + sm;
    const bool rowok = arow < Mlim;
    const int wm = (w & 1) * 32, wn = (w >> 1) * 32;
    const int quad = lane >> 4, cidx = lane & 15;
    const int am0 = wm + cidx, am1 = wm + 16 + cidx;
    const int an0 = wn + cidx, an1 = wn + 16 + cidx;
    const int apo0 = am0 * 32 + (quad ^ ((am0 >> 1) & 3)) * 8;
    const int apo1 = am1 * 32 + (quad ^ ((am1 >> 1) & 3)) * 8;
    const int bpo0 = an0 * 32 + (quad ^ ((an0 >> 1) & 3)) * 8;
    const int bpo1 = an1 * 32 + (quad ^ ((an1 >> 1) & 3)) * 8;

    bf16x8_t ast, bst;
    auto stage = [&](int k0) {
        int kg = k0 + sq * 8;
        if (AMODE == 1) {
            bf16x8_t r = {0, 0, 0, 0, 0, 0, 0, 0};
            if (rowok) {
                const unsigned short* src =
                    (Abf2 != nullptr && kg >= ksplit)
                        ? Abf2 + (size_t)arow * lda + (kg - ksplit)
                        : Abf + (size_t)arow * lda + kg;
                r = *(const bf16x8_t*)src;
            }
            ast = r;
        } else {
            float4 f0 = make_float4(0.f, 0.f, 0.f, 0.f);
            float4 f1 = make_float4(0.f, 0.f, 0.f, 0.f);
            if (rowok) {
                const float* src = (A2 != nullptr && kg >= ksplit)
                                       ? A2 + (size_t)arow * lda + (kg - ksplit)
                                       : A + (size_t)arow * lda + kg;
                if (kg + 8 <= Klim) {
                    f0 = *(const float4*)src;
                    f1 = *(const float4*)(src + 4);
                } else if (kg + 4 <= Klim) {
                    f0 = *(const float4*)src;
                }
            }
            ast = cvt8(f0, f1);
        }
        bst = *(const bf16x8_t*)(Bt + (size_t)(n0 + sm) * ldb + kg);
    };

    const int ktot = K >> 5;
    stage(0);
    *(bf16x8_t*)(As + t * 8) = ast;
    *(bf16x8_t*)(Bts + t * 8) = bst;
    for (int kt = 0; kt < ktot; ++kt) {
        __syncthreads();
        const int cur = (kt & 1) * 2048;
        const bool more = (kt + 1) < ktot;
        if (more) stage((kt + 1) << 5);
        bf16x8_t a0 = *(const bf16x8_t*)(As + cur + apo0);
        bf16x8_t a1 = *(const bf16x8_t*)(As + cur + apo1);
        bf16x8_t b0 = *(const bf16x8_t*)(Bts + cur + bpo0);
        bf16x8_t b1 = *(const bf16x8_t*)(Bts + cur + bpo1);
        acc[0][0] = __builtin_amdgcn_mfma_f32_16x16x32_bf16(a0, b0, acc[0][0], 0, 0, 0);
        acc[0][1] = __builtin_amdgcn_mfma_f32_16x16x32_bf16(a0, b1, acc[0][1], 0, 0, 0);
        acc[1][0] = __builtin_amdgcn_mfma_f32_16x16x32_bf16(a1, b0, acc[1][0], 0, 0, 0);
        acc[1][1] = __builtin_amdgcn_mfma_f32_16x16x32_bf16(a1, b1, acc[1][1], 0, 0, 0);
        if (more) {
            const int nxt = ((kt + 1) & 1) * 2048;
            *(bf16x8_t*)(As + nxt + t * 8) = ast;
            *(bf16x8_t*)(Bts + nxt + t * 8) = bst;
        }
    }
}

#define EPI_SETUP                                         \
    int t = threadIdx.x, lane = t & 63, w = t >> 6;       \
    int wm = (w & 1) * 32, wn = (w >> 1) * 32;            \
    int quad = lane >> 4, cidx = lane & 15;               \
    (void)wm; (void)wn; (void)quad; (void)cidx;

// ---------------------------------------------------------------------------
// nc = tanh(ng@Wn+bn) fp32;  lh0 = bf16(nc * rowmask)
__global__ __launch_bounds__(256) void gemm_nc_k(const float* __restrict__ ng,
                                                 const unsigned short* __restrict__ WnT,
                                                 const float* __restrict__ bn,
                                                 const int* __restrict__ lens,
                                                 float* __restrict__ nc,
                                                 unsigned short* __restrict__ lh0) {
    __shared__ __align__(16) unsigned short As[4096], Bts[4096];
    f32x4_t z = {0.f, 0.f, 0.f, 0.f};
    f32x4_t acc[2][2] = {{z, z}, {z, z}};
    int m0 = blockIdx.x * 64, n0 = blockIdx.y * 64;
    mfma_core<0>(ng, nullptr, nullptr, nullptr, DIN, 1 << 30, DIN, WnT, 320,
                 m0, n0, 320, Bn * Nn, As, Bts, acc);
    EPI_SETUP
#pragma unroll
    for (int nj = 0; nj < 2; ++nj) {
        int col = n0 + wn + nj * 16 + cidx;
        float bias = bn[col];
#pragma unroll
        for (int mi = 0; mi < 2; ++mi) {
#pragma unroll
            for (int r = 0; r < 4; ++r) {
                int row = m0 + wm + mi * 16 + quad * 4 + r;
                if (row < Bn * Nn) {
                    float tv = tanhf(acc[mi][nj][r] + bias);
                    int b = row / Nn, i = row - b * Nn;
                    float rm = (i < lens[b]) ? 1.0f : 0.0f;
                    nc[(size_t)row * ENC + col] = tv;
                    lh0[(size_t)row * ENC + col] = f2bf(tv * rm);
                }
            }
        }
    }
}

// ---------------------------------------------------------------------------
__global__ __launch_bounds__(256) void gemm_qc_k(const float* __restrict__ qg,
                                                 const unsigned short* __restrict__ WqT,
                                                 const float* __restrict__ bq,
                                                 float* __restrict__ qc) {
    __shared__ __align__(16) unsigned short As[4096], Bts[4096];
    f32x4_t z = {0.f, 0.f, 0.f, 0.f};
    f32x4_t acc[2][2] = {{z, z}, {z, z}};
    int m0 = blockIdx.x * 64, n0 = blockIdx.y * 64;
    mfma_core<0>(qg, nullptr, nullptr, nullptr, DIN, 1 << 30, DIN, WqT, 320,
                 m0, n0, 320, Bn * Qn, As, Bts, acc);
    EPI_SETUP
#pragma unroll
    for (int nj = 0; nj < 2; ++nj) {
        int col = n0 + wn + nj * 16 + cidx;
        float bias = bq[col];
#pragma unroll
        for (int mi = 0; mi < 2; ++mi) {
#pragma unroll
            for (int r = 0; r < 4; ++r) {
                int row = m0 + wm + mi * 16 + quad * 4 + r;
                if (row < Bn * Qn) qc[(size_t)row * ENC + col] = acc[mi][nj][r] + bias;
            }
        }
    }
}

// ---------------------------------------------------------------------------
// hm = bf16((lh @ Wh + bh) * rowmask), row-major.  A bf16 direct.
__global__ __launch_bounds__(256) void gemm_hm_k(const unsigned short* __restrict__ lh,
                                                 const unsigned short* __restrict__ WhT,
                                                 const float* __restrict__ bh,
                                                 const int* __restrict__ lens,
                                                 unsigned short* __restrict__ hm) {
    __shared__ __align__(16) unsigned short As[4096], Bts[4096];
    f32x4_t z = {0.f, 0.f, 0.f, 0.f};
    f32x4_t acc[2][2] = {{z, z}, {z, z}};
    int m0 = blockIdx.x * 64, n0 = blockIdx.y * 64;
    mfma_core<1>(nullptr, nullptr, lh, nullptr, ENC, 1 << 30, ENC, WhT, ENC,
                 m0, n0, ENC, Bn * Nn, As, Bts, acc);
    EPI_SETUP
#pragma unroll
    for (int nj = 0; nj < 2; ++nj) {
        int col = n0 + wn + nj * 16 + cidx;
        float bias = bh[col];
#pragma unroll
        for (int mi = 0; mi < 2; ++mi) {
#pragma unroll
            for (int r = 0; r < 4; ++r) {
                int row = m0 + wm + mi * 16 + quad * 4 + r;
                if (row < Bn * Nn) {
                    int b = row / Nn, i = row - b * Nn;
                    float rm = (i < lens[b]) ? 1.0f : 0.0f;
                    hm[(size_t)row * ENC + col] = f2bf((acc[mi][nj][r] + bias) * rm);
                }
            }
        }
    }
}

// ---------------------------------------------------------------------------
// Sparse aggregation: upd[b,i,:] = hm[b,i,:] + sum_j Asum[b,i,j]*hm[b,j,:].
// hm/upd bf16; acc fp32. One wave per row; ballot mask walk, 2 rows/iter.
__global__ __launch_bounds__(256) void upd_sparse_k(const float* __restrict__ Asum,
                                                    const unsigned short* __restrict__ hm,
                                                    unsigned short* __restrict__ upd) {
    int wv = threadIdx.x >> 6, lane = threadIdx.x & 63;
    int row = blockIdx.x * 4 + wv;            // 0..3999
    int b = row / Nn, i = row - b * Nn;
    const float* arow = Asum + (size_t)row * 512;
    const unsigned short* hmb = hm + (size_t)b * Nn * ENC;
    int d0 = lane * 8;

    float acc[8];
    {
        bf16x8_t h = *(const bf16x8_t*)(hmb + (size_t)i * ENC + d0);
#pragma unroll
        for (int j = 0; j < 8; ++j) acc[j] = bf2f((unsigned short)h[j]);
    }
#pragma unroll
    for (int c = 0; c < 8; ++c) {
        int j = c * 64 + lane;
        float val = (j < Nn) ? arow[j] : 0.0f;
        unsigned long long mask = __ballot(val != 0.0f);
        while (mask) {
            int b0 = __ffsll((unsigned long long)mask) - 1;
            mask &= mask - 1;
            int b1 = -1;
            if (mask) { b1 = __ffsll((unsigned long long)mask) - 1; mask &= mask - 1; }
            float v0 = __shfl(val, b0, 64);
            bf16x8_t x = *(const bf16x8_t*)(hmb + (size_t)(c * 64 + b0) * ENC + d0);
            float v1 = 0.0f;
            bf16x8_t y = {0, 0, 0, 0, 0, 0, 0, 0};
            if (b1 >= 0) {
                v1 = __shfl(val, b1, 64);
                y = *(const bf16x8_t*)(hmb + (size_t)(c * 64 + b1) * ENC + d0);
            }
#pragma unroll
            for (int k = 0; k < 8; ++k)
                acc[k] += v0 * bf2f((unsigned short)x[k]) + v1 * bf2f((unsigned short)y[k]);
        }
    }
    float4 o0 = make_float4(acc[0], acc[1], acc[2], acc[3]);
    float4 o1 = make_float4(acc[4], acc[5], acc[6], acc[7]);
    *(bf16x8_t*)(upd + (size_t)row * ENC + d0) = cvt8(o0, o1);
}

// ---------------------------------------------------------------------------
// att = sigmoid([upd|lh]@Wc+bc)*rm; lh_out = bf16(att*tanh(upd)+(1-att)*lh)
__global__ __launch_bounds__(256) void gemm_att_k(const unsigned short* __restrict__ upd,
                                                  const unsigned short* __restrict__ lh,
                                                  const unsigned short* __restrict__ WcT,
                                                  const float* __restrict__ bc,
                                                  const int* __restrict__ lens,
                                                  unsigned short* __restrict__ lh_out) {
    __shared__ __align__(16) unsigned short As[4096], Bts[4096];
    f32x4_t z = {0.f, 0.f, 0.f, 0.f};
    f32x4_t acc[2][2] = {{z, z}, {z, z}};
    int m0 = blockIdx.x * 64, n0 = blockIdx.y * 64;
    mfma_core<1>(nullptr, nullptr, upd, lh, ENC, ENC, 1 << 30, WcT, 2 * ENC,
                 m0, n0, 2 * ENC, Bn * Nn, As, Bts, acc);
    EPI_SETUP
#pragma unroll
    for (int nj = 0; nj < 2; ++nj) {
        int col = n0 + wn + nj * 16 + cidx;
        float bias = bc[col];
#pragma unroll
        for (int mi = 0; mi < 2; ++mi) {
#pragma unroll
            for (int r = 0; r < 4; ++r) {
                int row = m0 + wm + mi * 16 + quad * 4 + r;
                if (row < Bn * Nn) {
                    int b = row / Nn, i = row - b * Nn;
                    float rm = (i < lens[b]) ? 1.0f : 0.0f;
                    float a = sigmoidf_(acc[mi][nj][r] + bias) * rm;
                    size_t off = (size_t)row * ENC + col;
                    float u = bf2f(upd[off]);
                    float l = bf2f(lh[off]);
                    lh_out[off] = f2bf(a * tanhf(u) + (1.0f - a) * l);
                }
            }
        }
    }
}

// ---------------------------------------------------------------------------
// Materialize g = [nc | n2q | nc*n2q | nc*q2n] as bf16 [4000][2048].
__global__ __launch_bounds__(256) void gbf_k(const float* __restrict__ nc,
                                             const float* __restrict__ n2q,
                                             const float* __restrict__ q2n,
                                             unsigned short* __restrict__ gbf) {
    int row = blockIdx.x;
    int b = row / Nn;
    int t = threadIdx.x;
    int seg = t >> 6;          // 0..3
    int d = (t & 63) * 8;
    size_t off = (size_t)row * ENC + d;
    float4 a0, a1;
    if (seg == 0) {
        a0 = *(const float4*)(nc + off); a1 = *(const float4*)(nc + off + 4);
    } else if (seg == 1) {
        a0 = *(const float4*)(n2q + off); a1 = *(const float4*)(n2q + off + 4);
    } else if (seg == 2) {
        float4 x0 = *(const float4*)(nc + off), x1 = *(const float4*)(nc + off + 4);
        float4 y0 = *(const float4*)(n2q + off), y1 = *(const float4*)(n2q + off + 4);
        a0 = make_float4(x0.x * y0.x, x0.y * y0.y, x0.z * y0.z, x0.w * y0.w);
        a1 = make_float4(x1.x * y1.x, x1.y * y1.y, x1.z * y1.z, x1.w * y1.w);
    } else {
        float4 x0 = *(const float4*)(nc + off), x1 = *(const float4*)(nc + off + 4);
        const float* qp = q2n + (size_t)b * ENC + d;
        float4 y0 = *(const float4*)qp, y1 = *(const float4*)(qp + 4);
        a0 = make_float4(x0.x * y0.x, x0.y * y0.y, x0.z * y0.z, x0.w * y0.w);
        a1 = make_float4(x1.x * y1.x, x1.y * y1.y, x1.z * y1.z, x1.w * y1.w);
    }
    *(bf16x8_t*)(gbf + (size_t)row * 2048 + seg * 512 + d) = cvt8(a0, a1);
}

// ---------------------------------------------------------------------------
// g @ W1 split-K partials via MFMA; z = K-slice in [0,4) (512 wide).
__global__ __launch_bounds__(256) void gemm_final_k(const unsigned short* __restrict__ gbf,
                                                    const unsigned short* __restrict__ W1T,
                                                    float* __restrict__ part) {
    __shared__ __align__(16) unsigned short As[4096], Bts[4096];
    f32x4_t z4 = {0.f, 0.f, 0.f, 0.f};
    f32x4_t acc[2][2] = {{z4, z4}, {z4, z4}};
    int zz = blockIdx.z;
    int m0 = blockIdx.x * 64, n0 = blockIdx.y * 64;
    mfma_core<1>(nullptr, nullptr, gbf + zz * 512, nullptr, 2048, 1 << 30, 1 << 30,
                 W1T + zz * 512, 2048, m0, n0, 512, Bn * Nn, As, Bts, acc);
    EPI_SETUP
    constexpr int M = Bn * Nn;
#pragma unroll
    for (int nj = 0; nj < 2; ++nj) {
        int col = n0 + wn + nj * 16 + cidx;   // < 128
#pragma unroll
        for (int mi = 0; mi < 2; ++mi) {
#pragma unroll
            for (int r = 0; r < 4; ++r) {
                int row = m0 + wm + mi * 16 + quad * 4 + r;
                if (row < M) part[((size_t)zz * M + row) * 128 + col] = acc[mi][nj][r];
            }
        }
    }
}

// ---------------------------------------------------------------------------
// Fused sim -> softmax(q) -> nodes2query + rowmax.  One wave per n-row.
// lh is bf16. Lane owns d in {4L..4L+3} u {256+4L..256+4L+3}.
__global__ __launch_bounds__(256) void sim_fused_k(const unsigned short* __restrict__ lh,
                                                   const float* __restrict__ qc,
                                                   const float* __restrict__ wa,
                                                   float* __restrict__ n2q,
                                                   float* __restrict__ rowmax) {
    __shared__ float qcs[Qn * ENC];   // 51.2 KB
    __shared__ float qdot[32];
    int b = blockIdx.x;
    int t = threadIdx.x;
    const float* qcb = qc + (size_t)b * Qn * ENC;
    for (int i = t * 4; i < Qn * ENC; i += 1024) *(float4*)&qcs[i] = *(const float4*)&qcb[i];
    __syncthreads();
    {
        int q = t >> 3, j = t & 7;
        if (q < Qn) {
            float s = 0.f;
            for (int k = 0; k < 64; ++k) {
                int d = j + 8 * k;
                s += qcs[q * ENC + d] * wa[ENC + d];
            }
            s += __shfl_xor(s, 1, 64);
            s += __shfl_xor(s, 2, 64);
            s += __shfl_xor(s, 4, 64);
            if (j == 0) qdot[q] = s;
        }
    }
    __syncthreads();

    int wv = t >> 6, lane = t & 63;
    int n = blockIdx.y * 4 + wv;
    int dA = lane * 4;
    int dB = 256 + lane * 4;
    const unsigned short* lrow = lh + ((size_t)b * Nn + n) * ENC;
    ushort4 ua = *(const ushort4*)(lrow + dA);
    ushort4 ub = *(const ushort4*)(lrow + dB);
    float lv[8] = {bf2f(ua.x), bf2f(ua.y), bf2f(ua.z), bf2f(ua.w),
                   bf2f(ub.x), bf2f(ub.y), bf2f(ub.z), bf2f(ub.w)};
    float ndp = 0.f;
    float lvs[8];
#pragma unroll
    for (int j = 0; j < 4; ++j) {
        ndp += lv[j] * wa[dA + j];
        lvs[j] = lv[j] * wa[2 * ENC + dA + j];
        ndp += lv[4 + j] * wa[dB + j];
        lvs[4 + j] = lv[4 + j] * wa[2 * ENC + dB + j];
    }
#pragma unroll
    for (int off = 32; off; off >>= 1) ndp += __shfl_xor(ndp, off, 64);

    float s_[Qn];
#pragma unroll
    for (int q = 0; q < Qn; ++q) {
        float4 qa = *(const float4*)(qcs + q * ENC + dA);
        float4 qb = *(const float4*)(qcs + q * ENC + dB);
        s_[q] = lvs[0] * qa.x + lvs[1] * qa.y + lvs[2] * qa.z + lvs[3] * qa.w +
                lvs[4] * qb.x + lvs[5] * qb.y + lvs[6] * qb.z + lvs[7] * qb.w;
    }
#pragma unroll
    for (int q = 0; q < Qn; ++q) {
#pragma unroll
        for (int off = 32; off; off >>= 1) s_[q] += __shfl_xor(s_[q], off, 64);
    }
    float mx = -INFINITY;
#pragma unroll
    for (int q = 0; q < Qn; ++q) {
        s_[q] += ndp + qdot[q];
        mx = fmaxf(mx, s_[q]);
    }
    float sum = 0.f;
#pragma unroll
    for (int q = 0; q < Qn; ++q) { s_[q] = expf(s_[q] - mx); sum += s_[q]; }
    float inv = 1.0f / sum;
    float o[8] = {};
#pragma unroll
    for (int q = 0; q < Qn; ++q) {
        float4 qa = *(const float4*)(qcs + q * ENC + dA);
        float4 qb = *(const float4*)(qcs + q * ENC + dB);
        float p = s_[q] * inv;
        o[0] += p * qa.x; o[1] += p * qa.y; o[2] += p * qa.z; o[3] += p * qa.w;
        o[4] += p * qb.x; o[5] += p * qb.y; o[6] += p * qb.z; o[7] += p * qb.w;
    }
    float* orow = n2q + ((size_t)b * Nn + n) * ENC;
    *(float4*)(orow + dA) = make_float4(o[0], o[1], o[2], o[3]);
    *(float4*)(orow + dB) = make_float4(o[4], o[5], o[6], o[7]);
    if (lane == 0) rowmax[b * Nn + n] = mx;
}

// ---------------------------------------------------------------------------
__global__ __launch_bounds__(512) void bvec_k(const float* __restrict__ rowmax,
                                              float* __restrict__ bvec) {
    __shared__ float red[8];
    int b = blockIdx.x, t = threadIdx.x;
    float v = (t < Nn) ? rowmax[b * Nn + t] : -INFINITY;
    float m = v;
    for (int off = 32; off; off >>= 1) m = fmaxf(m, __shfl_xor(m, off, 64));
    if ((t & 63) == 0) red[t >> 6] = m;
    __syncthreads();
    float bm = red[0];
    for (int i = 1; i < 8; ++i) bm = fmaxf(bm, red[i]);
    float e = (t < Nn) ? expf(v - bm) : 0.0f;
    float ssum = e;
    for (int off = 32; off; off >>= 1) ssum += __shfl_xor(ssum, off, 64);
    __syncthreads();
    if ((t & 63) == 0) red[t >> 6] = ssum;
    __syncthreads();
    float tot = 0.f;
    for (int i = 0; i < 8; ++i) tot += red[i];
    if (t < Nn) bvec[b * Nn + t] = e / tot;
}

// ---------------------------------------------------------------------------
__global__ __launch_bounds__(256) void q2n_k(const float* __restrict__ bvec,
                                             const float* __restrict__ nc,
                                             float* __restrict__ q2n) {
    int b = blockIdx.x;
    int d = blockIdx.y * 256 + threadIdx.x;
    const float* ncb = nc + (size_t)b * Nn * ENC;
    float acc = 0.f;
    for (int n = 0; n < Nn; ++n) acc = fmaf(bvec[b * Nn + n], ncb[(size_t)n * ENC + d], acc);
    q2n[b * ENC + d] = acc;
}

// ---------------------------------------------------------------------------
// raw[row] = b2 + sum_h tanh(sum_z part[z][row][h] + b1[h]) * W2[h]
__global__ __launch_bounds__(256) void final_reduce_k(const float* __restrict__ part,
                                                      const float* __restrict__ b1p,
                                                      const float* __restrict__ W2p,
                                                      const float* __restrict__ b2p,
                                                      float* __restrict__ raw) {
    constexpr int M = Bn * Nn;
    int wave = threadIdx.x >> 6, lane = threadIdx.x & 63;
    int row = blockIdx.x * 4 + wave;
    if (row >= M) return;
    float v0 = 0.f, v1 = 0.f;
#pragma unroll
    for (int s = 0; s < 4; ++s) {
        const float* pr = part + ((size_t)s * M + row) * 128;
        v0 += pr[lane];
        v1 += pr[lane + 64];
    }
    float p = tanhf(v0 + b1p[lane]) * W2p[lane] + tanhf(v1 + b1p[lane + 64]) * W2p[lane + 64];
    for (int off = 32; off; off >>= 1) p += __shfl_xor(p, off, 64);
    if (lane == 0) raw[row] = p + b2p[0];
}

// ---------------------------------------------------------------------------
__global__ __launch_bounds__(256) void predmax_k(const int* __restrict__ mask,
                                                 const float* __restrict__ raw,
                                                 float* __restrict__ out) {
    int idx = blockIdx.x * 4 + (threadIdx.x >> 6);
    int lane = threadIdx.x & 63;
    if (idx >= Bn * NCn) return;
    int b = idx / NCn, c = idx - b * NCn;
    const int* mrow = mask + ((size_t)b * NCn + c) * Nn;
    const float* rrow = raw + (size_t)b * Nn;
    float mx = -INFINITY;
    for (int n = lane; n < Nn; n += 64) {
        float v = mrow[n] ? rrow[n] : 0.0f;
        if (v == 0.0f) v = -1.0e6f;
        mx = fmaxf(mx, v);
    }
    for (int off = 32; off; off >>= 1) mx = fmaxf(mx, __shfl_xor(mx, off, 64));
    if (lane == 0) out[idx] = mx;
}

}  // namespace

extern "C" void kernel_launch(void* const* d_in, const int* in_sizes, int n_in,
                              void* d_out, int out_size, void* d_ws, size_t ws_size,
                              hipStream_t stream) {
    const float* nodes_glove  = (const float*)d_in[0];
    const float* query_glove  = (const float*)d_in[1];
    const float* adj          = (const float*)d_in[2];
    const int*   nodes_length = (const int*)d_in[3];
    const int*   maskp        = (const int*)d_in[4];
    const float* Wn = (const float*)d_in[5];
    const float* bn = (const float*)d_in[6];
    const float* Wq = (const float*)d_in[7];
    const float* bq = (const float*)d_in[8];
    const float* Wh = (const float*)d_in[9];
    const float* bh = (const float*)d_in[10];
    const float* Wc = (const float*)d_in[11];
    const float* bc = (const float*)d_in[12];
    const float* wa = (const float*)d_in[13];
    const float* W1 = (const float*)d_in[14];
    const float* b1 = (const float*)d_in[15];
    const float* W2 = (const float*)d_in[16];
    const float* b2 = (const float*)d_in[17];
    float* out = (float*)d_out;

    float* ws = (float*)d_ws;
    size_t off = 0;
    auto alloc = [&](size_t n) { float* p = ws + off; off += n; return p; };
    constexpr size_t ME  = (size_t)Bn * Nn * ENC;       // 2,048,000 fp32 elems
    constexpr size_t MEH = ME / 2;                      // bf16 buffer in float words
    float* nc   = alloc(ME);
    float* Asum = alloc(ME);       // fp32 [8][500][512]; then n2q; then part buf
    unsigned short* lh0 = (unsigned short*)alloc(MEH);
    unsigned short* lh1 = (unsigned short*)alloc(MEH);
    unsigned short* upd = (unsigned short*)alloc(MEH);
    unsigned short* hm  = (unsigned short*)alloc(MEH);
    unsigned short* gbf = (unsigned short*)alloc(ME * 2);   // [4000][2048] bf16
    float* qc   = alloc((size_t)Bn * Qn * ENC);
    float* rowmax = alloc(Bn * Nn);
    float* bvec   = alloc(Bn * Nn);
    float* q2n    = alloc(Bn * ENC);
    float* raw    = alloc(Bn * Nn);
    unsigned short* WnT = (unsigned short*)alloc((size_t)ENC * 320 / 2);
    unsigned short* WqT = (unsigned short*)alloc((size_t)ENC * 320 / 2);
    unsigned short* WhT = (unsigned short*)alloc((size_t)ENC * ENC / 2);
    unsigned short* WcT = (unsigned short*)alloc((size_t)ENC * 2 * ENC / 2);
    unsigned short* W1T = (unsigned short*)alloc((size_t)128 * 2048 / 2);
    alloc(16384);  // tail pad
    float* n2q  = Asum;            // phase 2
    float* part = Asum;            // phase 3 (after gbf consumed n2q)

    constexpr int M = Bn * Nn;  // 4000

    sum_adj_pad_k<<<dim3(Bn * Nn), 128, 0, stream>>>(adj, Asum);
    tcvt_all_k<<<dim3(16, 64, 5), 256, 0, stream>>>(Wn, Wq, Wh, Wc, W1,
                                                    WnT, WqT, WhT, WcT, W1T);

    gemm_nc_k<<<dim3((M + 63) / 64, 8), 256, 0, stream>>>(nodes_glove, WnT, bn,
                                                          nodes_length, nc, lh0);
    gemm_qc_k<<<dim3((Bn * Qn + 63) / 64, 8), 256, 0, stream>>>(query_glove, WqT, bq, qc);

    // 3 hops; cur starts at lh0, after 3 swaps cur==lh1.
    unsigned short* cur = lh0;
    unsigned short* nxt = lh1;
    for (int h = 0; h < 3; ++h) {
        gemm_hm_k<<<dim3((M + 63) / 64, 8), 256, 0, stream>>>(cur, WhT, bh,
                                                              nodes_length, hm);
        upd_sparse_k<<<dim3(M / 4), 256, 0, stream>>>(Asum, hm, upd);
        gemm_att_k<<<dim3((M + 63) / 64, 8), 256, 0, stream>>>(upd, cur, WcT, bc,
                                                               nodes_length, nxt);
        unsigned short* tmp = cur; cur = nxt; nxt = tmp;
    }
    // cur == lh1 == final last_hop; Asum's adjacency copy is now dead.

    sim_fused_k<<<dim3(Bn, 125), 256, 0, stream>>>(cur, qc, wa, n2q, rowmax);
    bvec_k<<<dim3(Bn), 512, 0, stream>>>(rowmax, bvec);
    q2n_k<<<dim3(Bn, ENC / 256), 256, 0, stream>>>(bvec, nc, q2n);
    gbf_k<<<dim3(M), 256, 0, stream>>>(nc, n2q, q2n, gbf);       // consumes n2q
    gemm_final_k<<<dim3((M + 63) / 64, 2, 4), 256, 0, stream>>>(gbf, W1T, part);
    final_reduce_k<<<dim3((M + 3) / 4), 256, 0, stream>>>(part, b1, W2, b2, raw);
    predmax_k<<<dim3((Bn * NCn + 3) / 4), 256, 0, stream>>>(maskp, raw, out);
}

// Round 13
// 359.687 us; speedup vs baseline: 1.2935x; 1.0445x over previous
//
#include <hip/hip_runtime.h>
#include <hip/hip_bf16.h>
#include <math.h>
#include <stdint.h>

namespace {

constexpr int Bn  = 8;
constexpr int Nn  = 500;
constexpr int Qn  = 25;
constexpr int ENC = 512;
constexpr int DIN = 300;
constexpr int NCn = 70;
constexpr int NETn = 3;

typedef __attribute__((ext_vector_type(8))) short bf16x8_t;
typedef __attribute__((ext_vector_type(4))) float f32x4_t;

__device__ __forceinline__ unsigned short f2bf(float f) {
    union { __hip_bfloat16 b; unsigned short u; } r;
    r.b = __float2bfloat16(f);
    return r.u;
}
__device__ __forceinline__ bf16x8_t cvt8(float4 f0, float4 f1) {
    union { bf16x8_t v; __hip_bfloat162 b[4]; } r;
    r.b[0] = __float22bfloat162_rn(make_float2(f0.x, f0.y));
    r.b[1] = __float22bfloat162_rn(make_float2(f0.z, f0.w));
    r.b[2] = __float22bfloat162_rn(make_float2(f1.x, f1.y));
    r.b[3] = __float22bfloat162_rn(make_float2(f1.z, f1.w));
    return r.v;
}
__device__ __forceinline__ float bf2f(unsigned short h) {
    unsigned int u = ((unsigned int)h) << 16;
    return __builtin_bit_cast(float, u);
}
__device__ __forceinline__ float sigmoidf_(float x) { return 1.0f / (1.0f + expf(-x)); }

// ---------------------------------------------------------------------------
// Asum[b][i][j] = sum_e adj[b,e,i,j], fp32, j padded 500->512 with zeros.
__global__ __launch_bounds__(128) void sum_adj_pad_k(const float* __restrict__ adj,
                                                     float* __restrict__ Asum) {
    int bi = blockIdx.x;
    int b = bi / Nn, i = bi - b * Nn;
    int j = threadIdx.x * 4;
    float4 s = make_float4(0.f, 0.f, 0.f, 0.f);
    if (j < Nn) {
#pragma unroll
        for (int e = 0; e < NETn; ++e) {
            const float* p = adj + (((size_t)(b * NETn + e) * Nn) + i) * Nn + j;
            float4 v = *(const float4*)p;
            s.x += v.x; s.y += v.y; s.z += v.z; s.w += v.w;
        }
    }
    *(float4*)(Asum + ((size_t)bi) * 512 + j) = s;
}

// ---------------------------------------------------------------------------
// All 5 weight transposes in one launch. z selects matrix; idle blocks exit.
__global__ __launch_bounds__(256) void tcvt_all_k(
    const float* __restrict__ Wn, const float* __restrict__ Wq,
    const float* __restrict__ Wh, const float* __restrict__ Wc,
    const float* __restrict__ W1,
    unsigned short* __restrict__ WnT, unsigned short* __restrict__ WqT,
    unsigned short* __restrict__ WhT, unsigned short* __restrict__ WcT,
    unsigned short* __restrict__ W1T) {
    __shared__ float tile[32][33];
    int sel = blockIdx.z;
    const float* in; unsigned short* out; int K, N, Kpad;
    if (sel == 0)      { in = Wn; out = WnT; K = DIN;  N = ENC; Kpad = 320;  }
    else if (sel == 1) { in = Wq; out = WqT; K = DIN;  N = ENC; Kpad = 320;  }
    else if (sel == 2) { in = Wh; out = WhT; K = ENC;  N = ENC; Kpad = 512;  }
    else if (sel == 3) { in = Wc; out = WcT; K = 1024; N = ENC; Kpad = 1024; }
    else               { in = W1; out = W1T; K = 2048; N = 128; Kpad = 2048; }
    int n0 = blockIdx.x * 32, k0 = blockIdx.y * 32;
    if (n0 >= N || k0 >= Kpad) return;
    int tx = threadIdx.x & 31, ty = threadIdx.x >> 5;
#pragma unroll
    for (int r = 0; r < 4; ++r) {
        int k = k0 + ty * 4 + r;
        int n = n0 + tx;
        tile[ty * 4 + r][tx] = (k < K && n < N) ? in[(size_t)k * N + n] : 0.0f;
    }
    __syncthreads();
#pragma unroll
    for (int r = 0; r < 4; ++r) {
        int n = n0 + ty * 4 + r;
        int k = k0 + tx;
        if (n < N && k < Kpad) out[(size_t)n * Kpad + k] = f2bf(tile[tx][ty * 4 + r]);
    }
}

// ---------------------------------------------------------------------------
// MFMA core, BK=64: 64x64 tile, 4 waves (2x2 of 32x32), double-buffered LDS,
// one barrier per 64-k step (two 32-k sub-tiles staged/consumed per barrier;
// k-ascending MFMA order keeps numerics identical to the BK=32 version).
// AMODE 0: A fp32 row-major (A2 concat for k>=ksplit); chunks clamp at Klim.
// AMODE 1: A bf16 row-major (Abf; optional Abf2 concat for k>=ksplit).
// Bt: bf16 B^T row-major [n][k]. Per-32k-half LDS 16B lines XOR-swizzled.
// LDS per operand array: 2 dbuf x 2 halves x 2048 shorts = 8192 shorts (16KB).
template <int AMODE>
__device__ __forceinline__ void mfma_core(
    const float* __restrict__ A, const float* __restrict__ A2,
    const unsigned short* __restrict__ Abf, const unsigned short* __restrict__ Abf2,
    int lda, int ksplit, int Klim,
    const unsigned short* __restrict__ Bt, int ldb,
    int m0, int n0, int K, int Mlim,
    unsigned short* As, unsigned short* Bts, f32x4_t acc[2][2]) {
    const int t = threadIdx.x;
    const int lane = t & 63;
    const int w = t >> 6;
    const int sm = t >> 2;                 // staging row 0..63
    const int sp = t & 3;                  // physical 16B line within 32-k half
    const int sq = sp ^ ((sm >> 1) & 3);   // logical k-chunk staged
    const int arow = m0 + sm;
    const bool rowok = arow < Mlim;
    const int wm = (w & 1) * 32, wn = (w >> 1) * 32;
    const int quad = lane >> 4, cidx = lane & 15;
    const int am0 = wm + cidx, am1 = wm + 16 + cidx;
    const int an0 = wn + cidx, an1 = wn + 16 + cidx;
    const int apo0 = am0 * 32 + (quad ^ ((am0 >> 1) & 3)) * 8;
    const int apo1 = am1 * 32 + (quad ^ ((am1 >> 1) & 3)) * 8;
    const int bpo0 = an0 * 32 + (quad ^ ((an0 >> 1) & 3)) * 8;
    const int bpo1 = an1 * 32 + (quad ^ ((an1 >> 1) & 3)) * 8;

    bf16x8_t ast0, ast1, bst0, bst1;
    auto stageA = [&](int kg) -> bf16x8_t {
        if (AMODE == 1) {
            bf16x8_t r = {0, 0, 0, 0, 0, 0, 0, 0};
            if (rowok) {
                const unsigned short* src =
                    (Abf2 != nullptr && kg >= ksplit)
                        ? Abf2 + (size_t)arow * lda + (kg - ksplit)
                        : Abf + (size_t)arow * lda + kg;
                r = *(const bf16x8_t*)src;
            }
            return r;
        } else {
            float4 f0 = make_float4(0.f, 0.f, 0.f, 0.f);
            float4 f1 = make_float4(0.f, 0.f, 0.f, 0.f);
            if (rowok) {
                const float* src = (A2 != nullptr && kg >= ksplit)
                                       ? A2 + (size_t)arow * lda + (kg - ksplit)
                                       : A + (size_t)arow * lda + kg;
                if (kg + 8 <= Klim) {
                    f0 = *(const float4*)src;
                    f1 = *(const float4*)(src + 4);
                } else if (kg + 4 <= Klim) {
                    f0 = *(const float4*)src;
                }
            }
            return cvt8(f0, f1);
        }
    };
    auto stage = [&](int k0) {
        int kg0 = k0 + sq * 8;
        int kg1 = k0 + 32 + sq * 8;
        ast0 = stageA(kg0);
        ast1 = stageA(kg1);
        const unsigned short* brow = Bt + (size_t)(n0 + sm) * ldb;
        bst0 = *(const bf16x8_t*)(brow + kg0);
        bst1 = *(const bf16x8_t*)(brow + kg1);
    };

    const int ktot = K >> 6;
    stage(0);
    *(bf16x8_t*)(As + t * 8) = ast0;
    *(bf16x8_t*)(As + 2048 + t * 8) = ast1;
    *(bf16x8_t*)(Bts + t * 8) = bst0;
    *(bf16x8_t*)(Bts + 2048 + t * 8) = bst1;
    for (int kt = 0; kt < ktot; ++kt) {
        __syncthreads();
        const int cur = (kt & 1) * 4096;
        const bool more = (kt + 1) < ktot;
        if (more) stage((kt + 1) << 6);
        {   // first 32-k half
            bf16x8_t a0 = *(const bf16x8_t*)(As + cur + apo0);
            bf16x8_t a1 = *(const bf16x8_t*)(As + cur + apo1);
            bf16x8_t b0 = *(const bf16x8_t*)(Bts + cur + bpo0);
            bf16x8_t b1 = *(const bf16x8_t*)(Bts + cur + bpo1);
            acc[0][0] = __builtin_amdgcn_mfma_f32_16x16x32_bf16(a0, b0, acc[0][0], 0, 0, 0);
            acc[0][1] = __builtin_amdgcn_mfma_f32_16x16x32_bf16(a0, b1, acc[0][1], 0, 0, 0);
            acc[1][0] = __builtin_amdgcn_mfma_f32_16x16x32_bf16(a1, b0, acc[1][0], 0, 0, 0);
            acc[1][1] = __builtin_amdgcn_mfma_f32_16x16x32_bf16(a1, b1, acc[1][1], 0, 0, 0);
        }
        {   // second 32-k half
            bf16x8_t a0 = *(const bf16x8_t*)(As + cur + 2048 + apo0);
            bf16x8_t a1 = *(const bf16x8_t*)(As + cur + 2048 + apo1);
            bf16x8_t b0 = *(const bf16x8_t*)(Bts + cur + 2048 + bpo0);
            bf16x8_t b1 = *(const bf16x8_t*)(Bts + cur + 2048 + bpo1);
            acc[0][0] = __builtin_amdgcn_mfma_f32_16x16x32_bf16(a0, b0, acc[0][0], 0, 0, 0);
            acc[0][1] = __builtin_amdgcn_mfma_f32_16x16x32_bf16(a0, b1, acc[0][1], 0, 0, 0);
            acc[1][0] = __builtin_amdgcn_mfma_f32_16x16x32_bf16(a1, b0, acc[1][0], 0, 0, 0);
            acc[1][1] = __builtin_amdgcn_mfma_f32_16x16x32_bf16(a1, b1, acc[1][1], 0, 0, 0);
        }
        if (more) {
            const int nxt = ((kt + 1) & 1) * 4096;
            *(bf16x8_t*)(As + nxt + t * 8) = ast0;
            *(bf16x8_t*)(As + nxt + 2048 + t * 8) = ast1;
            *(bf16x8_t*)(Bts + nxt + t * 8) = bst0;
            *(bf16x8_t*)(Bts + nxt + 2048 + t * 8) = bst1;
        }
    }
}

#define EPI_SETUP                                         \
    int t = threadIdx.x, lane = t & 63, w = t >> 6;       \
    int wm = (w & 1) * 32, wn = (w >> 1) * 32;            \
    int quad = lane >> 4, cidx = lane & 15;               \
    (void)wm; (void)wn; (void)quad; (void)cidx;

// ---------------------------------------------------------------------------
// nc = tanh(ng@Wn+bn) fp32;  lh0 = bf16(nc * rowmask)
__global__ __launch_bounds__(256) void gemm_nc_k(const float* __restrict__ ng,
                                                 const unsigned short* __restrict__ WnT,
                                                 const float* __restrict__ bn,
                                                 const int* __restrict__ lens,
                                                 float* __restrict__ nc,
                                                 unsigned short* __restrict__ lh0) {
    __shared__ __align__(16) unsigned short As[8192], Bts[8192];
    f32x4_t z = {0.f, 0.f, 0.f, 0.f};
    f32x4_t acc[2][2] = {{z, z}, {z, z}};
    int m0 = blockIdx.x * 64, n0 = blockIdx.y * 64;
    mfma_core<0>(ng, nullptr, nullptr, nullptr, DIN, 1 << 30, DIN, WnT, 320,
                 m0, n0, 320, Bn * Nn, As, Bts, acc);
    EPI_SETUP
#pragma unroll
    for (int nj = 0; nj < 2; ++nj) {
        int col = n0 + wn + nj * 16 + cidx;
        float bias = bn[col];
#pragma unroll
        for (int mi = 0; mi < 2; ++mi) {
#pragma unroll
            for (int r = 0; r < 4; ++r) {
                int row = m0 + wm + mi * 16 + quad * 4 + r;
                if (row < Bn * Nn) {
                    float tv = tanhf(acc[mi][nj][r] + bias);
                    int b = row / Nn, i = row - b * Nn;
                    float rm = (i < lens[b]) ? 1.0f : 0.0f;
                    nc[(size_t)row * ENC + col] = tv;
                    lh0[(size_t)row * ENC + col] = f2bf(tv * rm);
                }
            }
        }
    }
}

// ---------------------------------------------------------------------------
__global__ __launch_bounds__(256) void gemm_qc_k(const float* __restrict__ qg,
                                                 const unsigned short* __restrict__ WqT,
                                                 const float* __restrict__ bq,
                                                 float* __restrict__ qc) {
    __shared__ __align__(16) unsigned short As[8192], Bts[8192];
    f32x4_t z = {0.f, 0.f, 0.f, 0.f};
    f32x4_t acc[2][2] = {{z, z}, {z, z}};
    int m0 = blockIdx.x * 64, n0 = blockIdx.y * 64;
    mfma_core<0>(qg, nullptr, nullptr, nullptr, DIN, 1 << 30, DIN, WqT, 320,
                 m0, n0, 320, Bn * Qn, As, Bts, acc);
    EPI_SETUP
#pragma unroll
    for (int nj = 0; nj < 2; ++nj) {
        int col = n0 + wn + nj * 16 + cidx;
        float bias = bq[col];
#pragma unroll
        for (int mi = 0; mi < 2; ++mi) {
#pragma unroll
            for (int r = 0; r < 4; ++r) {
                int row = m0 + wm + mi * 16 + quad * 4 + r;
                if (row < Bn * Qn) qc[(size_t)row * ENC + col] = acc[mi][nj][r] + bias;
            }
        }
    }
}

// ---------------------------------------------------------------------------
// hm = bf16((lh @ Wh + bh) * rowmask), row-major.  A bf16 direct.
__global__ __launch_bounds__(256) void gemm_hm_k(const unsigned short* __restrict__ lh,
                                                 const unsigned short* __restrict__ WhT,
                                                 const float* __restrict__ bh,
                                                 const int* __restrict__ lens,
                                                 unsigned short* __restrict__ hm) {
    __shared__ __align__(16) unsigned short As[8192], Bts[8192];
    f32x4_t z = {0.f, 0.f, 0.f, 0.f};
    f32x4_t acc[2][2] = {{z, z}, {z, z}};
    int m0 = blockIdx.x * 64, n0 = blockIdx.y * 64;
    mfma_core<1>(nullptr, nullptr, lh, nullptr, ENC, 1 << 30, ENC, WhT, ENC,
                 m0, n0, ENC, Bn * Nn, As, Bts, acc);
    EPI_SETUP
#pragma unroll
    for (int nj = 0; nj < 2; ++nj) {
        int col = n0 + wn + nj * 16 + cidx;
        float bias = bh[col];
#pragma unroll
        for (int mi = 0; mi < 2; ++mi) {
#pragma unroll
            for (int r = 0; r < 4; ++r) {
                int row = m0 + wm + mi * 16 + quad * 4 + r;
                if (row < Bn * Nn) {
                    int b = row / Nn, i = row - b * Nn;
                    float rm = (i < lens[b]) ? 1.0f : 0.0f;
                    hm[(size_t)row * ENC + col] = f2bf((acc[mi][nj][r] + bias) * rm);
                }
            }
        }
    }
}

// ---------------------------------------------------------------------------
// Sparse aggregation: upd[b,i,:] = hm[b,i,:] + sum_j Asum[b,i,j]*hm[b,j,:].
__global__ __launch_bounds__(256) void upd_sparse_k(const float* __restrict__ Asum,
                                                    const unsigned short* __restrict__ hm,
                                                    unsigned short* __restrict__ upd) {
    int wv = threadIdx.x >> 6, lane = threadIdx.x & 63;
    int row = blockIdx.x * 4 + wv;            // 0..3999
    int b = row / Nn, i = row - b * Nn;
    const float* arow = Asum + (size_t)row * 512;
    const unsigned short* hmb = hm + (size_t)b * Nn * ENC;
    int d0 = lane * 8;

    float acc[8];
    {
        bf16x8_t h = *(const bf16x8_t*)(hmb + (size_t)i * ENC + d0);
#pragma unroll
        for (int j = 0; j < 8; ++j) acc[j] = bf2f((unsigned short)h[j]);
    }
#pragma unroll
    for (int c = 0; c < 8; ++c) {
        int j = c * 64 + lane;
        float val = (j < Nn) ? arow[j] : 0.0f;
        unsigned long long mask = __ballot(val != 0.0f);
        while (mask) {
            int b0 = __ffsll((unsigned long long)mask) - 1;
            mask &= mask - 1;
            int b1 = -1;
            if (mask) { b1 = __ffsll((unsigned long long)mask) - 1; mask &= mask - 1; }
            float v0 = __shfl(val, b0, 64);
            bf16x8_t x = *(const bf16x8_t*)(hmb + (size_t)(c * 64 + b0) * ENC + d0);
            float v1 = 0.0f;
            bf16x8_t y = {0, 0, 0, 0, 0, 0, 0, 0};
            if (b1 >= 0) {
                v1 = __shfl(val, b1, 64);
                y = *(const bf16x8_t*)(hmb + (size_t)(c * 64 + b1) * ENC + d0);
            }
#pragma unroll
            for (int k = 0; k < 8; ++k)
                acc[k] += v0 * bf2f((unsigned short)x[k]) + v1 * bf2f((unsigned short)y[k]);
        }
    }
    float4 o0 = make_float4(acc[0], acc[1], acc[2], acc[3]);
    float4 o1 = make_float4(acc[4], acc[5], acc[6], acc[7]);
    *(bf16x8_t*)(upd + (size_t)row * ENC + d0) = cvt8(o0, o1);
}

// ---------------------------------------------------------------------------
// att = sigmoid([upd|lh]@Wc+bc)*rm; lh_out = bf16(att*tanh(upd)+(1-att)*lh)
__global__ __launch_bounds__(256) void gemm_att_k(const unsigned short* __restrict__ upd,
                                                  const unsigned short* __restrict__ lh,
                                                  const unsigned short* __restrict__ WcT,
                                                  const float* __restrict__ bc,
                                                  const int* __restrict__ lens,
                                                  unsigned short* __restrict__ lh_out) {
    __shared__ __align__(16) unsigned short As[8192], Bts[8192];
    f32x4_t z = {0.f, 0.f, 0.f, 0.f};
    f32x4_t acc[2][2] = {{z, z}, {z, z}};
    int m0 = blockIdx.x * 64, n0 = blockIdx.y * 64;
    mfma_core<1>(nullptr, nullptr, upd, lh, ENC, ENC, 1 << 30, WcT, 2 * ENC,
                 m0, n0, 2 * ENC, Bn * Nn, As, Bts, acc);
    EPI_SETUP
#pragma unroll
    for (int nj = 0; nj < 2; ++nj) {
        int col = n0 + wn + nj * 16 + cidx;
        float bias = bc[col];
#pragma unroll
        for (int mi = 0; mi < 2; ++mi) {
#pragma unroll
            for (int r = 0; r < 4; ++r) {
                int row = m0 + wm + mi * 16 + quad * 4 + r;
                if (row < Bn * Nn) {
                    int b = row / Nn, i = row - b * Nn;
                    float rm = (i < lens[b]) ? 1.0f : 0.0f;
                    float a = sigmoidf_(acc[mi][nj][r] + bias) * rm;
                    size_t off = (size_t)row * ENC + col;
                    float u = bf2f(upd[off]);
                    float l = bf2f(lh[off]);
                    lh_out[off] = f2bf(a * tanhf(u) + (1.0f - a) * l);
                }
            }
        }
    }
}

// ---------------------------------------------------------------------------
// Materialize g = [nc | n2q | nc*n2q | nc*q2n] as bf16 [4000][2048].
__global__ __launch_bounds__(256) void gbf_k(const float* __restrict__ nc,
                                             const float* __restrict__ n2q,
                                             const float* __restrict__ q2n,
                                             unsigned short* __restrict__ gbf) {
    int row = blockIdx.x;
    int b = row / Nn;
    int t = threadIdx.x;
    int seg = t >> 6;          // 0..3
    int d = (t & 63) * 8;
    size_t off = (size_t)row * ENC + d;
    float4 a0, a1;
    if (seg == 0) {
        a0 = *(const float4*)(nc + off); a1 = *(const float4*)(nc + off + 4);
    } else if (seg == 1) {
        a0 = *(const float4*)(n2q + off); a1 = *(const float4*)(n2q + off + 4);
    } else if (seg == 2) {
        float4 x0 = *(const float4*)(nc + off), x1 = *(const float4*)(nc + off + 4);
        float4 y0 = *(const float4*)(n2q + off), y1 = *(const float4*)(n2q + off + 4);
        a0 = make_float4(x0.x * y0.x, x0.y * y0.y, x0.z * y0.z, x0.w * y0.w);
        a1 = make_float4(x1.x * y1.x, x1.y * y1.y, x1.z * y1.z, x1.w * y1.w);
    } else {
        float4 x0 = *(const float4*)(nc + off), x1 = *(const float4*)(nc + off + 4);
        const float* qp = q2n + (size_t)b * ENC + d;
        float4 y0 = *(const float4*)qp, y1 = *(const float4*)(qp + 4);
        a0 = make_float4(x0.x * y0.x, x0.y * y0.y, x0.z * y0.z, x0.w * y0.w);
        a1 = make_float4(x1.x * y1.x, x1.y * y1.y, x1.z * y1.z, x1.w * y1.w);
    }
    *(bf16x8_t*)(gbf + (size_t)row * 2048 + seg * 512 + d) = cvt8(a0, a1);
}

// ---------------------------------------------------------------------------
// g @ W1 split-K partials via MFMA; z = K-slice in [0,4) (512 wide).
__global__ __launch_bounds__(256) void gemm_final_k(const unsigned short* __restrict__ gbf,
                                                    const unsigned short* __restrict__ W1T,
                                                    float* __restrict__ part) {
    __shared__ __align__(16) unsigned short As[8192], Bts[8192];
    f32x4_t z4 = {0.f, 0.f, 0.f, 0.f};
    f32x4_t acc[2][2] = {{z4, z4}, {z4, z4}};
    int zz = blockIdx.z;
    int m0 = blockIdx.x * 64, n0 = blockIdx.y * 64;
    mfma_core<1>(nullptr, nullptr, gbf + zz * 512, nullptr, 2048, 1 << 30, 1 << 30,
                 W1T + zz * 512, 2048, m0, n0, 512, Bn * Nn, As, Bts, acc);
    EPI_SETUP
    constexpr int M = Bn * Nn;
#pragma unroll
    for (int nj = 0; nj < 2; ++nj) {
        int col = n0 + wn + nj * 16 + cidx;   // < 128
#pragma unroll
        for (int mi = 0; mi < 2; ++mi) {
#pragma unroll
            for (int r = 0; r < 4; ++r) {
                int row = m0 + wm + mi * 16 + quad * 4 + r;
                if (row < M) part[((size_t)zz * M + row) * 128 + col] = acc[mi][nj][r];
            }
        }
    }
}

// ---------------------------------------------------------------------------
// Fused sim -> softmax(q) -> nodes2query + rowmax.  One wave per n-row.
__global__ __launch_bounds__(256) void sim_fused_k(const unsigned short* __restrict__ lh,
                                                   const float* __restrict__ qc,
                                                   const float* __restrict__ wa,
                                                   float* __restrict__ n2q,
                                                   float* __restrict__ rowmax) {
    __shared__ float qcs[Qn * ENC];   // 51.2 KB
    __shared__ float qdot[32];
    int b = blockIdx.x;
    int t = threadIdx.x;
    const float* qcb = qc + (size_t)b * Qn * ENC;
    for (int i = t * 4; i < Qn * ENC; i += 1024) *(float4*)&qcs[i] = *(const float4*)&qcb[i];
    __syncthreads();
    {
        int q = t >> 3, j = t & 7;
        if (q < Qn) {
            float s = 0.f;
            for (int k = 0; k < 64; ++k) {
                int d = j + 8 * k;
                s += qcs[q * ENC + d] * wa[ENC + d];
            }
            s += __shfl_xor(s, 1, 64);
            s += __shfl_xor(s, 2, 64);
            s += __shfl_xor(s, 4, 64);
            if (j == 0) qdot[q] = s;
        }
    }
    __syncthreads();

    int wv = t >> 6, lane = t & 63;
    int n = blockIdx.y * 4 + wv;
    int dA = lane * 4;
    int dB = 256 + lane * 4;
    const unsigned short* lrow = lh + ((size_t)b * Nn + n) * ENC;
    ushort4 ua = *(const ushort4*)(lrow + dA);
    ushort4 ub = *(const ushort4*)(lrow + dB);
    float lv[8] = {bf2f(ua.x), bf2f(ua.y), bf2f(ua.z), bf2f(ua.w),
                   bf2f(ub.x), bf2f(ub.y), bf2f(ub.z), bf2f(ub.w)};
    float ndp = 0.f;
    float lvs[8];
#pragma unroll
    for (int j = 0; j < 4; ++j) {
        ndp += lv[j] * wa[dA + j];
        lvs[j] = lv[j] * wa[2 * ENC + dA + j];
        ndp += lv[4 + j] * wa[dB + j];
        lvs[4 + j] = lv[4 + j] * wa[2 * ENC + dB + j];
    }
#pragma unroll
    for (int off = 32; off; off >>= 1) ndp += __shfl_xor(ndp, off, 64);

    float s_[Qn];
#pragma unroll
    for (int q = 0; q < Qn; ++q) {
        float4 qa = *(const float4*)(qcs + q * ENC + dA);
        float4 qb = *(const float4*)(qcs + q * ENC + dB);
        s_[q] = lvs[0] * qa.x + lvs[1] * qa.y + lvs[2] * qa.z + lvs[3] * qa.w +
                lvs[4] * qb.x + lvs[5] * qb.y + lvs[6] * qb.z + lvs[7] * qb.w;
    }
#pragma unroll
    for (int q = 0; q < Qn; ++q) {
#pragma unroll
        for (int off = 32; off; off >>= 1) s_[q] += __shfl_xor(s_[q], off, 64);
    }
    float mx = -INFINITY;
#pragma unroll
    for (int q = 0; q < Qn; ++q) {
        s_[q] += ndp + qdot[q];
        mx = fmaxf(mx, s_[q]);
    }
    float sum = 0.f;
#pragma unroll
    for (int q = 0; q < Qn; ++q) { s_[q] = expf(s_[q] - mx); sum += s_[q]; }
    float inv = 1.0f / sum;
    float o[8] = {};
#pragma unroll
    for (int q = 0; q < Qn; ++q) {
        float4 qa = *(const float4*)(qcs + q * ENC + dA);
        float4 qb = *(const float4*)(qcs + q * ENC + dB);
        float p = s_[q] * inv;
        o[0] += p * qa.x; o[1] += p * qa.y; o[2] += p * qa.z; o[3] += p * qa.w;
        o[4] += p * qb.x; o[5] += p * qb.y; o[6] += p * qb.z; o[7] += p * qb.w;
    }
    float* orow = n2q + ((size_t)b * Nn + n) * ENC;
    *(float4*)(orow + dA) = make_float4(o[0], o[1], o[2], o[3]);
    *(float4*)(orow + dB) = make_float4(o[4], o[5], o[6], o[7]);
    if (lane == 0) rowmax[b * Nn + n] = mx;
}

// ---------------------------------------------------------------------------
__global__ __launch_bounds__(512) void bvec_k(const float* __restrict__ rowmax,
                                              float* __restrict__ bvec) {
    __shared__ float red[8];
    int b = blockIdx.x, t = threadIdx.x;
    float v = (t < Nn) ? rowmax[b * Nn + t] : -INFINITY;
    float m = v;
    for (int off = 32; off; off >>= 1) m = fmaxf(m, __shfl_xor(m, off, 64));
    if ((t & 63) == 0) red[t >> 6] = m;
    __syncthreads();
    float bm = red[0];
    for (int i = 1; i < 8; ++i) bm = fmaxf(bm, red[i]);
    float e = (t < Nn) ? expf(v - bm) : 0.0f;
    float ssum = e;
    for (int off = 32; off; off >>= 1) ssum += __shfl_xor(ssum, off, 64);
    __syncthreads();
    if ((t & 63) == 0) red[t >> 6] = ssum;
    __syncthreads();
    float tot = 0.f;
    for (int i = 0; i < 8; ++i) tot += red[i];
    if (t < Nn) bvec[b * Nn + t] = e / tot;
}

// ---------------------------------------------------------------------------
__global__ __launch_bounds__(256) void q2n_k(const float* __restrict__ bvec,
                                             const float* __restrict__ nc,
                                             float* __restrict__ q2n) {
    int b = blockIdx.x;
    int d = blockIdx.y * 256 + threadIdx.x;
    const float* ncb = nc + (size_t)b * Nn * ENC;
    float acc = 0.f;
    for (int n = 0; n < Nn; ++n) acc = fmaf(bvec[b * Nn + n], ncb[(size_t)n * ENC + d], acc);
    q2n[b * ENC + d] = acc;
}

// ---------------------------------------------------------------------------
// raw[row] = b2 + sum_h tanh(sum_z part[z][row][h] + b1[h]) * W2[h]
__global__ __launch_bounds__(256) void final_reduce_k(const float* __restrict__ part,
                                                      const float* __restrict__ b1p,
                                                      const float* __restrict__ W2p,
                                                      const float* __restrict__ b2p,
                                                      float* __restrict__ raw) {
    constexpr int M = Bn * Nn;
    int wave = threadIdx.x >> 6, lane = threadIdx.x & 63;
    int row = blockIdx.x * 4 + wave;
    if (row >= M) return;
    float v0 = 0.f, v1 = 0.f;
#pragma unroll
    for (int s = 0; s < 4; ++s) {
        const float* pr = part + ((size_t)s * M + row) * 128;
        v0 += pr[lane];
        v1 += pr[lane + 64];
    }
    float p = tanhf(v0 + b1p[lane]) * W2p[lane] + tanhf(v1 + b1p[lane + 64]) * W2p[lane + 64];
    for (int off = 32; off; off >>= 1) p += __shfl_xor(p, off, 64);
    if (lane == 0) raw[row] = p + b2p[0];
}

// ---------------------------------------------------------------------------
__global__ __launch_bounds__(256) void predmax_k(const int* __restrict__ mask,
                                                 const float* __restrict__ raw,
                                                 float* __restrict__ out) {
    int idx = blockIdx.x * 4 + (threadIdx.x >> 6);
    int lane = threadIdx.x & 63;
    if (idx >= Bn * NCn) return;
    int b = idx / NCn, c = idx - b * NCn;
    const int* mrow = mask + ((size_t)b * NCn + c) * Nn;
    const float* rrow = raw + (size_t)b * Nn;
    float mx = -INFINITY;
    for (int n = lane; n < Nn; n += 64) {
        float v = mrow[n] ? rrow[n] : 0.0f;
        if (v == 0.0f) v = -1.0e6f;
        mx = fmaxf(mx, v);
    }
    for (int off = 32; off; off >>= 1) mx = fmaxf(mx, __shfl_xor(mx, off, 64));
    if (lane == 0) out[idx] = mx;
}

}  // namespace

extern "C" void kernel_launch(void* const* d_in, const int* in_sizes, int n_in,
                              void* d_out, int out_size, void* d_ws, size_t ws_size,
                              hipStream_t stream) {
    const float* nodes_glove  = (const float*)d_in[0];
    const float* query_glove  = (const float*)d_in[1];
    const float* adj          = (const float*)d_in[2];
    const int*   nodes_length = (const int*)d_in[3];
    const int*   maskp        = (const int*)d_in[4];
    const float* Wn = (const float*)d_in[5];
    const float* bn = (const float*)d_in[6];
    const float* Wq = (const float*)d_in[7];
    const float* bq = (const float*)d_in[8];
    const float* Wh = (const float*)d_in[9];
    const float* bh = (const float*)d_in[10];
    const float* Wc = (const float*)d_in[11];
    const float* bc = (const float*)d_in[12];
    const float* wa = (const float*)d_in[13];
    const float* W1 = (const float*)d_in[14];
    const float* b1 = (const float*)d_in[15];
    const float* W2 = (const float*)d_in[16];
    const float* b2 = (const float*)d_in[17];
    float* out = (float*)d_out;

    float* ws = (float*)d_ws;
    size_t off = 0;
    auto alloc = [&](size_t n) { float* p = ws + off; off += n; return p; };
    constexpr size_t ME  = (size_t)Bn * Nn * ENC;       // 2,048,000 fp32 elems
    constexpr size_t MEH = ME / 2;                      // bf16 buffer in float words
    float* nc   = alloc(ME);
    float* Asum = alloc(ME);       // fp32 [8][500][512]; then n2q; then part buf
    unsigned short* lh0 = (unsigned short*)alloc(MEH);
    unsigned short* lh1 = (unsigned short*)alloc(MEH);
    unsigned short* upd = (unsigned short*)alloc(MEH);
    unsigned short* hm  = (unsigned short*)alloc(MEH);
    unsigned short* gbf = (unsigned short*)alloc(ME * 2);   // [4000][2048] bf16
    float* qc   = alloc((size_t)Bn * Qn * ENC);
    float* rowmax = alloc(Bn * Nn);
    float* bvec   = alloc(Bn * Nn);
    float* q2n    = alloc(Bn * ENC);
    float* raw    = alloc(Bn * Nn);
    unsigned short* WnT = (unsigned short*)alloc((size_t)ENC * 320 / 2);
    unsigned short* WqT = (unsigned short*)alloc((size_t)ENC * 320 / 2);
    unsigned short* WhT = (unsigned short*)alloc((size_t)ENC * ENC / 2);
    unsigned short* WcT = (unsigned short*)alloc((size_t)ENC * 2 * ENC / 2);
    unsigned short* W1T = (unsigned short*)alloc((size_t)128 * 2048 / 2);
    alloc(16384);  // tail pad
    float* n2q  = Asum;            // phase 2
    float* part = Asum;            // phase 3 (after gbf consumed n2q)

    constexpr int M = Bn * Nn;  // 4000

    sum_adj_pad_k<<<dim3(Bn * Nn), 128, 0, stream>>>(adj, Asum);
    tcvt_all_k<<<dim3(16, 64, 5), 256, 0, stream>>>(Wn, Wq, Wh, Wc, W1,
                                                    WnT, WqT, WhT, WcT, W1T);

    gemm_nc_k<<<dim3((M + 63) / 64, 8), 256, 0, stream>>>(nodes_glove, WnT, bn,
                                                          nodes_length, nc, lh0);
    gemm_qc_k<<<dim3((Bn * Qn + 63) / 64, 8), 256, 0, stream>>>(query_glove, WqT, bq, qc);

    // 3 hops; cur starts at lh0, after 3 swaps cur==lh1.
    unsigned short* cur = lh0;
    unsigned short* nxt = lh1;
    for (int h = 0; h < 3; ++h) {
        gemm_hm_k<<<dim3((M + 63) / 64, 8), 256, 0, stream>>>(cur, WhT, bh,
                                                              nodes_length, hm);
        upd_sparse_k<<<dim3(M / 4), 256, 0, stream>>>(Asum, hm, upd);
        gemm_att_k<<<dim3((M + 63) / 64, 8), 256, 0, stream>>>(upd, cur, WcT, bc,
                                                               nodes_length, nxt);
        unsigned short* tmp = cur; cur = nxt; nxt = tmp;
    }
    // cur == lh1 == final last_hop.

    sim_fused_k<<<dim3(Bn, 125), 256, 0, stream>>>(cur, qc, wa, n2q, rowmax);
    bvec_k<<<dim3(Bn), 512, 0, stream>>>(rowmax, bvec);
    q2n_k<<<dim3(Bn, ENC / 256), 256, 0, stream>>>(bvec, nc, q2n);
    gbf_k<<<dim3(M), 256, 0, stream>>>(nc, n2q, q2n, gbf);       // consumes n2q
    gemm_final_k<<<dim3((M + 63) / 64, 2, 4), 256, 0, stream>>>(gbf, W1T, part);
    final_reduce_k<<<dim3((M + 3) / 4), 256, 0, stream>>>(part, b1, W2, b2, raw);
    predmax_k<<<dim3((Bn * NCn + 3) / 4), 256, 0, stream>>>(maskp, raw, out);
}

// Round 14
// 340.622 us; speedup vs baseline: 1.3659x; 1.0560x over previous
//
#include <hip/hip_runtime.h>
#include <hip/hip_bf16.h>
#include <math.h>
#include <stdint.h>

namespace {

constexpr int Bn  = 8;
constexpr int Nn  = 500;
constexpr int Qn  = 25;
constexpr int ENC = 512;
constexpr int DIN = 300;
constexpr int NCn = 70;
constexpr int NETn = 3;

typedef __attribute__((ext_vector_type(8))) short bf16x8_t;
typedef __attribute__((ext_vector_type(4))) float f32x4_t;

__device__ __forceinline__ unsigned short f2bf(float f) {
    union { __hip_bfloat16 b; unsigned short u; } r;
    r.b = __float2bfloat16(f);
    return r.u;
}
__device__ __forceinline__ bf16x8_t cvt8(float4 f0, float4 f1) {
    union { bf16x8_t v; __hip_bfloat162 b[4]; } r;
    r.b[0] = __float22bfloat162_rn(make_float2(f0.x, f0.y));
    r.b[1] = __float22bfloat162_rn(make_float2(f0.z, f0.w));
    r.b[2] = __float22bfloat162_rn(make_float2(f1.x, f1.y));
    r.b[3] = __float22bfloat162_rn(make_float2(f1.z, f1.w));
    return r.v;
}
__device__ __forceinline__ float bf2f(unsigned short h) {
    unsigned int u = ((unsigned int)h) << 16;
    return __builtin_bit_cast(float, u);
}
__device__ __forceinline__ float sigmoidf_(float x) { return 1.0f / (1.0f + expf(-x)); }

// ---------------------------------------------------------------------------
// Asum[b][i][j] = sum_e adj[b,e,i,j], fp32, j padded 500->512 with zeros.
__global__ __launch_bounds__(128) void sum_adj_pad_k(const float* __restrict__ adj,
                                                     float* __restrict__ Asum) {
    int bi = blockIdx.x;
    int b = bi / Nn, i = bi - b * Nn;
    int j = threadIdx.x * 4;
    float4 s = make_float4(0.f, 0.f, 0.f, 0.f);
    if (j < Nn) {
#pragma unroll
        for (int e = 0; e < NETn; ++e) {
            const float* p = adj + (((size_t)(b * NETn + e) * Nn) + i) * Nn + j;
            float4 v = *(const float4*)p;
            s.x += v.x; s.y += v.y; s.z += v.z; s.w += v.w;
        }
    }
    *(float4*)(Asum + ((size_t)bi) * 512 + j) = s;
}

// ---------------------------------------------------------------------------
// All weight transposes in one launch. z selects slice; idle blocks exit.
// sel2: Wh -> WhcT rows 0..511.  sel3: Wc rows 512..1023 -> WhcT rows 512..1023
// (so WhcT = B^T for lh @ [Wh | Wc_lo]).  sel4: Wc rows 0..511 -> WcHiT.
__global__ __launch_bounds__(256) void tcvt_all_k(
    const float* __restrict__ Wn, const float* __restrict__ Wq,
    const float* __restrict__ Wh, const float* __restrict__ Wc,
    const float* __restrict__ W1,
    unsigned short* __restrict__ WnT, unsigned short* __restrict__ WqT,
    unsigned short* __restrict__ WhcT, unsigned short* __restrict__ WcHiT,
    unsigned short* __restrict__ W1T) {
    __shared__ float tile[32][33];
    int sel = blockIdx.z;
    const float* in; unsigned short* out; int K, N, Kpad;
    if (sel == 0)      { in = Wn; out = WnT; K = DIN; N = ENC; Kpad = 320; }
    else if (sel == 1) { in = Wq; out = WqT; K = DIN; N = ENC; Kpad = 320; }
    else if (sel == 2) { in = Wh; out = WhcT; K = 512; N = ENC; Kpad = 512; }
    else if (sel == 3) { in = Wc + (size_t)512 * ENC; out = WhcT + (size_t)512 * 512;
                         K = 512; N = ENC; Kpad = 512; }
    else if (sel == 4) { in = Wc; out = WcHiT; K = 512; N = ENC; Kpad = 512; }
    else               { in = W1; out = W1T; K = 2048; N = 128; Kpad = 2048; }
    int n0 = blockIdx.x * 32, k0 = blockIdx.y * 32;
    if (n0 >= N || k0 >= Kpad) return;
    int tx = threadIdx.x & 31, ty = threadIdx.x >> 5;
#pragma unroll
    for (int r = 0; r < 4; ++r) {
        int k = k0 + ty * 4 + r;
        int n = n0 + tx;
        tile[ty * 4 + r][tx] = (k < K && n < N) ? in[(size_t)k * N + n] : 0.0f;
    }
    __syncthreads();
#pragma unroll
    for (int r = 0; r < 4; ++r) {
        int n = n0 + ty * 4 + r;
        int k = k0 + tx;
        if (n < N && k < Kpad) out[(size_t)n * Kpad + k] = f2bf(tile[tx][ty * 4 + r]);
    }
}

// ---------------------------------------------------------------------------
// MFMA core, BK=64 (R13-proven): 64x64 tile, 4 waves, double-buffered LDS,
// one barrier per 64-k step.  AMODE 0: A fp32 (A2 concat, Klim clamp).
// AMODE 1: A bf16 (Abf; optional Abf2 concat).  Bt: bf16 B^T [n][k].
template <int AMODE>
__device__ __forceinline__ void mfma_core(
    const float* __restrict__ A, const float* __restrict__ A2,
    const unsigned short* __restrict__ Abf, const unsigned short* __restrict__ Abf2,
    int lda, int ksplit, int Klim,
    const unsigned short* __restrict__ Bt, int ldb,
    int m0, int n0, int K, int Mlim,
    unsigned short* As, unsigned short* Bts, f32x4_t acc[2][2]) {
    const int t = threadIdx.x;
    const int lane = t & 63;
    const int w = t >> 6;
    const int sm = t >> 2;
    const int sp = t & 3;
    const int sq = sp ^ ((sm >> 1) & 3);
    const int arow = m0 + sm;
    const bool rowok = arow < Mlim;
    const int wm = (w & 1) * 32, wn = (w >> 1) * 32;
    const int quad = lane >> 4, cidx = lane & 15;
    const int am0 = wm + cidx, am1 = wm + 16 + cidx;
    const int an0 = wn + cidx, an1 = wn + 16 + cidx;
    const int apo0 = am0 * 32 + (quad ^ ((am0 >> 1) & 3)) * 8;
    const int apo1 = am1 * 32 + (quad ^ ((am1 >> 1) & 3)) * 8;
    const int bpo0 = an0 * 32 + (quad ^ ((an0 >> 1) & 3)) * 8;
    const int bpo1 = an1 * 32 + (quad ^ ((an1 >> 1) & 3)) * 8;

    bf16x8_t ast0, ast1, bst0, bst1;
    auto stageA = [&](int kg) -> bf16x8_t {
        if (AMODE == 1) {
            bf16x8_t r = {0, 0, 0, 0, 0, 0, 0, 0};
            if (rowok) {
                const unsigned short* src =
                    (Abf2 != nullptr && kg >= ksplit)
                        ? Abf2 + (size_t)arow * lda + (kg - ksplit)
                        : Abf + (size_t)arow * lda + kg;
                r = *(const bf16x8_t*)src;
            }
            return r;
        } else {
            float4 f0 = make_float4(0.f, 0.f, 0.f, 0.f);
            float4 f1 = make_float4(0.f, 0.f, 0.f, 0.f);
            if (rowok) {
                const float* src = (A2 != nullptr && kg >= ksplit)
                                       ? A2 + (size_t)arow * lda + (kg - ksplit)
                                       : A + (size_t)arow * lda + kg;
                if (kg + 8 <= Klim) {
                    f0 = *(const float4*)src;
                    f1 = *(const float4*)(src + 4);
                } else if (kg + 4 <= Klim) {
                    f0 = *(const float4*)src;
                }
            }
            return cvt8(f0, f1);
        }
    };
    auto stage = [&](int k0) {
        int kg0 = k0 + sq * 8;
        int kg1 = k0 + 32 + sq * 8;
        ast0 = stageA(kg0);
        ast1 = stageA(kg1);
        const unsigned short* brow = Bt + (size_t)(n0 + sm) * ldb;
        bst0 = *(const bf16x8_t*)(brow + kg0);
        bst1 = *(const bf16x8_t*)(brow + kg1);
    };

    const int ktot = K >> 6;
    stage(0);
    *(bf16x8_t*)(As + t * 8) = ast0;
    *(bf16x8_t*)(As + 2048 + t * 8) = ast1;
    *(bf16x8_t*)(Bts + t * 8) = bst0;
    *(bf16x8_t*)(Bts + 2048 + t * 8) = bst1;
    for (int kt = 0; kt < ktot; ++kt) {
        __syncthreads();
        const int cur = (kt & 1) * 4096;
        const bool more = (kt + 1) < ktot;
        if (more) stage((kt + 1) << 6);
        {
            bf16x8_t a0 = *(const bf16x8_t*)(As + cur + apo0);
            bf16x8_t a1 = *(const bf16x8_t*)(As + cur + apo1);
            bf16x8_t b0 = *(const bf16x8_t*)(Bts + cur + bpo0);
            bf16x8_t b1 = *(const bf16x8_t*)(Bts + cur + bpo1);
            acc[0][0] = __builtin_amdgcn_mfma_f32_16x16x32_bf16(a0, b0, acc[0][0], 0, 0, 0);
            acc[0][1] = __builtin_amdgcn_mfma_f32_16x16x32_bf16(a0, b1, acc[0][1], 0, 0, 0);
            acc[1][0] = __builtin_amdgcn_mfma_f32_16x16x32_bf16(a1, b0, acc[1][0], 0, 0, 0);
            acc[1][1] = __builtin_amdgcn_mfma_f32_16x16x32_bf16(a1, b1, acc[1][1], 0, 0, 0);
        }
        {
            bf16x8_t a0 = *(const bf16x8_t*)(As + cur + 2048 + apo0);
            bf16x8_t a1 = *(const bf16x8_t*)(As + cur + 2048 + apo1);
            bf16x8_t b0 = *(const bf16x8_t*)(Bts + cur + 2048 + bpo0);
            bf16x8_t b1 = *(const bf16x8_t*)(Bts + cur + 2048 + bpo1);
            acc[0][0] = __builtin_amdgcn_mfma_f32_16x16x32_bf16(a0, b0, acc[0][0], 0, 0, 0);
            acc[0][1] = __builtin_amdgcn_mfma_f32_16x16x32_bf16(a0, b1, acc[0][1], 0, 0, 0);
            acc[1][0] = __builtin_amdgcn_mfma_f32_16x16x32_bf16(a1, b0, acc[1][0], 0, 0, 0);
            acc[1][1] = __builtin_amdgcn_mfma_f32_16x16x32_bf16(a1, b1, acc[1][1], 0, 0, 0);
        }
        if (more) {
            const int nxt = ((kt + 1) & 1) * 4096;
            *(bf16x8_t*)(As + nxt + t * 8) = ast0;
            *(bf16x8_t*)(As + nxt + 2048 + t * 8) = ast1;
            *(bf16x8_t*)(Bts + nxt + t * 8) = bst0;
            *(bf16x8_t*)(Bts + nxt + 2048 + t * 8) = bst1;
        }
    }
}

#define EPI_SETUP                                         \
    int t = threadIdx.x, lane = t & 63, w = t >> 6;       \
    int wm = (w & 1) * 32, wn = (w >> 1) * 32;            \
    int quad = lane >> 4, cidx = lane & 15;               \
    (void)wm; (void)wn; (void)quad; (void)cidx;

// ---------------------------------------------------------------------------
// nc = tanh(ng@Wn+bn) fp32;  lh0 = bf16(nc * rowmask)
__global__ __launch_bounds__(256) void gemm_nc_k(const float* __restrict__ ng,
                                                 const unsigned short* __restrict__ WnT,
                                                 const float* __restrict__ bn,
                                                 const int* __restrict__ lens,
                                                 float* __restrict__ nc,
                                                 unsigned short* __restrict__ lh0) {
    __shared__ __align__(16) unsigned short As[8192], Bts[8192];
    f32x4_t z = {0.f, 0.f, 0.f, 0.f};
    f32x4_t acc[2][2] = {{z, z}, {z, z}};
    int m0 = blockIdx.x * 64, n0 = blockIdx.y * 64;
    mfma_core<0>(ng, nullptr, nullptr, nullptr, DIN, 1 << 30, DIN, WnT, 320,
                 m0, n0, 320, Bn * Nn, As, Bts, acc);
    EPI_SETUP
#pragma unroll
    for (int nj = 0; nj < 2; ++nj) {
        int col = n0 + wn + nj * 16 + cidx;
        float bias = bn[col];
#pragma unroll
        for (int mi = 0; mi < 2; ++mi) {
#pragma unroll
            for (int r = 0; r < 4; ++r) {
                int row = m0 + wm + mi * 16 + quad * 4 + r;
                if (row < Bn * Nn) {
                    float tv = tanhf(acc[mi][nj][r] + bias);
                    int b = row / Nn, i = row - b * Nn;
                    float rm = (i < lens[b]) ? 1.0f : 0.0f;
                    nc[(size_t)row * ENC + col] = tv;
                    lh0[(size_t)row * ENC + col] = f2bf(tv * rm);
                }
            }
        }
    }
}

// ---------------------------------------------------------------------------
__global__ __launch_bounds__(256) void gemm_qc_k(const float* __restrict__ qg,
                                                 const unsigned short* __restrict__ WqT,
                                                 const float* __restrict__ bq,
                                                 float* __restrict__ qc) {
    __shared__ __align__(16) unsigned short As[8192], Bts[8192];
    f32x4_t z = {0.f, 0.f, 0.f, 0.f};
    f32x4_t acc[2][2] = {{z, z}, {z, z}};
    int m0 = blockIdx.x * 64, n0 = blockIdx.y * 64;
    mfma_core<0>(qg, nullptr, nullptr, nullptr, DIN, 1 << 30, DIN, WqT, 320,
                 m0, n0, 320, Bn * Qn, As, Bts, acc);
    EPI_SETUP
#pragma unroll
    for (int nj = 0; nj < 2; ++nj) {
        int col = n0 + wn + nj * 16 + cidx;
        float bias = bq[col];
#pragma unroll
        for (int mi = 0; mi < 2; ++mi) {
#pragma unroll
            for (int r = 0; r < 4; ++r) {
                int row = m0 + wm + mi * 16 + quad * 4 + r;
                if (row < Bn * Qn) qc[(size_t)row * ENC + col] = acc[mi][nj][r] + bias;
            }
        }
    }
}

// ---------------------------------------------------------------------------
// Wide hop GEMM: lh @ [Wh | Wc_lo]  (N=1024, K=512).
// cols 0..511  -> hm = bf16((x + bh)*rm)
// cols 512..1023 -> pa = x  (fp32 partial att logits, lh @ Wc_lo)
__global__ __launch_bounds__(256) void gemm_hmw_k(const unsigned short* __restrict__ lh,
                                                  const unsigned short* __restrict__ WhcT,
                                                  const float* __restrict__ bh,
                                                  const int* __restrict__ lens,
                                                  unsigned short* __restrict__ hm,
                                                  float* __restrict__ pa) {
    __shared__ __align__(16) unsigned short As[8192], Bts[8192];
    f32x4_t z = {0.f, 0.f, 0.f, 0.f};
    f32x4_t acc[2][2] = {{z, z}, {z, z}};
    int m0 = blockIdx.x * 64, n0 = blockIdx.y * 64;   // n0 in [0,1024)
    mfma_core<1>(nullptr, nullptr, lh, nullptr, ENC, 1 << 30, ENC, WhcT, 512,
                 m0, n0, ENC, Bn * Nn, As, Bts, acc);
    EPI_SETUP
#pragma unroll
    for (int nj = 0; nj < 2; ++nj) {
        int col = n0 + wn + nj * 16 + cidx;
        bool ishm = col < 512;
        float bias = ishm ? bh[col] : 0.0f;
#pragma unroll
        for (int mi = 0; mi < 2; ++mi) {
#pragma unroll
            for (int r = 0; r < 4; ++r) {
                int row = m0 + wm + mi * 16 + quad * 4 + r;
                if (row < Bn * Nn) {
                    int b = row / Nn, i = row - b * Nn;
                    float rm = (i < lens[b]) ? 1.0f : 0.0f;
                    float v = acc[mi][nj][r];
                    if (ishm) {
                        hm[(size_t)row * ENC + col] = f2bf((v + bias) * rm);
                    } else {
                        pa[(size_t)row * ENC + (col - 512)] = v;
                    }
                }
            }
        }
    }
}

// ---------------------------------------------------------------------------
// Sparse aggregation: upd[b,i,:] = hm[b,i,:] + sum_j Asum[b,i,j]*hm[b,j,:].
__global__ __launch_bounds__(256) void upd_sparse_k(const float* __restrict__ Asum,
                                                    const unsigned short* __restrict__ hm,
                                                    unsigned short* __restrict__ upd) {
    int wv = threadIdx.x >> 6, lane = threadIdx.x & 63;
    int row = blockIdx.x * 4 + wv;
    int b = row / Nn, i = row - b * Nn;
    const float* arow = Asum + (size_t)row * 512;
    const unsigned short* hmb = hm + (size_t)b * Nn * ENC;
    int d0 = lane * 8;

    float acc[8];
    {
        bf16x8_t h = *(const bf16x8_t*)(hmb + (size_t)i * ENC + d0);
#pragma unroll
        for (int j = 0; j < 8; ++j) acc[j] = bf2f((unsigned short)h[j]);
    }
#pragma unroll
    for (int c = 0; c < 8; ++c) {
        int j = c * 64 + lane;
        float val = (j < Nn) ? arow[j] : 0.0f;
        unsigned long long mask = __ballot(val != 0.0f);
        while (mask) {
            int b0 = __ffsll((unsigned long long)mask) - 1;
            mask &= mask - 1;
            int b1 = -1;
            if (mask) { b1 = __ffsll((unsigned long long)mask) - 1; mask &= mask - 1; }
            float v0 = __shfl(val, b0, 64);
            bf16x8_t x = *(const bf16x8_t*)(hmb + (size_t)(c * 64 + b0) * ENC + d0);
            float v1 = 0.0f;
            bf16x8_t y = {0, 0, 0, 0, 0, 0, 0, 0};
            if (b1 >= 0) {
                v1 = __shfl(val, b1, 64);
                y = *(const bf16x8_t*)(hmb + (size_t)(c * 64 + b1) * ENC + d0);
            }
#pragma unroll
            for (int k = 0; k < 8; ++k)
                acc[k] += v0 * bf2f((unsigned short)x[k]) + v1 * bf2f((unsigned short)y[k]);
        }
    }
    float4 o0 = make_float4(acc[0], acc[1], acc[2], acc[3]);
    float4 o1 = make_float4(acc[4], acc[5], acc[6], acc[7]);
    *(bf16x8_t*)(upd + (size_t)row * ENC + d0) = cvt8(o0, o1);
}

// ---------------------------------------------------------------------------
// att = sigmoid(upd@Wc_hi + pa + bc)*rm; lh_out = bf16(att*tanh(upd)+(1-att)*lh)
// K = 512 only (the upd half) — pa carries the lh half.
__global__ __launch_bounds__(256) void gemm_att_k(const unsigned short* __restrict__ upd,
                                                  const unsigned short* __restrict__ lh,
                                                  const unsigned short* __restrict__ WcHiT,
                                                  const float* __restrict__ pa,
                                                  const float* __restrict__ bc,
                                                  const int* __restrict__ lens,
                                                  unsigned short* __restrict__ lh_out) {
    __shared__ __align__(16) unsigned short As[8192], Bts[8192];
    f32x4_t z = {0.f, 0.f, 0.f, 0.f};
    f32x4_t acc[2][2] = {{z, z}, {z, z}};
    int m0 = blockIdx.x * 64, n0 = blockIdx.y * 64;
    mfma_core<1>(nullptr, nullptr, upd, nullptr, ENC, 1 << 30, ENC, WcHiT, 512,
                 m0, n0, ENC, Bn * Nn, As, Bts, acc);
    EPI_SETUP
#pragma unroll
    for (int nj = 0; nj < 2; ++nj) {
        int col = n0 + wn + nj * 16 + cidx;
        float bias = bc[col];
#pragma unroll
        for (int mi = 0; mi < 2; ++mi) {
#pragma unroll
            for (int r = 0; r < 4; ++r) {
                int row = m0 + wm + mi * 16 + quad * 4 + r;
                if (row < Bn * Nn) {
                    int b = row / Nn, i = row - b * Nn;
                    float rm = (i < lens[b]) ? 1.0f : 0.0f;
                    size_t off = (size_t)row * ENC + col;
                    float a = sigmoidf_(acc[mi][nj][r] + pa[off] + bias) * rm;
                    float u = bf2f(upd[off]);
                    float l = bf2f(lh[off]);
                    lh_out[off] = f2bf(a * tanhf(u) + (1.0f - a) * l);
                }
            }
        }
    }
}

// ---------------------------------------------------------------------------
// Materialize g = [nc | n2q | nc*n2q | nc*q2n] as bf16 [4000][2048].
__global__ __launch_bounds__(256) void gbf_k(const float* __restrict__ nc,
                                             const float* __restrict__ n2q,
                                             const float* __restrict__ q2n,
                                             unsigned short* __restrict__ gbf) {
    int row = blockIdx.x;
    int b = row / Nn;
    int t = threadIdx.x;
    int seg = t >> 6;
    int d = (t & 63) * 8;
    size_t off = (size_t)row * ENC + d;
    float4 a0, a1;
    if (seg == 0) {
        a0 = *(const float4*)(nc + off); a1 = *(const float4*)(nc + off + 4);
    } else if (seg == 1) {
        a0 = *(const float4*)(n2q + off); a1 = *(const float4*)(n2q + off + 4);
    } else if (seg == 2) {
        float4 x0 = *(const float4*)(nc + off), x1 = *(const float4*)(nc + off + 4);
        float4 y0 = *(const float4*)(n2q + off), y1 = *(const float4*)(n2q + off + 4);
        a0 = make_float4(x0.x * y0.x, x0.y * y0.y, x0.z * y0.z, x0.w * y0.w);
        a1 = make_float4(x1.x * y1.x, x1.y * y1.y, x1.z * y1.z, x1.w * y1.w);
    } else {
        float4 x0 = *(const float4*)(nc + off), x1 = *(const float4*)(nc + off + 4);
        const float* qp = q2n + (size_t)b * ENC + d;
        float4 y0 = *(const float4*)qp, y1 = *(const float4*)(qp + 4);
        a0 = make_float4(x0.x * y0.x, x0.y * y0.y, x0.z * y0.z, x0.w * y0.w);
        a1 = make_float4(x1.x * y1.x, x1.y * y1.y, x1.z * y1.z, x1.w * y1.w);
    }
    *(bf16x8_t*)(gbf + (size_t)row * 2048 + seg * 512 + d) = cvt8(a0, a1);
}

// ---------------------------------------------------------------------------
// g @ W1 split-K partials via MFMA; z = K-slice in [0,4) (512 wide).
__global__ __launch_bounds__(256) void gemm_final_k(const unsigned short* __restrict__ gbf,
                                                    const unsigned short* __restrict__ W1T,
                                                    float* __restrict__ part) {
    __shared__ __align__(16) unsigned short As[8192], Bts[8192];
    f32x4_t z4 = {0.f, 0.f, 0.f, 0.f};
    f32x4_t acc[2][2] = {{z4, z4}, {z4, z4}};
    int zz = blockIdx.z;
    int m0 = blockIdx.x * 64, n0 = blockIdx.y * 64;
    mfma_core<1>(nullptr, nullptr, gbf + zz * 512, nullptr, 2048, 1 << 30, 1 << 30,
                 W1T + zz * 512, 2048, m0, n0, 512, Bn * Nn, As, Bts, acc);
    EPI_SETUP
    constexpr int M = Bn * Nn;
#pragma unroll
    for (int nj = 0; nj < 2; ++nj) {
        int col = n0 + wn + nj * 16 + cidx;
#pragma unroll
        for (int mi = 0; mi < 2; ++mi) {
#pragma unroll
            for (int r = 0; r < 4; ++r) {
                int row = m0 + wm + mi * 16 + quad * 4 + r;
                if (row < M) part[((size_t)zz * M + row) * 128 + col] = acc[mi][nj][r];
            }
        }
    }
}

// ---------------------------------------------------------------------------
// Fused sim -> softmax(q) -> nodes2query + rowmax.  One wave per n-row.
__global__ __launch_bounds__(256) void sim_fused_k(const unsigned short* __restrict__ lh,
                                                   const float* __restrict__ qc,
                                                   const float* __restrict__ wa,
                                                   float* __restrict__ n2q,
                                                   float* __restrict__ rowmax) {
    __shared__ float qcs[Qn * ENC];
    __shared__ float qdot[32];
    int b = blockIdx.x;
    int t = threadIdx.x;
    const float* qcb = qc + (size_t)b * Qn * ENC;
    for (int i = t * 4; i < Qn * ENC; i += 1024) *(float4*)&qcs[i] = *(const float4*)&qcb[i];
    __syncthreads();
    {
        int q = t >> 3, j = t & 7;
        if (q < Qn) {
            float s = 0.f;
            for (int k = 0; k < 64; ++k) {
                int d = j + 8 * k;
                s += qcs[q * ENC + d] * wa[ENC + d];
            }
            s += __shfl_xor(s, 1, 64);
            s += __shfl_xor(s, 2, 64);
            s += __shfl_xor(s, 4, 64);
            if (j == 0) qdot[q] = s;
        }
    }
    __syncthreads();

    int wv = t >> 6, lane = t & 63;
    int n = blockIdx.y * 4 + wv;
    int dA = lane * 4;
    int dB = 256 + lane * 4;
    const unsigned short* lrow = lh + ((size_t)b * Nn + n) * ENC;
    ushort4 ua = *(const ushort4*)(lrow + dA);
    ushort4 ub = *(const ushort4*)(lrow + dB);
    float lv[8] = {bf2f(ua.x), bf2f(ua.y), bf2f(ua.z), bf2f(ua.w),
                   bf2f(ub.x), bf2f(ub.y), bf2f(ub.z), bf2f(ub.w)};
    float ndp = 0.f;
    float lvs[8];
#pragma unroll
    for (int j = 0; j < 4; ++j) {
        ndp += lv[j] * wa[dA + j];
        lvs[j] = lv[j] * wa[2 * ENC + dA + j];
        ndp += lv[4 + j] * wa[dB + j];
        lvs[4 + j] = lv[4 + j] * wa[2 * ENC + dB + j];
    }
#pragma unroll
    for (int off = 32; off; off >>= 1) ndp += __shfl_xor(ndp, off, 64);

    float s_[Qn];
#pragma unroll
    for (int q = 0; q < Qn; ++q) {
        float4 qa = *(const float4*)(qcs + q * ENC + dA);
        float4 qb = *(const float4*)(qcs + q * ENC + dB);
        s_[q] = lvs[0] * qa.x + lvs[1] * qa.y + lvs[2] * qa.z + lvs[3] * qa.w +
                lvs[4] * qb.x + lvs[5] * qb.y + lvs[6] * qb.z + lvs[7] * qb.w;
    }
#pragma unroll
    for (int q = 0; q < Qn; ++q) {
#pragma unroll
        for (int off = 32; off; off >>= 1) s_[q] += __shfl_xor(s_[q], off, 64);
    }
    float mx = -INFINITY;
#pragma unroll
    for (int q = 0; q < Qn; ++q) {
        s_[q] += ndp + qdot[q];
        mx = fmaxf(mx, s_[q]);
    }
    float sum = 0.f;
#pragma unroll
    for (int q = 0; q < Qn; ++q) { s_[q] = expf(s_[q] - mx); sum += s_[q]; }
    float inv = 1.0f / sum;
    float o[8] = {};
#pragma unroll
    for (int q = 0; q < Qn; ++q) {
        float4 qa = *(const float4*)(qcs + q * ENC + dA);
        float4 qb = *(const float4*)(qcs + q * ENC + dB);
        float p = s_[q] * inv;
        o[0] += p * qa.x; o[1] += p * qa.y; o[2] += p * qa.z; o[3] += p * qa.w;
        o[4] += p * qb.x; o[5] += p * qb.y; o[6] += p * qb.z; o[7] += p * qb.w;
    }
    float* orow = n2q + ((size_t)b * Nn + n) * ENC;
    *(float4*)(orow + dA) = make_float4(o[0], o[1], o[2], o[3]);
    *(float4*)(orow + dB) = make_float4(o[4], o[5], o[6], o[7]);
    if (lane == 0) rowmax[b * Nn + n] = mx;
}

// ---------------------------------------------------------------------------
// Fused bvec (softmax over rowmax) + q2n (bvec-weighted sum of nc).
// grid Bn, block 512.
__global__ __launch_bounds__(512) void bvec_q2n_k(const float* __restrict__ rowmax,
                                                  const float* __restrict__ nc,
                                                  float* __restrict__ q2n) {
    __shared__ float red[8];
    __shared__ float bvs[512];
    int b = blockIdx.x, t = threadIdx.x;
    float v = (t < Nn) ? rowmax[b * Nn + t] : -INFINITY;
    float m = v;
    for (int off = 32; off; off >>= 1) m = fmaxf(m, __shfl_xor(m, off, 64));
    if ((t & 63) == 0) red[t >> 6] = m;
    __syncthreads();
    float bm = red[0];
    for (int i = 1; i < 8; ++i) bm = fmaxf(bm, red[i]);
    float e = (t < Nn) ? expf(v - bm) : 0.0f;
    float ssum = e;
    for (int off = 32; off; off >>= 1) ssum += __shfl_xor(ssum, off, 64);
    __syncthreads();
    if ((t & 63) == 0) red[t >> 6] = ssum;
    __syncthreads();
    float tot = 0.f;
    for (int i = 0; i < 8; ++i) tot += red[i];
    bvs[t] = e / tot;
    __syncthreads();
    // q2n[b][t] = sum_n bvs[n] * nc[b][n][t]
    const float* ncb = nc + (size_t)b * Nn * ENC;
    float acc = 0.f;
    for (int n = 0; n < Nn; ++n) acc = fmaf(bvs[n], ncb[(size_t)n * ENC + t], acc);
    q2n[b * ENC + t] = acc;
}

// ---------------------------------------------------------------------------
// raw[row] = b2 + sum_h tanh(sum_z part[z][row][h] + b1[h]) * W2[h]
__global__ __launch_bounds__(256) void final_reduce_k(const float* __restrict__ part,
                                                      const float* __restrict__ b1p,
                                                      const float* __restrict__ W2p,
                                                      const float* __restrict__ b2p,
                                                      float* __restrict__ raw) {
    constexpr int M = Bn * Nn;
    int wave = threadIdx.x >> 6, lane = threadIdx.x & 63;
    int row = blockIdx.x * 4 + wave;
    if (row >= M) return;
    float v0 = 0.f, v1 = 0.f;
#pragma unroll
    for (int s = 0; s < 4; ++s) {
        const float* pr = part + ((size_t)s * M + row) * 128;
        v0 += pr[lane];
        v1 += pr[lane + 64];
    }
    float p = tanhf(v0 + b1p[lane]) * W2p[lane] + tanhf(v1 + b1p[lane + 64]) * W2p[lane + 64];
    for (int off = 32; off; off >>= 1) p += __shfl_xor(p, off, 64);
    if (lane == 0) raw[row] = p + b2p[0];
}

// ---------------------------------------------------------------------------
__global__ __launch_bounds__(256) void predmax_k(const int* __restrict__ mask,
                                                 const float* __restrict__ raw,
                                                 float* __restrict__ out) {
    int idx = blockIdx.x * 4 + (threadIdx.x >> 6);
    int lane = threadIdx.x & 63;
    if (idx >= Bn * NCn) return;
    int b = idx / NCn, c = idx - b * NCn;
    const int* mrow = mask + ((size_t)b * NCn + c) * Nn;
    const float* rrow = raw + (size_t)b * Nn;
    float mx = -INFINITY;
    for (int n = lane; n < Nn; n += 64) {
        float v = mrow[n] ? rrow[n] : 0.0f;
        if (v == 0.0f) v = -1.0e6f;
        mx = fmaxf(mx, v);
    }
    for (int off = 32; off; off >>= 1) mx = fmaxf(mx, __shfl_xor(mx, off, 64));
    if (lane == 0) out[idx] = mx;
}

}  // namespace

extern "C" void kernel_launch(void* const* d_in, const int* in_sizes, int n_in,
                              void* d_out, int out_size, void* d_ws, size_t ws_size,
                              hipStream_t stream) {
    const float* nodes_glove  = (const float*)d_in[0];
    const float* query_glove  = (const float*)d_in[1];
    const float* adj          = (const float*)d_in[2];
    const int*   nodes_length = (const int*)d_in[3];
    const int*   maskp        = (const int*)d_in[4];
    const float* Wn = (const float*)d_in[5];
    const float* bn = (const float*)d_in[6];
    const float* Wq = (const float*)d_in[7];
    const float* bq = (const float*)d_in[8];
    const float* Wh = (const float*)d_in[9];
    const float* bh = (const float*)d_in[10];
    const float* Wc = (const float*)d_in[11];
    const float* bc = (const float*)d_in[12];
    const float* wa = (const float*)d_in[13];
    const float* W1 = (const float*)d_in[14];
    const float* b1 = (const float*)d_in[15];
    const float* W2 = (const float*)d_in[16];
    const float* b2 = (const float*)d_in[17];
    float* out = (float*)d_out;

    float* ws = (float*)d_ws;
    size_t off = 0;
    auto alloc = [&](size_t n) { float* p = ws + off; off += n; return p; };
    constexpr size_t ME  = (size_t)Bn * Nn * ENC;       // 2,048,000 fp32 elems
    constexpr size_t MEH = ME / 2;
    float* nc   = alloc(ME);
    float* Asum = alloc(ME);       // fp32 adjacency; then n2q; then part buf
    float* pa   = alloc(ME);       // fp32 partial att logits (lh @ Wc_lo)
    unsigned short* lh0 = (unsigned short*)alloc(MEH);
    unsigned short* lh1 = (unsigned short*)alloc(MEH);
    unsigned short* upd = (unsigned short*)alloc(MEH);
    unsigned short* hm  = (unsigned short*)alloc(MEH);
    unsigned short* gbf = (unsigned short*)alloc(ME * 2);   // [4000][2048] bf16
    float* qc   = alloc((size_t)Bn * Qn * ENC);
    float* rowmax = alloc(Bn * Nn);
    float* q2n    = alloc(Bn * ENC);
    float* raw    = alloc(Bn * Nn);
    unsigned short* WnT  = (unsigned short*)alloc((size_t)ENC * 320 / 2);
    unsigned short* WqT  = (unsigned short*)alloc((size_t)ENC * 320 / 2);
    unsigned short* WhcT = (unsigned short*)alloc((size_t)1024 * 512 / 2);
    unsigned short* WcHiT = (unsigned short*)alloc((size_t)512 * 512 / 2);
    unsigned short* W1T  = (unsigned short*)alloc((size_t)128 * 2048 / 2);
    alloc(16384);  // tail pad
    float* n2q  = Asum;            // phase 2
    float* part = Asum;            // phase 3 (after gbf consumed n2q)

    constexpr int M = Bn * Nn;  // 4000

    sum_adj_pad_k<<<dim3(Bn * Nn), 128, 0, stream>>>(adj, Asum);
    tcvt_all_k<<<dim3(16, 64, 6), 256, 0, stream>>>(Wn, Wq, Wh, Wc, W1,
                                                    WnT, WqT, WhcT, WcHiT, W1T);

    gemm_nc_k<<<dim3((M + 63) / 64, 8), 256, 0, stream>>>(nodes_glove, WnT, bn,
                                                          nodes_length, nc, lh0);
    gemm_qc_k<<<dim3((Bn * Qn + 63) / 64, 8), 256, 0, stream>>>(query_glove, WqT, bq, qc);

    // 3 hops; cur starts at lh0, after 3 swaps cur==lh1.
    unsigned short* cur = lh0;
    unsigned short* nxt = lh1;
    for (int h = 0; h < 3; ++h) {
        gemm_hmw_k<<<dim3((M + 63) / 64, 16), 256, 0, stream>>>(cur, WhcT, bh,
                                                                nodes_length, hm, pa);
        upd_sparse_k<<<dim3(M / 4), 256, 0, stream>>>(Asum, hm, upd);
        gemm_att_k<<<dim3((M + 63) / 64, 8), 256, 0, stream>>>(upd, cur, WcHiT, pa,
                                                               bc, nodes_length, nxt);
        unsigned short* tmp = cur; cur = nxt; nxt = tmp;
    }
    // cur == lh1 == final last_hop.

    sim_fused_k<<<dim3(Bn, 125), 256, 0, stream>>>(cur, qc, wa, n2q, rowmax);
    bvec_q2n_k<<<dim3(Bn), 512, 0, stream>>>(rowmax, nc, q2n);
    gbf_k<<<dim3(M), 256, 0, stream>>>(nc, n2q, q2n, gbf);       // consumes n2q
    gemm_final_k<<<dim3((M + 63) / 64, 2, 4), 256, 0, stream>>>(gbf, W1T, part);
    final_reduce_k<<<dim3((M + 3) / 4), 256, 0, stream>>>(part, b1, W2, b2, raw);
    predmax_k<<<dim3((Bn * NCn + 3) / 4), 256, 0, stream>>>(maskp, raw, out);
}